// Round 10
// baseline (2570.754 us; speedup 1.0000x reference)
//
#include <hip/hip_runtime.h>
#include <math.h>

#define EPS 1e-5f

// Model dims: B=64, T=512, CIN=4, E=256, H=8, dh=32, S=513, L=4, NC=2.
// GEMMs: split-bf16 (hi+lo planes, 3 MFMA terms) => ~fp32 accuracy.
// Attention: S^T trick (MFMA(K,Q)) puts P directly in A-operand layout ->
// NO LDS round-trip, no barriers; V read as 2x ushort4 to match key order.

typedef __attribute__((ext_vector_type(8))) short short8;
typedef __attribute__((ext_vector_type(4))) float f32x4;

__device__ __forceinline__ float gelu_f(float x) {
  return 0.5f * x * (1.0f + erff(x * 0.70710678118654752440f));
}
__device__ __forceinline__ float sigmoid_f(float x) {
  return 1.0f / (1.0f + __expf(-x));
}
__device__ __forceinline__ unsigned short f2bf(float f) {
  unsigned int u = __float_as_uint(f);
  u = (u + 0x7FFFu + ((u >> 16) & 1u)) >> 16;
  return (unsigned short)u;
}
__device__ __forceinline__ float bf2f(unsigned short s) {
  return __uint_as_float(((unsigned int)s) << 16);
}
__device__ __forceinline__ float fexp2(float x) {
#if __has_builtin(__builtin_amdgcn_exp2f)
  return __builtin_amdgcn_exp2f(x);
#else
  return exp2f(x);
#endif
}
__device__ __forceinline__ void gl_lds16(const unsigned short* g, unsigned short* l) {
  __builtin_amdgcn_global_load_lds(
      (const __attribute__((address_space(1))) void*)g,
      (__attribute__((address_space(3))) void*)l, 16, 0, 0);
}

// ---------------- prep: fold conv bias + eval-BN into scale/shift ----------------
__global__ void prep_kernel(const float* __restrict__ c1b, const float* __restrict__ g1,
                            const float* __restrict__ b1, const float* __restrict__ c2b,
                            const float* __restrict__ g2, const float* __restrict__ b2,
                            float* __restrict__ eff) {
  const int t = threadIdx.x;
  const float bninv = rsqrtf(1.0f + EPS);
  const float e1g = bninv * g1[t];
  eff[t]       = e1g;
  eff[256 + t] = c1b[t] * e1g + b1[t];
  const float e2g = bninv * g2[t];
  eff[512 + t] = e2g;
  eff[768 + t] = c2b[t] * e2g + b2[t];
}

// positional embedding table [512][256]
__global__ void pe_kernel(float* __restrict__ pe) {
  const int t = blockIdx.x, e = threadIdx.x;
  const float freq = __expf((float)(e & ~1) * (-0.03597789207803197f));  // -ln(10000)/256
  const float ang = (float)t * freq;
  pe[t * 256 + e] = (e & 1) ? cosf(ang) : sinf(ang);
}

// zero Vt tail (k in [512,544)) once; k=512 is rewritten by QKV each layer
__global__ void vtzero_kernel(unsigned short* __restrict__ vth) {
  const int i = blockIdx.x * 256 + threadIdx.x;  // 16384 rows x 32
  if (i < 524288) vth[(long)(i >> 5) * 544 + 512 + (i & 31)] = 0;
}

// f32 -> bf16 hi+lo planes
__global__ void f2bf2_kernel(const float* __restrict__ src, unsigned short* __restrict__ dh,
                             unsigned short* __restrict__ dl, int n) {
  const int i = blockIdx.x * 256 + threadIdx.x;
  if (i < n) {
    const float x = src[i];
    const unsigned short h = f2bf(x);
    dh[i] = h;
    dl[i] = f2bf(x - bf2f(h));
  }
}

// w2e[e][s*256+ci] = conv2_w[e][ci][s]  (hi/lo), so conv2 == one K=768 GEMM
__global__ void repack_w2_kernel(const float* __restrict__ w2, unsigned short* __restrict__ w2h,
                                 unsigned short* __restrict__ w2l) {
  const int idx = blockIdx.x * 256 + threadIdx.x;  // 256*768
  const int e = idx / 768, rem = idx % 768;
  const int s = rem >> 8, ci = rem & 255;
  const float x = w2[e * 768 + ci * 3 + s];
  const unsigned short h = f2bf(x);
  w2h[idx] = h;
  w2l[idx] = f2bf(x - bf2f(h));
}

// zero padding rows of x1p planes [B][T+2][E]
__global__ void zeropad_kernel(unsigned short* __restrict__ xh, unsigned short* __restrict__ xl) {
  const int b = blockIdx.x, tid = threadIdx.x;
  const long r0 = ((long)b * 514) * 256 + tid;
  const long r1 = ((long)b * 514 + 513) * 256 + tid;
  xh[r0] = 0; xh[r1] = 0; xl[r0] = 0; xl[r1] = 0;
}

// ---------------- conv1 + BN + GELU -> x1p hi/lo planes (rows 1..T) ----------------
__global__ __launch_bounds__(256) void conv1_kernel(const float* __restrict__ in,
                                                    const float* __restrict__ w1,
                                                    const float* __restrict__ eff,
                                                    unsigned short* __restrict__ xh,
                                                    unsigned short* __restrict__ xl) {
  const int b = blockIdx.y, t0 = blockIdx.x * 64;
  const int tid = threadIdx.x;
  __shared__ float4 Ls[66];
  __shared__ float Wl[3072];
  if (tid < 66) {
    const int t = t0 - 1 + tid;
    float4 v = make_float4(0.f, 0.f, 0.f, 0.f);
    if (t >= 0 && t < 512) v = *(const float4*)(in + ((long)b * 512 + t) * 4);
    Ls[tid] = v;
  }
#pragma unroll
  for (int i = 0; i < 12; ++i) Wl[i * 256 + tid] = w1[i * 256 + tid];
  __syncthreads();
  float w[12];
#pragma unroll
  for (int i = 0; i < 12; ++i) w[i] = Wl[tid * 12 + i];  // [c*3+k]
  const float eg = eff[tid], eb = eff[256 + tid];
  const long ob = ((long)b * 514 + t0 + 1) * 256 + tid;
  for (int tl = 0; tl < 64; ++tl) {
    const float4 i0 = Ls[tl], i1 = Ls[tl + 1], i2 = Ls[tl + 2];
    float s = i0.x * w[0] + i1.x * w[1] + i2.x * w[2]
            + i0.y * w[3] + i1.y * w[4] + i2.y * w[5]
            + i0.z * w[6] + i1.z * w[7] + i2.z * w[8]
            + i0.w * w[9] + i1.w * w[10] + i2.w * w[11];
    const float y = gelu_f(s * eg + eb);
    const unsigned short h = f2bf(y);
    xh[ob + (long)tl * 256] = h;
    xl[ob + (long)tl * 256] = f2bf(y - bf2f(h));
  }
}

// ---------------- split-bf16 MFMA GEMM: C[M,N] = epi(A@W^T) ----------------
// Grid: n-tile = blockIdx.x, m-tile = blockIdx.y (A-tile shared by consecutive blocks).
// OUT: 0 = fp32 Cf; 1 = bf16 hi only; 2 = bf16 hi+lo; 3 = QKV fused (n<512: bf16 hi
// rows; n>=512: V written transposed into vth[b][h][d][kpad=544], k = row % 513).
template <int OUT, bool ACC, bool GELU_, bool SCALE, bool SPLITA>
__global__ __launch_bounds__(256) void bgemm3_kernel(
    const unsigned short* __restrict__ Ah, const unsigned short* __restrict__ Al,
    const unsigned short* __restrict__ Wh, const unsigned short* __restrict__ Wlo,
    const float* __restrict__ bias, const float* __restrict__ scale,
    float* __restrict__ Cf, unsigned short* __restrict__ Cbh, unsigned short* __restrict__ Cbl,
    unsigned short* __restrict__ vth,
    int M, int N, int K, int lda, int ldw, int groupT, int strideA) {
  __shared__ __align__(16) unsigned short SH[4][4096];  // Ah, Al, Wh, Wl tiles [128][32]
  const int tid = threadIdx.x;
  const int lane = tid & 63;
  const int m0 = blockIdx.y << 7, n0 = blockIdx.x << 7;
  const int g = m0 / groupT;
  const long abase = (long)(g * strideA + (m0 - g * groupT)) * lda;
  const int c0 = tid, c1 = tid + 256;
  const int r0c = c0 >> 2, k0c = (c0 & 3) << 3;
  const int r1c = c1 >> 2, k1c = (c1 & 3) << 3;
  const int mEdge = M - m0 - 1;
  const int r0a = r0c <= mEdge ? r0c : mEdge;
  const int r1a = r1c <= mEdge ? r1c : mEdge;
  const long offA0 = abase + (long)r0a * lda + k0c;
  const long offA1 = abase + (long)r1a * lda + k1c;
  const long offB0 = (long)(n0 + r0c) * ldw + k0c;
  const long offB1 = (long)(n0 + r1c) * ldw + k1c;
  unsigned short* s0 = &SH[0][c0 * 8];
  unsigned short* s1 = &SH[0][c1 * 8];
  const int fr = lane & 15, kg = lane >> 4;
  const int aoff = (((tid >> 7) << 6) + fr) * 32 + kg * 8;
  const int boff = ((((tid >> 6) & 1) << 6) + fr) * 32 + kg * 8;
  f32x4 acc[4][4];
#pragma unroll
  for (int i = 0; i < 4; ++i)
#pragma unroll
    for (int j = 0; j < 4; ++j) acc[i][j] = f32x4{0.f, 0.f, 0.f, 0.f};
  for (int k0 = 0; k0 < K; k0 += 32) {
    gl_lds16(Ah + offA0 + k0, s0);
    gl_lds16(Ah + offA1 + k0, s1);
    if (SPLITA) {
      gl_lds16(Al + offA0 + k0, s0 + 4096);
      gl_lds16(Al + offA1 + k0, s1 + 4096);
    }
    gl_lds16(Wh + offB0 + k0, s0 + 8192);
    gl_lds16(Wh + offB1 + k0, s1 + 8192);
    gl_lds16(Wlo + offB0 + k0, s0 + 12288);
    gl_lds16(Wlo + offB1 + k0, s1 + 12288);
    __syncthreads();
    short8 ah[4], al[4], bh[4], bl[4];
#pragma unroll
    for (int i = 0; i < 4; ++i) {
      ah[i] = *(const short8*)&SH[0][aoff + i * 512];
      if (SPLITA) al[i] = *(const short8*)&SH[1][aoff + i * 512];
    }
#pragma unroll
    for (int j = 0; j < 4; ++j) {
      bh[j] = *(const short8*)&SH[2][boff + j * 512];
      bl[j] = *(const short8*)&SH[3][boff + j * 512];
    }
#pragma unroll
    for (int i = 0; i < 4; ++i)
#pragma unroll
      for (int j = 0; j < 4; ++j) {
        acc[i][j] = __builtin_amdgcn_mfma_f32_16x16x32_bf16(ah[i], bl[j], acc[i][j], 0, 0, 0);
        if (SPLITA)
          acc[i][j] = __builtin_amdgcn_mfma_f32_16x16x32_bf16(al[i], bh[j], acc[i][j], 0, 0, 0);
        acc[i][j] = __builtin_amdgcn_mfma_f32_16x16x32_bf16(ah[i], bh[j], acc[i][j], 0, 0, 0);
      }
    __syncthreads();
  }
  const int colb = n0 + (((tid >> 6) & 1) << 6) + fr;
  float bj[4], sj[4];
#pragma unroll
  for (int j = 0; j < 4; ++j) {
    bj[j] = bias ? bias[colb + j * 16] : 0.f;
    sj[j] = SCALE ? scale[colb + j * 16] : 1.f;
  }
  const int rowb = m0 + ((tid >> 7) << 6) + kg * 4;
  if (OUT == 3 && n0 >= 512) {
    // V path: write transposed into vth[b][h][d][544]; rows = k (per batch of 513)
#pragma unroll
    for (int i = 0; i < 4; ++i) {
      const int row0 = rowb + i * 16;
      const int b0 = row0 / 513;
      const int sq0 = row0 - b0 * 513;
#pragma unroll
      for (int j = 0; j < 4; ++j) {
        const int col = colb + j * 16;
        const int hh = (col - 512) >> 5;
        const int dd = col & 31;
        ushort4 pk;
        pk.x = f2bf(acc[i][j][0] + bj[j]);
        pk.y = f2bf(acc[i][j][1] + bj[j]);
        pk.z = f2bf(acc[i][j][2] + bj[j]);
        pk.w = f2bf(acc[i][j][3] + bj[j]);
        if (row0 + 3 < M && sq0 <= 509) {
          *(ushort4*)(vth + (((long)(b0 * 8 + hh)) * 32 + dd) * 544 + sq0) = pk;
        } else {
          const unsigned short pr[4] = {pk.x, pk.y, pk.z, pk.w};
#pragma unroll
          for (int r = 0; r < 4; ++r) {
            const int row = row0 + r;
            if (row < M) {
              const int bb = row / 513, ss = row - bb * 513;
              vth[(((long)(bb * 8 + hh)) * 32 + dd) * 544 + ss] = pr[r];
            }
          }
        }
      }
    }
    return;
  }
#pragma unroll
  for (int i = 0; i < 4; ++i) {
#pragma unroll
    for (int r = 0; r < 4; ++r) {
      const int row = rowb + i * 16 + r;
      if (row < M) {
#pragma unroll
        for (int j = 0; j < 4; ++j) {
          const long off = (long)row * N + colb + j * 16;
          float v = acc[i][j][r];
          if (ACC) v += Cf[off];
          if (SCALE) v *= sj[j];
          v += bj[j];
          if (GELU_) v = gelu_f(v);
          if (OUT == 0) {
            Cf[off] = v;
          } else if (OUT == 2) {
            const unsigned short h = f2bf(v);
            Cbh[off] = h;
            Cbl[off] = f2bf(v - bf2f(h));
          } else {
            Cbh[off] = f2bf(v);
          }
        }
      }
    }
  }
}

// ---------------- fp32 GEMM (tiny tail mats only) ----------------
template <bool ACC, bool GELU_, bool SCALE>
__global__ __launch_bounds__(256) void gemm_kernel(const float* __restrict__ A,
                                                   const float* __restrict__ W,
                                                   const float* __restrict__ bias,
                                                   const float* __restrict__ scale,
                                                   float* __restrict__ C, int M, int N, int K,
                                                   int groupT, int strideA, int rowOff) {
  __shared__ float As[16][68];
  __shared__ float Bs[16][68];
  const int m0 = blockIdx.x * 64, n0 = blockIdx.y * 64;
  const int g = m0 / groupT, r0 = m0 - g * groupT;
  const float* Ab = A + (long)(g * strideA + r0 + rowOff) * K;
  const float* Wb = W + (long)n0 * K;
  const int tid = threadIdx.x;
  const int lr = tid >> 2;
  const int lk = (tid & 3) << 2;
  const int tr = (tid >> 4) << 2;
  const int tc = (tid & 15) << 2;
  float acc[4][4] = {{0.f}};
  for (int k0 = 0; k0 < K; k0 += 16) {
    const float4 a4 = *(const float4*)(Ab + (long)lr * K + k0 + lk);
    const float4 b4 = *(const float4*)(Wb + (long)lr * K + k0 + lk);
    __syncthreads();
    As[lk + 0][lr] = a4.x; As[lk + 1][lr] = a4.y; As[lk + 2][lr] = a4.z; As[lk + 3][lr] = a4.w;
    Bs[lk + 0][lr] = b4.x; Bs[lk + 1][lr] = b4.y; Bs[lk + 2][lr] = b4.z; Bs[lk + 3][lr] = b4.w;
    __syncthreads();
#pragma unroll
    for (int kk = 0; kk < 16; ++kk) {
      const float4 av = *(const float4*)&As[kk][tr];
      const float4 bv = *(const float4*)&Bs[kk][tc];
      acc[0][0] += av.x * bv.x; acc[0][1] += av.x * bv.y; acc[0][2] += av.x * bv.z; acc[0][3] += av.x * bv.w;
      acc[1][0] += av.y * bv.x; acc[1][1] += av.y * bv.y; acc[1][2] += av.y * bv.z; acc[1][3] += av.y * bv.w;
      acc[2][0] += av.z * bv.x; acc[2][1] += av.z * bv.y; acc[2][2] += av.z * bv.z; acc[2][3] += av.z * bv.w;
      acc[3][0] += av.w * bv.x; acc[3][1] += av.w * bv.y; acc[3][2] += av.w * bv.z; acc[3][3] += av.w * bv.w;
    }
  }
  float4 bb = make_float4(0.f, 0.f, 0.f, 0.f);
  if (bias) bb = *(const float4*)(bias + n0 + tc);
  float4 sv = make_float4(1.f, 1.f, 1.f, 1.f);
  if (SCALE) sv = *(const float4*)(scale + n0 + tc);
#pragma unroll
  for (int i = 0; i < 4; ++i) {
    float* cp = C + (long)(m0 + tr + i) * N + n0 + tc;
    float4 v = make_float4(acc[i][0], acc[i][1], acc[i][2], acc[i][3]);
    if (ACC) {
      const float4 c4 = *(const float4*)cp;
      v.x += c4.x; v.y += c4.y; v.z += c4.z; v.w += c4.w;
    }
    if (SCALE) { v.x *= sv.x; v.y *= sv.y; v.z *= sv.z; v.w *= sv.w; }
    v.x += bb.x; v.y += bb.y; v.z += bb.z; v.w += bb.w;
    if (GELU_) { v.x = gelu_f(v.x); v.y = gelu_f(v.y); v.z = gelu_f(v.z); v.w = gelu_f(v.w); }
    *(float4*)cp = v;
  }
}

// ---------------- SE gates (fp32) ----------------
__global__ __launch_bounds__(256) void ca_mean_kernel(const float* __restrict__ x2,
                                                      float* __restrict__ ca) {
  const int b = blockIdx.x, tid = threadIdx.x;
  float s = 0.f;
  for (int t = 0; t < 512; ++t) s += x2[((long)(b * 512 + t)) * 256 + tid];
  ca[b * 256 + tid] = s * (1.0f / 512.0f);
}

__global__ __launch_bounds__(256) void gate1_kernel(const float* __restrict__ ca,
    const float* __restrict__ w1, const float* __restrict__ b1,
    const float* __restrict__ lng, const float* __restrict__ lnb,
    const float* __restrict__ w2, const float* __restrict__ b2, float* __restrict__ ge) {
  const int b = blockIdx.x, tid = threadIdx.x;
  __shared__ float caL[256];
  __shared__ float zL[32];
  caL[tid] = ca[b * 256 + tid];
  __syncthreads();
  if (tid < 32) {
    float s = b1[tid];
    for (int e = 0; e < 256; ++e) s += caL[e] * w1[tid * 256 + e];
    float mean = s;
    for (int msk = 1; msk < 32; msk <<= 1) mean += __shfl_xor(mean, msk);
    mean *= (1.0f / 32.0f);
    const float d = s - mean;
    float v = d * d;
    for (int msk = 1; msk < 32; msk <<= 1) v += __shfl_xor(v, msk);
    v *= (1.0f / 32.0f);
    zL[tid] = gelu_f(d * rsqrtf(v + EPS) * lng[tid] + lnb[tid]);
  }
  __syncthreads();
  float a = b2[tid];
#pragma unroll
  for (int j = 0; j < 32; ++j) a += zL[j] * w2[tid * 32 + j];
  ge[b * 256 + tid] = sigmoid_f(a);
}

__global__ __launch_bounds__(256) void ta_mean_kernel(const float* __restrict__ x2,
                                                      const float* __restrict__ ge,
                                                      float* __restrict__ ta) {
  const int b = blockIdx.x, tid = threadIdx.x;
  const int w = tid >> 6, lane = tid & 63;
  const float4 g4 = *(const float4*)(ge + b * 256 + lane * 4);
  for (int t = w; t < 512; t += 4) {
    const float4 x4 = *(const float4*)(x2 + ((long)(b * 512 + t)) * 256 + lane * 4);
    float s = x4.x * g4.x + x4.y * g4.y + x4.z * g4.z + x4.w * g4.w;
#pragma unroll
    for (int msk = 32; msk; msk >>= 1) s += __shfl_xor(s, msk);
    if (lane == 0) ta[b * 512 + t] = s * (1.0f / 256.0f);
  }
}

__global__ __launch_bounds__(256) void gate2_kernel(const float* __restrict__ ta,
    const float* __restrict__ w1, const float* __restrict__ b1,
    const float* __restrict__ lng, const float* __restrict__ lnb,
    const float* __restrict__ w2, const float* __restrict__ b2, float* __restrict__ gt) {
  const int b = blockIdx.x, tid = threadIdx.x;
  __shared__ float taL[512];
  __shared__ float zL[64];
  taL[tid] = ta[b * 512 + tid];
  taL[256 + tid] = ta[b * 512 + 256 + tid];
  __syncthreads();
  if (tid < 64) {
    float s = b1[tid];
    for (int t = 0; t < 512; ++t) s += taL[t] * w1[tid * 512 + t];
    float mean = s;
    for (int msk = 1; msk < 64; msk <<= 1) mean += __shfl_xor(mean, msk);
    mean *= (1.0f / 64.0f);
    const float d = s - mean;
    float v = d * d;
    for (int msk = 1; msk < 64; msk <<= 1) v += __shfl_xor(v, msk);
    v *= (1.0f / 64.0f);
    zL[tid] = gelu_f(d * rsqrtf(v + EPS) * lng[tid] + lnb[tid]);
  }
  __syncthreads();
#pragma unroll
  for (int r = 0; r < 2; ++r) {
    const int t = tid + r * 256;
    float a = b2[t];
    for (int j = 0; j < 64; ++j) a += zL[j] * w2[t * 64 + j];
    gt[b * 512 + t] = sigmoid_f(a);
  }
}

// x_seq build (fp32 residual stream); PE precomputed
__global__ __launch_bounds__(256) void xseq_kernel(const float* __restrict__ x2,
    const float* __restrict__ ge, const float* __restrict__ gt,
    const float* __restrict__ cls, const float* __restrict__ pe, float* __restrict__ x) {
  const int srow = blockIdx.x, b = blockIdx.y, e = threadIdx.x;
  float* outp = x + ((long)(b * 513 + srow)) * 256 + e;
  if (srow == 0) { *outp = cls[e]; return; }
  const int t = srow - 1;
  *outp = x2[((long)(b * 512 + t)) * 256 + e] * ge[b * 256 + e] * gt[b * 512 + t]
        + pe[t * 256 + e];
}

// ---------------- LayerNorm fp32 -> fp32 (tail) ----------------
template <bool GELU_>
__global__ __launch_bounds__(256) void ln_kernel(const float* __restrict__ in,
                                                 const float* __restrict__ g,
                                                 const float* __restrict__ bta,
                                                 float* __restrict__ out, int D, int ostride) {
  const int row = blockIdx.x, tid = threadIdx.x;
  __shared__ float red[8];
  const float* x = in + (long)row * D;
  const int nv = D >> 8;
  float xv[4];
  float s = 0.f;
  for (int i = 0; i < nv; ++i) { xv[i] = x[tid + (i << 8)]; s += xv[i]; }
#pragma unroll
  for (int msk = 32; msk; msk >>= 1) s += __shfl_xor(s, msk);
  if ((tid & 63) == 0) red[tid >> 6] = s;
  __syncthreads();
  s = red[0] + red[1] + red[2] + red[3];
  const float mean = s / (float)D;
  float vs = 0.f;
  for (int i = 0; i < nv; ++i) { const float d = xv[i] - mean; vs += d * d; }
#pragma unroll
  for (int msk = 32; msk; msk >>= 1) vs += __shfl_xor(vs, msk);
  if ((tid & 63) == 0) red[4 + (tid >> 6)] = vs;
  __syncthreads();
  vs = red[4] + red[5] + red[6] + red[7];
  const float inv = rsqrtf(vs / (float)D + EPS);
  for (int i = 0; i < nv; ++i) {
    const int col = tid + (i << 8);
    float y = (xv[i] - mean) * inv * g[col] + bta[col];
    if (GELU_) y = gelu_f(y);
    out[(long)row * ostride + col] = y;
  }
}

// ---------------- LayerNorm D=256, fp32 -> bf16 hi/lo planes ----------------
__global__ __launch_bounds__(256) void ln256p_kernel(const float* __restrict__ in,
                                                     const float* __restrict__ g,
                                                     const float* __restrict__ bta,
                                                     unsigned short* __restrict__ oh,
                                                     unsigned short* __restrict__ ol) {
  const int row = blockIdx.x, tid = threadIdx.x;
  __shared__ float red[8];
  const float xv = in[(long)row * 256 + tid];
  float s = xv;
#pragma unroll
  for (int msk = 32; msk; msk >>= 1) s += __shfl_xor(s, msk);
  if ((tid & 63) == 0) red[tid >> 6] = s;
  __syncthreads();
  s = red[0] + red[1] + red[2] + red[3];
  const float mean = s * (1.0f / 256.0f);
  const float d = xv - mean;
  float vs = d * d;
#pragma unroll
  for (int msk = 32; msk; msk >>= 1) vs += __shfl_xor(vs, msk);
  if ((tid & 63) == 0) red[4 + (tid >> 6)] = vs;
  __syncthreads();
  vs = red[4] + red[5] + red[6] + red[7];
  const float inv = rsqrtf(vs * (1.0f / 256.0f) + EPS);
  const float y = d * inv * g[tid] + bta[tid];
  const unsigned short h = f2bf(y);
  oh[(long)row * 256 + tid] = h;
  ol[(long)row * 256 + tid] = f2bf(y - bf2f(h));
}

// ---------------- MFMA flash attention (S^T trick: zero LDS, zero barriers) ----------------
// 1D grid 4608: flat = h + 8*(qb + 9*b) (XCD locality). 4 waves, wave owns 16 q rows.
// S^T = MFMA(A=K, B=Q): C-layout gives lane(l16=q, quad) the 8 scores for keys
// {quad*4+r} u {16+quad*4+r} -> after exp, that IS the A-operand P fragment.
// V B-fragment read as two ushort4 at key offsets quad*4 and 16+quad*4 (matches order).
__global__ __launch_bounds__(256) void attn_bf16_kernel(
    const unsigned short* __restrict__ qkvh, const unsigned short* __restrict__ vth,
    unsigned short* __restrict__ oh) {
  const int flat = blockIdx.x;
  const int h = flat & 7;
  const int t_ = flat >> 3;
  const int qb = t_ % 9;
  const int b = t_ / 9;
  const int tid = threadIdx.x;
  const int wave = tid >> 6, lane = tid & 63;
  const int quad = lane >> 4, l16 = lane & 15;

  const long base = (long)b * 513;
  const int qrow = qb * 64 + wave * 16 + l16;
  const int qsafe = qrow < 513 ? qrow : 512;
  const short8 qh8 = *(const short8*)(qkvh + (base + qsafe) * 768 + h * 32 + quad * 8);
  const long vtb = ((long)(b * 8 + h)) * 32 * 544;

  const unsigned short* kp0 = qkvh + (base + l16) * 768 + 256 + h * 32 + quad * 8;
  const unsigned short* kp1 = kp0 + 16 * 768;
  const unsigned short* vr0 = vth + vtb + (long)l16 * 544 + quad * 4;        // d in [0,16)
  const unsigned short* vr1 = vr0 + 16 * 544;                                // d in [16,32)

  float lsum = 0.f;
  const f32x4 zf = {0.f, 0.f, 0.f, 0.f};
  f32x4 oacc[2] = {zf, zf};
  const float sf2 = 0.25506994362f;  // log2(e)/sqrt(32)

#pragma unroll 2
  for (int c = 0; c < 16; ++c) {
    const long ko = (long)c * (32 * 768);
    const short8 k0r = *(const short8*)(kp0 + ko);
    const short8 k1r = *(const short8*)(kp1 + ko);
    const f32x4 sc0 = __builtin_amdgcn_mfma_f32_16x16x32_bf16(k0r, qh8, zf, 0, 0, 0);
    const f32x4 sc1 = __builtin_amdgcn_mfma_f32_16x16x32_bf16(k1r, qh8, zf, 0, 0, 0);
    short8 p8;
#pragma unroll
    for (int j = 0; j < 4; ++j) {
      const unsigned short h0 = f2bf(fexp2(sc0[j] * sf2));
      const unsigned short h1 = f2bf(fexp2(sc1[j] * sf2));
      p8[j] = (short)h0;
      p8[4 + j] = (short)h1;
      lsum += bf2f(h0) + bf2f(h1);
    }
    const int kc = c * 32;
    const ushort4 va0 = *(const ushort4*)(vr0 + kc);
    const ushort4 va1 = *(const ushort4*)(vr0 + kc + 16);
    const ushort4 vb0 = *(const ushort4*)(vr1 + kc);
    const ushort4 vb1 = *(const ushort4*)(vr1 + kc + 16);
    const short8 vf0 = {(short)va0.x, (short)va0.y, (short)va0.z, (short)va0.w,
                        (short)va1.x, (short)va1.y, (short)va1.z, (short)va1.w};
    const short8 vf1 = {(short)vb0.x, (short)vb0.y, (short)vb0.z, (short)vb0.w,
                        (short)vb1.x, (short)vb1.y, (short)vb1.z, (short)vb1.w};
    oacc[0] = __builtin_amdgcn_mfma_f32_16x16x32_bf16(p8, vf0, oacc[0], 0, 0, 0);
    oacc[1] = __builtin_amdgcn_mfma_f32_16x16x32_bf16(p8, vf1, oacc[1], 0, 0, 0);
  }
  // tail: key 512 only. All lanes load K row 512 (broadcast A); the only real P
  // entry is k-index t=0 (key 512), held by quad==0 lanes.
  {
    const short8 kt = *(const short8*)(qkvh + (base + 512) * 768 + 256 + h * 32 + quad * 8);
    const f32x4 sct = __builtin_amdgcn_mfma_f32_16x16x32_bf16(kt, qh8, zf, 0, 0, 0);
    short8 p8 = {0, 0, 0, 0, 0, 0, 0, 0};
    if (quad == 0) {
      const unsigned short h0 = f2bf(fexp2(sct[0] * sf2));
      p8[0] = (short)h0;
      lsum += bf2f(h0);
    }
    const ushort4 va0 = *(const ushort4*)(vr0 + 512);
    const ushort4 va1 = *(const ushort4*)(vr0 + 528);
    const ushort4 vb0 = *(const ushort4*)(vr1 + 512);
    const ushort4 vb1 = *(const ushort4*)(vr1 + 528);
    const short8 vf0 = {(short)va0.x, (short)va0.y, (short)va0.z, (short)va0.w,
                        (short)va1.x, (short)va1.y, (short)va1.z, (short)va1.w};
    const short8 vf1 = {(short)vb0.x, (short)vb0.y, (short)vb0.z, (short)vb0.w,
                        (short)vb1.x, (short)vb1.y, (short)vb1.z, (short)vb1.w};
    oacc[0] = __builtin_amdgcn_mfma_f32_16x16x32_bf16(p8, vf0, oacc[0], 0, 0, 0);
    oacc[1] = __builtin_amdgcn_mfma_f32_16x16x32_bf16(p8, vf1, oacc[1], 0, 0, 0);
  }
  // l-reduction: sum over quads (lanes sharing l16), then gather per output row.
  lsum += __shfl_xor(lsum, 16);
  lsum += __shfl_xor(lsum, 32);
  const int orow0 = qb * 64 + wave * 16 + quad * 4;
#pragma unroll
  for (int r = 0; r < 4; ++r) {
    const int qr = orow0 + r;
    const float lv = __shfl(lsum, quad * 4 + r);
    if (qr < 513) {
      const float inv = 1.0f / lv;
      oh[(base + qr) * 256 + h * 32 + l16] = f2bf(oacc[0][r] * inv);
      oh[(base + qr) * 256 + h * 32 + 16 + l16] = f2bf(oacc[1][r] * inv);
    }
  }
}

// ---------------- fused fusion head: f = GELU(LN(CLS @ fus_w^T + fus_b)) ----------------
__global__ __launch_bounds__(256) void fushead_kernel(const float* __restrict__ x,
    const float* __restrict__ fw, const float* __restrict__ fb,
    const float* __restrict__ lng, const float* __restrict__ lnb,
    float* __restrict__ feats) {
  const int b = blockIdx.x, tid = threadIdx.x;
  __shared__ float cls[256];
  __shared__ float red[8];
  cls[tid] = x[(long)b * 513 * 256 + tid];
  __syncthreads();
  float s = fb[tid];
  const float* wr = fw + (long)tid * 256;
  for (int j = 0; j < 256; j += 4) {
    const float4 w4 = *(const float4*)(wr + j);
    s += cls[j] * w4.x + cls[j + 1] * w4.y + cls[j + 2] * w4.z + cls[j + 3] * w4.w;
  }
  float m = s;
#pragma unroll
  for (int msk = 32; msk; msk >>= 1) m += __shfl_xor(m, msk);
  if ((tid & 63) == 0) red[tid >> 6] = m;
  __syncthreads();
  m = (red[0] + red[1] + red[2] + red[3]) * (1.0f / 256.0f);
  const float d = s - m;
  float vs = d * d;
#pragma unroll
  for (int msk = 32; msk; msk >>= 1) vs += __shfl_xor(vs, msk);
  if ((tid & 63) == 0) red[4 + (tid >> 6)] = vs;
  __syncthreads();
  vs = red[4] + red[5] + red[6] + red[7];
  const float inv = rsqrtf(vs * (1.0f / 256.0f) + EPS);
  feats[b * 1024 + tid] = gelu_f(d * inv * lng[tid] + lnb[tid]);
}

__global__ void final_kernel(const float* __restrict__ c2, const float* __restrict__ w,
                             const float* __restrict__ bias, float* __restrict__ out) {
  const int tid = threadIdx.x;  // 128 threads: (b, n)
  const int b = tid >> 1, n = tid & 1;
  float s = bias[n];
  for (int j = 0; j < 256; ++j) s += c2[b * 256 + j] * w[n * 256 + j];
  out[b * 2 + n] = s;
}

extern "C" void kernel_launch(void* const* d_in, const int* in_sizes, int n_in, void* d_out,
                              int out_size, void* d_ws, size_t ws_size, hipStream_t stream) {
  const float* acc_data = (const float*)d_in[0];
  const float* conv1_w = (const float*)d_in[1];
  const float* conv1_b = (const float*)d_in[2];
  const float* bn1_g = (const float*)d_in[3];
  const float* bn1_b = (const float*)d_in[4];
  const float* conv2_w = (const float*)d_in[5];
  const float* conv2_b = (const float*)d_in[6];
  const float* bn2_g = (const float*)d_in[7];
  const float* bn2_b = (const float*)d_in[8];
  const float* sa_w1 = (const float*)d_in[9];
  const float* sa_b1 = (const float*)d_in[10];
  const float* sa_ln_g = (const float*)d_in[11];
  const float* sa_ln_b = (const float*)d_in[12];
  const float* sa_w2 = (const float*)d_in[13];
  const float* sa_b2 = (const float*)d_in[14];
  const float* ca_w1 = (const float*)d_in[15];
  const float* ca_b1 = (const float*)d_in[16];
  const float* ca_ln_g = (const float*)d_in[17];
  const float* ca_ln_b = (const float*)d_in[18];
  const float* ca_w2 = (const float*)d_in[19];
  const float* ca_b2 = (const float*)d_in[20];
  const float* cls_token = (const float*)d_in[21];
  const float* n1_g = (const float*)d_in[22];
  const float* n1_b = (const float*)d_in[23];
  const float* attn_in_w = (const float*)d_in[24];
  const float* attn_in_b = (const float*)d_in[25];
  const float* attn_out_w = (const float*)d_in[26];
  const float* attn_out_b = (const float*)d_in[27];
  const float* n2_g = (const float*)d_in[28];
  const float* n2_b = (const float*)d_in[29];
  const float* mlp_w1 = (const float*)d_in[30];
  const float* mlp_b1 = (const float*)d_in[31];
  const float* mlp_w2 = (const float*)d_in[32];
  const float* mlp_b2 = (const float*)d_in[33];
  const float* fus_w = (const float*)d_in[34];
  const float* fus_b = (const float*)d_in[35];
  const float* fus_ln_g = (const float*)d_in[36];
  const float* fus_ln_b = (const float*)d_in[37];
  const float* clf_ln_g = (const float*)d_in[38];
  const float* clf_ln_b = (const float*)d_in[39];
  const float* clf_w1 = (const float*)d_in[40];
  const float* clf_b1 = (const float*)d_in[41];
  const float* clf_w2 = (const float*)d_in[42];
  const float* clf_b2 = (const float*)d_in[43];

  // ---- workspace layout (bytes); total ~185 MB ----
  char* p = (char*)d_ws;
  char* RA = p; p += 68255744L;  // aliases: conv [X1P planes|X2] / QKVh / H planes
  float* X = (float*)p; p += 33619968L;                      // residual [32832,256] f32
  unsigned short* XNh = (unsigned short*)p; p += 16809984L;  // LN out planes (full batch)
  unsigned short* XNl = (unsigned short*)p; p += 16809984L;
  unsigned short* Oh = (unsigned short*)p; p += 16809984L;   // attn out bf16 (full batch)
  unsigned short* Vth = (unsigned short*)p; p += 17825792L;  // DEDICATED Vt [64,8,32,544]
  unsigned short* WQKVh = (unsigned short*)p; p += 1572864L;
  unsigned short* WQKVl = (unsigned short*)p; p += 1572864L;
  unsigned short* WAOh = (unsigned short*)p; p += 524288L;
  unsigned short* WAOl = (unsigned short*)p; p += 524288L;
  unsigned short* WM1h = (unsigned short*)p; p += 2097152L;
  unsigned short* WM1l = (unsigned short*)p; p += 2097152L;
  unsigned short* WM2h = (unsigned short*)p; p += 2097152L;
  unsigned short* WM2l = (unsigned short*)p; p += 2097152L;
  unsigned short* W2Eh = (unsigned short*)p; p += 393216L;
  unsigned short* W2El = (unsigned short*)p; p += 393216L;
  float* EFF = (float*)p;    p += 1024L * 4;
  float* CA = (float*)p;     p += 16384L * 4;
  float* GE = (float*)p;     p += 16384L * 4;
  float* TA = (float*)p;     p += 32768L * 4;
  float* GT = (float*)p;     p += 32768L * 4;
  float* FEATS = (float*)p;  p += 65536L * 4;
  float* CLN = (float*)p;    p += 65536L * 4;
  float* C2 = (float*)p;     p += 16384L * 4;
  float* PE = (float*)p;     p += 131072L * 4;

  // RA aliases
  unsigned short* X1Ph = (unsigned short*)RA;                 // conv: [64,514,256] hi
  unsigned short* X1Pl = (unsigned short*)(RA + 16842752L);   // lo
  float* X2 = (float*)(RA + 33685504L);                       // [32768,256] f32
  unsigned short* QKVh = (unsigned short*)RA;                 // FULL [32832,768] bf16
  unsigned short* Hh = (unsigned short*)RA;                   // per half [16416,1024] hi
  unsigned short* Hl = (unsigned short*)(RA + 33619968L);     // lo

  const int GBIG = 1 << 30;

  // weight prep
  prep_kernel<<<1, 256, 0, stream>>>(conv1_b, bn1_g, bn1_b, conv2_b, bn2_g, bn2_b, EFF);
  pe_kernel<<<512, 256, 0, stream>>>(PE);
  vtzero_kernel<<<2048, 256, 0, stream>>>(Vth);
  repack_w2_kernel<<<768, 256, 0, stream>>>(conv2_w, W2Eh, W2El);
  f2bf2_kernel<<<3072, 256, 0, stream>>>(attn_in_w, WQKVh, WQKVl, 786432);
  f2bf2_kernel<<<1024, 256, 0, stream>>>(attn_out_w, WAOh, WAOl, 262144);
  f2bf2_kernel<<<4096, 256, 0, stream>>>(mlp_w1, WM1h, WM1l, 1048576);
  f2bf2_kernel<<<4096, 256, 0, stream>>>(mlp_w2, WM2h, WM2l, 1048576);

  // conv encoder
  zeropad_kernel<<<64, 256, 0, stream>>>(X1Ph, X1Pl);
  conv1_kernel<<<dim3(8, 64), 256, 0, stream>>>(acc_data, conv1_w, EFF, X1Ph, X1Pl);
  bgemm3_kernel<0, false, true, true, true><<<dim3(2, 256), 256, 0, stream>>>(
      X1Ph, X1Pl, W2Eh, W2El, EFF + 768, EFF + 512, X2, nullptr, nullptr, nullptr,
      32768, 256, 768, 256, 768, 512, 514);
  // SE gates + sequence build (fp32)
  ca_mean_kernel<<<64, 256, 0, stream>>>(X2, CA);
  gate1_kernel<<<64, 256, 0, stream>>>(CA, sa_w1, sa_b1, sa_ln_g, sa_ln_b, sa_w2, sa_b2, GE);
  ta_mean_kernel<<<64, 256, 0, stream>>>(X2, GE, TA);
  gate2_kernel<<<64, 256, 0, stream>>>(TA, ca_w1, ca_b1, ca_ln_g, ca_ln_b, ca_w2, ca_b2, GT);
  xseq_kernel<<<dim3(513, 64), 256, 0, stream>>>(X2, GE, GT, cls_token, PE, X);

  for (int i = 0; i < 4; ++i) {
    ln256p_kernel<<<32832, 256, 0, stream>>>(X, n1_g + i * 256, n1_b + i * 256, XNh, XNl);
    // QKV full-batch GEMM with fused V-transpose (n-tiles 4..5 -> Vth)
    bgemm3_kernel<3, false, false, false, true><<<dim3(6, 257), 256, 0, stream>>>(
        XNh, XNl, WQKVh + (long)i * 196608, WQKVl + (long)i * 196608,
        attn_in_b + i * 768, nullptr, nullptr, QKVh, nullptr, Vth,
        32832, 768, 256, 256, 256, GBIG, 0);
    attn_bf16_kernel<<<4608, 256, 0, stream>>>(QKVh, Vth, Oh);
    bgemm3_kernel<0, true, false, false, false><<<dim3(2, 257), 256, 0, stream>>>(
        Oh, nullptr, WAOh + (long)i * 65536, WAOl + (long)i * 65536,
        attn_out_b + i * 256, nullptr, X, nullptr, nullptr, nullptr,
        32832, 256, 256, 256, 256, GBIG, 0);
    ln256p_kernel<<<32832, 256, 0, stream>>>(X, n2_g + i * 256, n2_b + i * 256, XNh, XNl);
    for (int half = 0; half < 2; ++half) {
      const long ho = (long)half * 16416 * 256;
      bgemm3_kernel<2, false, true, false, true><<<dim3(8, 129), 256, 0, stream>>>(
          XNh + ho, XNl + ho, WM1h + (long)i * 262144, WM1l + (long)i * 262144,
          mlp_b1 + i * 1024, nullptr, nullptr, Hh, Hl, nullptr,
          16416, 1024, 256, 256, 256, GBIG, 0);
      bgemm3_kernel<0, true, false, false, true><<<dim3(2, 129), 256, 0, stream>>>(
          Hh, Hl, WM2h + (long)i * 262144, WM2l + (long)i * 262144,
          mlp_b2 + i * 256, nullptr, X + ho, nullptr, nullptr, nullptr,
          16416, 256, 1024, 1024, 1024, GBIG, 0);
    }
    fushead_kernel<<<64, 256, 0, stream>>>(X, fus_w + (long)i * 65536, fus_b + i * 256,
                                           fus_ln_g + i * 256, fus_ln_b + i * 256,
                                           FEATS + i * 256);
  }
  ln_kernel<false><<<64, 256, 0, stream>>>(FEATS, clf_ln_g, clf_ln_b, CLN, 1024, 1024);
  gemm_kernel<false, true, false><<<dim3(1, 4), 256, 0, stream>>>(
      CLN, clf_w1, clf_b1, nullptr, C2, 64, 256, 1024, GBIG, 0, 0);
  final_kernel<<<1, 128, 0, stream>>>(C2, clf_w2, clf_b2, (float*)d_out);
}

// Round 11
// 2128.647 us; speedup vs baseline: 1.2077x; 1.2077x over previous
//
#include <hip/hip_runtime.h>
#include <math.h>

#define EPS 1e-5f

// Model dims: B=64, T=512, CIN=4, E=256, H=8, dh=32, S=513, L=4, NC=2.
// GEMMs: split-bf16 (hi+lo planes); conv2/QKV/MLP1 3-term, AO/MLP2 2-term.
// Attention: r8 kernel (LDS packed-P, XCD swizzle). V-transpose fused in QKV epilogue.

typedef __attribute__((ext_vector_type(8))) short short8;
typedef __attribute__((ext_vector_type(4))) float f32x4;

__device__ __forceinline__ float gelu_f(float x) {
  return 0.5f * x * (1.0f + erff(x * 0.70710678118654752440f));
}
__device__ __forceinline__ float sigmoid_f(float x) {
  return 1.0f / (1.0f + __expf(-x));
}
__device__ __forceinline__ unsigned short f2bf(float f) {
  unsigned int u = __float_as_uint(f);
  u = (u + 0x7FFFu + ((u >> 16) & 1u)) >> 16;
  return (unsigned short)u;
}
__device__ __forceinline__ float bf2f(unsigned short s) {
  return __uint_as_float(((unsigned int)s) << 16);
}
__device__ __forceinline__ float fexp2(float x) {
#if __has_builtin(__builtin_amdgcn_exp2f)
  return __builtin_amdgcn_exp2f(x);
#else
  return exp2f(x);
#endif
}
__device__ __forceinline__ void gl_lds16(const unsigned short* g, unsigned short* l) {
  __builtin_amdgcn_global_load_lds(
      (const __attribute__((address_space(1))) void*)g,
      (__attribute__((address_space(3))) void*)l, 16, 0, 0);
}

// ---------------- prep: fold conv bias + eval-BN into scale/shift ----------------
__global__ void prep_kernel(const float* __restrict__ c1b, const float* __restrict__ g1,
                            const float* __restrict__ b1, const float* __restrict__ c2b,
                            const float* __restrict__ g2, const float* __restrict__ b2,
                            float* __restrict__ eff) {
  const int t = threadIdx.x;
  const float bninv = rsqrtf(1.0f + EPS);
  const float e1g = bninv * g1[t];
  eff[t]       = e1g;
  eff[256 + t] = c1b[t] * e1g + b1[t];
  const float e2g = bninv * g2[t];
  eff[512 + t] = e2g;
  eff[768 + t] = c2b[t] * e2g + b2[t];
}

// positional embedding table [512][256]
__global__ void pe_kernel(float* __restrict__ pe) {
  const int t = blockIdx.x, e = threadIdx.x;
  const float freq = __expf((float)(e & ~1) * (-0.03597789207803197f));  // -ln(10000)/256
  const float ang = (float)t * freq;
  pe[t * 256 + e] = (e & 1) ? cosf(ang) : sinf(ang);
}

// zero Vt tail (k in [512,544)) once; k=512 is rewritten by QKV each layer
__global__ void vtzero_kernel(unsigned short* __restrict__ vth) {
  const int i = blockIdx.x * 256 + threadIdx.x;  // 16384 rows x 32
  if (i < 524288) vth[(long)(i >> 5) * 544 + 512 + (i & 31)] = 0;
}

// f32 -> bf16 hi+lo planes
__global__ void f2bf2_kernel(const float* __restrict__ src, unsigned short* __restrict__ dh,
                             unsigned short* __restrict__ dl, int n) {
  const int i = blockIdx.x * 256 + threadIdx.x;
  if (i < n) {
    const float x = src[i];
    const unsigned short h = f2bf(x);
    dh[i] = h;
    dl[i] = f2bf(x - bf2f(h));
  }
}

// w2e[e][s*256+ci] = conv2_w[e][ci][s]  (hi/lo), so conv2 == one K=768 GEMM
__global__ void repack_w2_kernel(const float* __restrict__ w2, unsigned short* __restrict__ w2h,
                                 unsigned short* __restrict__ w2l) {
  const int idx = blockIdx.x * 256 + threadIdx.x;  // 256*768
  const int e = idx / 768, rem = idx % 768;
  const int s = rem >> 8, ci = rem & 255;
  const float x = w2[e * 768 + ci * 3 + s];
  const unsigned short h = f2bf(x);
  w2h[idx] = h;
  w2l[idx] = f2bf(x - bf2f(h));
}

// zero padding rows of x1p planes [B][T+2][E]
__global__ void zeropad_kernel(unsigned short* __restrict__ xh, unsigned short* __restrict__ xl) {
  const int b = blockIdx.x, tid = threadIdx.x;
  const long r0 = ((long)b * 514) * 256 + tid;
  const long r1 = ((long)b * 514 + 513) * 256 + tid;
  xh[r0] = 0; xh[r1] = 0; xl[r0] = 0; xl[r1] = 0;
}

// ---------------- conv1 + BN + GELU -> x1p hi/lo planes (rows 1..T) ----------------
__global__ __launch_bounds__(256) void conv1_kernel(const float* __restrict__ in,
                                                    const float* __restrict__ w1,
                                                    const float* __restrict__ eff,
                                                    unsigned short* __restrict__ xh,
                                                    unsigned short* __restrict__ xl) {
  const int b = blockIdx.y, t0 = blockIdx.x * 64;
  const int tid = threadIdx.x;
  __shared__ float4 Ls[66];
  __shared__ float Wl[3072];
  if (tid < 66) {
    const int t = t0 - 1 + tid;
    float4 v = make_float4(0.f, 0.f, 0.f, 0.f);
    if (t >= 0 && t < 512) v = *(const float4*)(in + ((long)b * 512 + t) * 4);
    Ls[tid] = v;
  }
#pragma unroll
  for (int i = 0; i < 12; ++i) Wl[i * 256 + tid] = w1[i * 256 + tid];
  __syncthreads();
  float w[12];
#pragma unroll
  for (int i = 0; i < 12; ++i) w[i] = Wl[tid * 12 + i];  // [c*3+k]
  const float eg = eff[tid], eb = eff[256 + tid];
  const long ob = ((long)b * 514 + t0 + 1) * 256 + tid;
  for (int tl = 0; tl < 64; ++tl) {
    const float4 i0 = Ls[tl], i1 = Ls[tl + 1], i2 = Ls[tl + 2];
    float s = i0.x * w[0] + i1.x * w[1] + i2.x * w[2]
            + i0.y * w[3] + i1.y * w[4] + i2.y * w[5]
            + i0.z * w[6] + i1.z * w[7] + i2.z * w[8]
            + i0.w * w[9] + i1.w * w[10] + i2.w * w[11];
    const float y = gelu_f(s * eg + eb);
    const unsigned short h = f2bf(y);
    xh[ob + (long)tl * 256] = h;
    xl[ob + (long)tl * 256] = f2bf(y - bf2f(h));
  }
}

// ---------------- split-bf16 MFMA GEMM: C[M,N] = epi(A@W^T) ----------------
// Grid: n-tile = blockIdx.x, m-tile = blockIdx.y (A-tile shared by consecutive blocks).
// OUT: 0 = fp32 Cf; 1 = bf16 hi only; 2 = bf16 hi+lo; 3 = QKV fused (n<512: bf16 hi
// rows; n>=512: V written transposed into vth[b][h][d][kpad=544], k = row % 513).
template <int OUT, bool ACC, bool GELU_, bool SCALE, bool SPLITA>
__global__ __launch_bounds__(256) void bgemm3_kernel(
    const unsigned short* __restrict__ Ah, const unsigned short* __restrict__ Al,
    const unsigned short* __restrict__ Wh, const unsigned short* __restrict__ Wlo,
    const float* __restrict__ bias, const float* __restrict__ scale,
    float* __restrict__ Cf, unsigned short* __restrict__ Cbh, unsigned short* __restrict__ Cbl,
    unsigned short* __restrict__ vth,
    int M, int N, int K, int lda, int ldw, int groupT, int strideA) {
  __shared__ __align__(16) unsigned short SH[4][4096];  // Ah, Al, Wh, Wl tiles [128][32]
  const int tid = threadIdx.x;
  const int lane = tid & 63;
  const int m0 = blockIdx.y << 7, n0 = blockIdx.x << 7;
  const int g = m0 / groupT;
  const long abase = (long)(g * strideA + (m0 - g * groupT)) * lda;
  const int c0 = tid, c1 = tid + 256;
  const int r0c = c0 >> 2, k0c = (c0 & 3) << 3;
  const int r1c = c1 >> 2, k1c = (c1 & 3) << 3;
  const int mEdge = M - m0 - 1;
  const int r0a = r0c <= mEdge ? r0c : mEdge;
  const int r1a = r1c <= mEdge ? r1c : mEdge;
  const long offA0 = abase + (long)r0a * lda + k0c;
  const long offA1 = abase + (long)r1a * lda + k1c;
  const long offB0 = (long)(n0 + r0c) * ldw + k0c;
  const long offB1 = (long)(n0 + r1c) * ldw + k1c;
  unsigned short* s0 = &SH[0][c0 * 8];
  unsigned short* s1 = &SH[0][c1 * 8];
  const int fr = lane & 15, kg = lane >> 4;
  const int aoff = (((tid >> 7) << 6) + fr) * 32 + kg * 8;
  const int boff = ((((tid >> 6) & 1) << 6) + fr) * 32 + kg * 8;
  f32x4 acc[4][4];
#pragma unroll
  for (int i = 0; i < 4; ++i)
#pragma unroll
    for (int j = 0; j < 4; ++j) acc[i][j] = f32x4{0.f, 0.f, 0.f, 0.f};
  for (int k0 = 0; k0 < K; k0 += 32) {
    gl_lds16(Ah + offA0 + k0, s0);
    gl_lds16(Ah + offA1 + k0, s1);
    if (SPLITA) {
      gl_lds16(Al + offA0 + k0, s0 + 4096);
      gl_lds16(Al + offA1 + k0, s1 + 4096);
    }
    gl_lds16(Wh + offB0 + k0, s0 + 8192);
    gl_lds16(Wh + offB1 + k0, s1 + 8192);
    gl_lds16(Wlo + offB0 + k0, s0 + 12288);
    gl_lds16(Wlo + offB1 + k0, s1 + 12288);
    __syncthreads();
    short8 ah[4], al[4], bh[4], bl[4];
#pragma unroll
    for (int i = 0; i < 4; ++i) {
      ah[i] = *(const short8*)&SH[0][aoff + i * 512];
      if (SPLITA) al[i] = *(const short8*)&SH[1][aoff + i * 512];
    }
#pragma unroll
    for (int j = 0; j < 4; ++j) {
      bh[j] = *(const short8*)&SH[2][boff + j * 512];
      bl[j] = *(const short8*)&SH[3][boff + j * 512];
    }
#pragma unroll
    for (int i = 0; i < 4; ++i)
#pragma unroll
      for (int j = 0; j < 4; ++j) {
        acc[i][j] = __builtin_amdgcn_mfma_f32_16x16x32_bf16(ah[i], bl[j], acc[i][j], 0, 0, 0);
        if (SPLITA)
          acc[i][j] = __builtin_amdgcn_mfma_f32_16x16x32_bf16(al[i], bh[j], acc[i][j], 0, 0, 0);
        acc[i][j] = __builtin_amdgcn_mfma_f32_16x16x32_bf16(ah[i], bh[j], acc[i][j], 0, 0, 0);
      }
    __syncthreads();
  }
  const int colb = n0 + (((tid >> 6) & 1) << 6) + fr;
  float bj[4], sj[4];
#pragma unroll
  for (int j = 0; j < 4; ++j) {
    bj[j] = bias ? bias[colb + j * 16] : 0.f;
    sj[j] = SCALE ? scale[colb + j * 16] : 1.f;
  }
  const int rowb = m0 + ((tid >> 7) << 6) + kg * 4;
  if (OUT == 3 && n0 >= 512) {
    // V path: write transposed into vth[b][h][d][544]; rows = k (per batch of 513)
#pragma unroll
    for (int i = 0; i < 4; ++i) {
      const int row0 = rowb + i * 16;
      const int b0 = row0 / 513;
      const int sq0 = row0 - b0 * 513;
#pragma unroll
      for (int j = 0; j < 4; ++j) {
        const int col = colb + j * 16;
        const int hh = (col - 512) >> 5;
        const int dd = col & 31;
        ushort4 pk;
        pk.x = f2bf(acc[i][j][0] + bj[j]);
        pk.y = f2bf(acc[i][j][1] + bj[j]);
        pk.z = f2bf(acc[i][j][2] + bj[j]);
        pk.w = f2bf(acc[i][j][3] + bj[j]);
        if (row0 + 3 < M && sq0 <= 509) {
          *(ushort4*)(vth + (((long)(b0 * 8 + hh)) * 32 + dd) * 544 + sq0) = pk;
        } else {
          const unsigned short pr[4] = {pk.x, pk.y, pk.z, pk.w};
#pragma unroll
          for (int r = 0; r < 4; ++r) {
            const int row = row0 + r;
            if (row < M) {
              const int bb = row / 513, ss = row - bb * 513;
              vth[(((long)(bb * 8 + hh)) * 32 + dd) * 544 + ss] = pr[r];
            }
          }
        }
      }
    }
    return;
  }
#pragma unroll
  for (int i = 0; i < 4; ++i) {
#pragma unroll
    for (int r = 0; r < 4; ++r) {
      const int row = rowb + i * 16 + r;
      if (row < M) {
#pragma unroll
        for (int j = 0; j < 4; ++j) {
          const long off = (long)row * N + colb + j * 16;
          float v = acc[i][j][r];
          if (ACC) v += Cf[off];
          if (SCALE) v *= sj[j];
          v += bj[j];
          if (GELU_) v = gelu_f(v);
          if (OUT == 0) {
            Cf[off] = v;
          } else if (OUT == 2) {
            const unsigned short h = f2bf(v);
            Cbh[off] = h;
            Cbl[off] = f2bf(v - bf2f(h));
          } else {
            Cbh[off] = f2bf(v);
          }
        }
      }
    }
  }
}

// ---------------- fp32 GEMM (tiny tail mats only) ----------------
template <bool ACC, bool GELU_, bool SCALE>
__global__ __launch_bounds__(256) void gemm_kernel(const float* __restrict__ A,
                                                   const float* __restrict__ W,
                                                   const float* __restrict__ bias,
                                                   const float* __restrict__ scale,
                                                   float* __restrict__ C, int M, int N, int K,
                                                   int groupT, int strideA, int rowOff) {
  __shared__ float As[16][68];
  __shared__ float Bs[16][68];
  const int m0 = blockIdx.x * 64, n0 = blockIdx.y * 64;
  const int g = m0 / groupT, r0 = m0 - g * groupT;
  const float* Ab = A + (long)(g * strideA + r0 + rowOff) * K;
  const float* Wb = W + (long)n0 * K;
  const int tid = threadIdx.x;
  const int lr = tid >> 2;
  const int lk = (tid & 3) << 2;
  const int tr = (tid >> 4) << 2;
  const int tc = (tid & 15) << 2;
  float acc[4][4] = {{0.f}};
  for (int k0 = 0; k0 < K; k0 += 16) {
    const float4 a4 = *(const float4*)(Ab + (long)lr * K + k0 + lk);
    const float4 b4 = *(const float4*)(Wb + (long)lr * K + k0 + lk);
    __syncthreads();
    As[lk + 0][lr] = a4.x; As[lk + 1][lr] = a4.y; As[lk + 2][lr] = a4.z; As[lk + 3][lr] = a4.w;
    Bs[lk + 0][lr] = b4.x; Bs[lk + 1][lr] = b4.y; Bs[lk + 2][lr] = b4.z; Bs[lk + 3][lr] = b4.w;
    __syncthreads();
#pragma unroll
    for (int kk = 0; kk < 16; ++kk) {
      const float4 av = *(const float4*)&As[kk][tr];
      const float4 bv = *(const float4*)&Bs[kk][tc];
      acc[0][0] += av.x * bv.x; acc[0][1] += av.x * bv.y; acc[0][2] += av.x * bv.z; acc[0][3] += av.x * bv.w;
      acc[1][0] += av.y * bv.x; acc[1][1] += av.y * bv.y; acc[1][2] += av.y * bv.z; acc[1][3] += av.y * bv.w;
      acc[2][0] += av.z * bv.x; acc[2][1] += av.z * bv.y; acc[2][2] += av.z * bv.z; acc[2][3] += av.z * bv.w;
      acc[3][0] += av.w * bv.x; acc[3][1] += av.w * bv.y; acc[3][2] += av.w * bv.z; acc[3][3] += av.w * bv.w;
    }
  }
  float4 bb = make_float4(0.f, 0.f, 0.f, 0.f);
  if (bias) bb = *(const float4*)(bias + n0 + tc);
  float4 sv = make_float4(1.f, 1.f, 1.f, 1.f);
  if (SCALE) sv = *(const float4*)(scale + n0 + tc);
#pragma unroll
  for (int i = 0; i < 4; ++i) {
    float* cp = C + (long)(m0 + tr + i) * N + n0 + tc;
    float4 v = make_float4(acc[i][0], acc[i][1], acc[i][2], acc[i][3]);
    if (ACC) {
      const float4 c4 = *(const float4*)cp;
      v.x += c4.x; v.y += c4.y; v.z += c4.z; v.w += c4.w;
    }
    if (SCALE) { v.x *= sv.x; v.y *= sv.y; v.z *= sv.z; v.w *= sv.w; }
    v.x += bb.x; v.y += bb.y; v.z += bb.z; v.w += bb.w;
    if (GELU_) { v.x = gelu_f(v.x); v.y = gelu_f(v.y); v.z = gelu_f(v.z); v.w = gelu_f(v.w); }
    *(float4*)cp = v;
  }
}

// ---------------- SE gates (fp32) ----------------
__global__ __launch_bounds__(256) void ca_mean_kernel(const float* __restrict__ x2,
                                                      float* __restrict__ ca) {
  const int b = blockIdx.x, tid = threadIdx.x;
  float s = 0.f;
  for (int t = 0; t < 512; ++t) s += x2[((long)(b * 512 + t)) * 256 + tid];
  ca[b * 256 + tid] = s * (1.0f / 512.0f);
}

__global__ __launch_bounds__(256) void gate1_kernel(const float* __restrict__ ca,
    const float* __restrict__ w1, const float* __restrict__ b1,
    const float* __restrict__ lng, const float* __restrict__ lnb,
    const float* __restrict__ w2, const float* __restrict__ b2, float* __restrict__ ge) {
  const int b = blockIdx.x, tid = threadIdx.x;
  __shared__ float caL[256];
  __shared__ float zL[32];
  caL[tid] = ca[b * 256 + tid];
  __syncthreads();
  if (tid < 32) {
    float s = b1[tid];
    for (int e = 0; e < 256; ++e) s += caL[e] * w1[tid * 256 + e];
    float mean = s;
    for (int msk = 1; msk < 32; msk <<= 1) mean += __shfl_xor(mean, msk);
    mean *= (1.0f / 32.0f);
    const float d = s - mean;
    float v = d * d;
    for (int msk = 1; msk < 32; msk <<= 1) v += __shfl_xor(v, msk);
    v *= (1.0f / 32.0f);
    zL[tid] = gelu_f(d * rsqrtf(v + EPS) * lng[tid] + lnb[tid]);
  }
  __syncthreads();
  float a = b2[tid];
#pragma unroll
  for (int j = 0; j < 32; ++j) a += zL[j] * w2[tid * 32 + j];
  ge[b * 256 + tid] = sigmoid_f(a);
}

__global__ __launch_bounds__(256) void ta_mean_kernel(const float* __restrict__ x2,
                                                      const float* __restrict__ ge,
                                                      float* __restrict__ ta) {
  const int b = blockIdx.x, tid = threadIdx.x;
  const int w = tid >> 6, lane = tid & 63;
  const float4 g4 = *(const float4*)(ge + b * 256 + lane * 4);
  for (int t = w; t < 512; t += 4) {
    const float4 x4 = *(const float4*)(x2 + ((long)(b * 512 + t)) * 256 + lane * 4);
    float s = x4.x * g4.x + x4.y * g4.y + x4.z * g4.z + x4.w * g4.w;
#pragma unroll
    for (int msk = 32; msk; msk >>= 1) s += __shfl_xor(s, msk);
    if (lane == 0) ta[b * 512 + t] = s * (1.0f / 256.0f);
  }
}

__global__ __launch_bounds__(256) void gate2_kernel(const float* __restrict__ ta,
    const float* __restrict__ w1, const float* __restrict__ b1,
    const float* __restrict__ lng, const float* __restrict__ lnb,
    const float* __restrict__ w2, const float* __restrict__ b2, float* __restrict__ gt) {
  const int b = blockIdx.x, tid = threadIdx.x;
  __shared__ float taL[512];
  __shared__ float zL[64];
  taL[tid] = ta[b * 512 + tid];
  taL[256 + tid] = ta[b * 512 + 256 + tid];
  __syncthreads();
  if (tid < 64) {
    float s = b1[tid];
    for (int t = 0; t < 512; ++t) s += taL[t] * w1[tid * 512 + t];
    float mean = s;
    for (int msk = 1; msk < 64; msk <<= 1) mean += __shfl_xor(mean, msk);
    mean *= (1.0f / 64.0f);
    const float d = s - mean;
    float v = d * d;
    for (int msk = 1; msk < 64; msk <<= 1) v += __shfl_xor(v, msk);
    v *= (1.0f / 64.0f);
    zL[tid] = gelu_f(d * rsqrtf(v + EPS) * lng[tid] + lnb[tid]);
  }
  __syncthreads();
#pragma unroll
  for (int r = 0; r < 2; ++r) {
    const int t = tid + r * 256;
    float a = b2[t];
    for (int j = 0; j < 64; ++j) a += zL[j] * w2[t * 64 + j];
    gt[b * 512 + t] = sigmoid_f(a);
  }
}

// x_seq build (fp32 residual stream); PE precomputed
__global__ __launch_bounds__(256) void xseq_kernel(const float* __restrict__ x2,
    const float* __restrict__ ge, const float* __restrict__ gt,
    const float* __restrict__ cls, const float* __restrict__ pe, float* __restrict__ x) {
  const int srow = blockIdx.x, b = blockIdx.y, e = threadIdx.x;
  float* outp = x + ((long)(b * 513 + srow)) * 256 + e;
  if (srow == 0) { *outp = cls[e]; return; }
  const int t = srow - 1;
  *outp = x2[((long)(b * 512 + t)) * 256 + e] * ge[b * 256 + e] * gt[b * 512 + t]
        + pe[t * 256 + e];
}

// ---------------- LayerNorm fp32 -> fp32 (tail) ----------------
template <bool GELU_>
__global__ __launch_bounds__(256) void ln_kernel(const float* __restrict__ in,
                                                 const float* __restrict__ g,
                                                 const float* __restrict__ bta,
                                                 float* __restrict__ out, int D, int ostride) {
  const int row = blockIdx.x, tid = threadIdx.x;
  __shared__ float red[8];
  const float* x = in + (long)row * D;
  const int nv = D >> 8;
  float xv[4];
  float s = 0.f;
  for (int i = 0; i < nv; ++i) { xv[i] = x[tid + (i << 8)]; s += xv[i]; }
#pragma unroll
  for (int msk = 32; msk; msk >>= 1) s += __shfl_xor(s, msk);
  if ((tid & 63) == 0) red[tid >> 6] = s;
  __syncthreads();
  s = red[0] + red[1] + red[2] + red[3];
  const float mean = s / (float)D;
  float vs = 0.f;
  for (int i = 0; i < nv; ++i) { const float d = xv[i] - mean; vs += d * d; }
#pragma unroll
  for (int msk = 32; msk; msk >>= 1) vs += __shfl_xor(vs, msk);
  if ((tid & 63) == 0) red[4 + (tid >> 6)] = vs;
  __syncthreads();
  vs = red[4] + red[5] + red[6] + red[7];
  const float inv = rsqrtf(vs / (float)D + EPS);
  for (int i = 0; i < nv; ++i) {
    const int col = tid + (i << 8);
    float y = (xv[i] - mean) * inv * g[col] + bta[col];
    if (GELU_) y = gelu_f(y);
    out[(long)row * ostride + col] = y;
  }
}

// ---------------- LayerNorm D=256, fp32 -> bf16 hi/lo planes ----------------
__global__ __launch_bounds__(256) void ln256p_kernel(const float* __restrict__ in,
                                                     const float* __restrict__ g,
                                                     const float* __restrict__ bta,
                                                     unsigned short* __restrict__ oh,
                                                     unsigned short* __restrict__ ol) {
  const int row = blockIdx.x, tid = threadIdx.x;
  __shared__ float red[8];
  const float xv = in[(long)row * 256 + tid];
  float s = xv;
#pragma unroll
  for (int msk = 32; msk; msk >>= 1) s += __shfl_xor(s, msk);
  if ((tid & 63) == 0) red[tid >> 6] = s;
  __syncthreads();
  s = red[0] + red[1] + red[2] + red[3];
  const float mean = s * (1.0f / 256.0f);
  const float d = xv - mean;
  float vs = d * d;
#pragma unroll
  for (int msk = 32; msk; msk >>= 1) vs += __shfl_xor(vs, msk);
  if ((tid & 63) == 0) red[4 + (tid >> 6)] = vs;
  __syncthreads();
  vs = red[4] + red[5] + red[6] + red[7];
  const float inv = rsqrtf(vs * (1.0f / 256.0f) + EPS);
  const float y = d * inv * g[tid] + bta[tid];
  const unsigned short h = f2bf(y);
  oh[(long)row * 256 + tid] = h;
  ol[(long)row * 256 + tid] = f2bf(y - bf2f(h));
}

// ---------------- MFMA flash attention (r8 version — proven optimum) ----------------
// 1D grid 4608: flat = h + 8*(qb + 9*b) => blocks sharing (b,h) K/V are 8 apart
// (same XCD under round-robin). 256 thr = 4 waves; wave owns 16 q rows; k-chunk 32.
// Keys interleaved per half (key = k0 + 2*l16 + hh) so the P pair packs to one u32.
// Main loop: 16 chunks, no masks/clamps. Tail handles key 512 alone.
__global__ __launch_bounds__(256) void attn_bf16_kernel(
    const unsigned short* __restrict__ qkvh, const unsigned short* __restrict__ vth,
    unsigned short* __restrict__ oh) {
  const int flat = blockIdx.x;
  const int h = flat & 7;
  const int t_ = flat >> 3;
  const int qb = t_ % 9;
  const int b = t_ / 9;
  const int tid = threadIdx.x;
  const int wave = tid >> 6, lane = tid & 63;
  const int quad = lane >> 4, l16 = lane & 15;
  __shared__ __align__(16) unsigned short PhS[4][16][40];
  unsigned short (*Ph)[40] = PhS[wave];

  const long base = (long)b * 513;
  const int qrow = qb * 64 + wave * 16 + l16;
  const int qsafe = qrow < 513 ? qrow : 512;
  const short8 qh8 = *(const short8*)(qkvh + (base + qsafe) * 768 + h * 32 + quad * 8);
  const long vtb = ((long)(b * 8 + h)) * 32 * 544;

  const unsigned short* kp0 = qkvh + (base + 2 * l16) * 768 + 256 + h * 32 + quad * 8;
  const unsigned short* kp1 = kp0 + 768;
  const unsigned short* vp0 = vth + vtb + (long)l16 * 544 + quad * 8;
  const unsigned short* vp1 = vth + vtb + (long)(16 + l16) * 544 + quad * 8;
  unsigned int* php = (unsigned int*)&Ph[quad * 4][2 * l16];  // packed pair, row stride 20 uint
  const short8* prd = (const short8*)&Ph[l16][quad * 8];

  float lrow[4] = {0.f, 0.f, 0.f, 0.f};
  const f32x4 zf = {0.f, 0.f, 0.f, 0.f};
  f32x4 oacc[2] = {zf, zf};
  const float sf2 = 0.25506994362f;  // log2(e)/sqrt(32)

  for (int c = 0; c < 16; ++c) {
    const f32x4 sc0 = __builtin_amdgcn_mfma_f32_16x16x32_bf16(qh8, *(const short8*)kp0, zf, 0, 0, 0);
    const f32x4 sc1 = __builtin_amdgcn_mfma_f32_16x16x32_bf16(qh8, *(const short8*)kp1, zf, 0, 0, 0);
    kp0 += 32 * 768;
    kp1 += 32 * 768;
#pragma unroll
    for (int r = 0; r < 4; ++r) {
      const float p0 = fexp2(sc0[r] * sf2);
      const float p1 = fexp2(sc1[r] * sf2);
      const unsigned int pk = ((unsigned int)f2bf(p1) << 16) | f2bf(p0);
      php[r * 20] = pk;
      lrow[r] += __uint_as_float(pk << 16) + __uint_as_float(pk & 0xFFFF0000u);
    }
    asm volatile("" ::: "memory");  // DS writes stay before DS reads (same-wave order)
    const short8 ph8 = *prd;
    oacc[0] = __builtin_amdgcn_mfma_f32_16x16x32_bf16(ph8, *(const short8*)vp0, oacc[0], 0, 0, 0);
    oacc[1] = __builtin_amdgcn_mfma_f32_16x16x32_bf16(ph8, *(const short8*)vp1, oacc[1], 0, 0, 0);
    vp0 += 32;
    vp1 += 32;
    asm volatile("" ::: "memory");  // next chunk's DS writes stay after these reads
  }
  // tail: key 512 only (all lanes load key-512 row; only l16==0 col is real)
  {
    const short8 k512 = *(const short8*)(qkvh + (base + 512) * 768 + 256 + h * 32 + quad * 8);
    const f32x4 sc0 = __builtin_amdgcn_mfma_f32_16x16x32_bf16(qh8, k512, zf, 0, 0, 0);
#pragma unroll
    for (int r = 0; r < 4; ++r) {
      const float p0 = (l16 == 0) ? fexp2(sc0[r] * sf2) : 0.f;
      const unsigned int pk = (unsigned int)f2bf(p0);
      php[r * 20] = pk;
      lrow[r] += __uint_as_float(pk << 16);
    }
    asm volatile("" ::: "memory");
    const short8 ph8 = *prd;
    oacc[0] = __builtin_amdgcn_mfma_f32_16x16x32_bf16(ph8, *(const short8*)vp0, oacc[0], 0, 0, 0);
    oacc[1] = __builtin_amdgcn_mfma_f32_16x16x32_bf16(ph8, *(const short8*)vp1, oacc[1], 0, 0, 0);
  }
#pragma unroll
  for (int r = 0; r < 4; ++r) {
    lrow[r] += __shfl_xor(lrow[r], 1);
    lrow[r] += __shfl_xor(lrow[r], 2);
    lrow[r] += __shfl_xor(lrow[r], 4);
    lrow[r] += __shfl_xor(lrow[r], 8);
  }
  const int orow0 = qb * 64 + wave * 16 + quad * 4;
#pragma unroll
  for (int r = 0; r < 4; ++r) {
    const int qr = orow0 + r;
    if (qr < 513) {
      const float inv = 1.0f / lrow[r];
      oh[(base + qr) * 256 + h * 32 + l16] = f2bf(oacc[0][r] * inv);
      oh[(base + qr) * 256 + h * 32 + 16 + l16] = f2bf(oacc[1][r] * inv);
    }
  }
}

// ---------------- fused fusion head: f = GELU(LN(CLS @ fus_w^T + fus_b)) ----------------
__global__ __launch_bounds__(256) void fushead_kernel(const float* __restrict__ x,
    const float* __restrict__ fw, const float* __restrict__ fb,
    const float* __restrict__ lng, const float* __restrict__ lnb,
    float* __restrict__ feats) {
  const int b = blockIdx.x, tid = threadIdx.x;
  __shared__ float cls[256];
  __shared__ float red[8];
  cls[tid] = x[(long)b * 513 * 256 + tid];
  __syncthreads();
  float s = fb[tid];
  const float* wr = fw + (long)tid * 256;
  for (int j = 0; j < 256; j += 4) {
    const float4 w4 = *(const float4*)(wr + j);
    s += cls[j] * w4.x + cls[j + 1] * w4.y + cls[j + 2] * w4.z + cls[j + 3] * w4.w;
  }
  float m = s;
#pragma unroll
  for (int msk = 32; msk; msk >>= 1) m += __shfl_xor(m, msk);
  if ((tid & 63) == 0) red[tid >> 6] = m;
  __syncthreads();
  m = (red[0] + red[1] + red[2] + red[3]) * (1.0f / 256.0f);
  const float d = s - m;
  float vs = d * d;
#pragma unroll
  for (int msk = 32; msk; msk >>= 1) vs += __shfl_xor(vs, msk);
  if ((tid & 63) == 0) red[4 + (tid >> 6)] = vs;
  __syncthreads();
  vs = red[4] + red[5] + red[6] + red[7];
  const float inv = rsqrtf(vs * (1.0f / 256.0f) + EPS);
  feats[b * 1024 + tid] = gelu_f(d * inv * lng[tid] + lnb[tid]);
}

__global__ void final_kernel(const float* __restrict__ c2, const float* __restrict__ w,
                             const float* __restrict__ bias, float* __restrict__ out) {
  const int tid = threadIdx.x;  // 128 threads: (b, n)
  const int b = tid >> 1, n = tid & 1;
  float s = bias[n];
  for (int j = 0; j < 256; ++j) s += c2[b * 256 + j] * w[n * 256 + j];
  out[b * 2 + n] = s;
}

extern "C" void kernel_launch(void* const* d_in, const int* in_sizes, int n_in, void* d_out,
                              int out_size, void* d_ws, size_t ws_size, hipStream_t stream) {
  const float* acc_data = (const float*)d_in[0];
  const float* conv1_w = (const float*)d_in[1];
  const float* conv1_b = (const float*)d_in[2];
  const float* bn1_g = (const float*)d_in[3];
  const float* bn1_b = (const float*)d_in[4];
  const float* conv2_w = (const float*)d_in[5];
  const float* conv2_b = (const float*)d_in[6];
  const float* bn2_g = (const float*)d_in[7];
  const float* bn2_b = (const float*)d_in[8];
  const float* sa_w1 = (const float*)d_in[9];
  const float* sa_b1 = (const float*)d_in[10];
  const float* sa_ln_g = (const float*)d_in[11];
  const float* sa_ln_b = (const float*)d_in[12];
  const float* sa_w2 = (const float*)d_in[13];
  const float* sa_b2 = (const float*)d_in[14];
  const float* ca_w1 = (const float*)d_in[15];
  const float* ca_b1 = (const float*)d_in[16];
  const float* ca_ln_g = (const float*)d_in[17];
  const float* ca_ln_b = (const float*)d_in[18];
  const float* ca_w2 = (const float*)d_in[19];
  const float* ca_b2 = (const float*)d_in[20];
  const float* cls_token = (const float*)d_in[21];
  const float* n1_g = (const float*)d_in[22];
  const float* n1_b = (const float*)d_in[23];
  const float* attn_in_w = (const float*)d_in[24];
  const float* attn_in_b = (const float*)d_in[25];
  const float* attn_out_w = (const float*)d_in[26];
  const float* attn_out_b = (const float*)d_in[27];
  const float* n2_g = (const float*)d_in[28];
  const float* n2_b = (const float*)d_in[29];
  const float* mlp_w1 = (const float*)d_in[30];
  const float* mlp_b1 = (const float*)d_in[31];
  const float* mlp_w2 = (const float*)d_in[32];
  const float* mlp_b2 = (const float*)d_in[33];
  const float* fus_w = (const float*)d_in[34];
  const float* fus_b = (const float*)d_in[35];
  const float* fus_ln_g = (const float*)d_in[36];
  const float* fus_ln_b = (const float*)d_in[37];
  const float* clf_ln_g = (const float*)d_in[38];
  const float* clf_ln_b = (const float*)d_in[39];
  const float* clf_w1 = (const float*)d_in[40];
  const float* clf_b1 = (const float*)d_in[41];
  const float* clf_w2 = (const float*)d_in[42];
  const float* clf_b2 = (const float*)d_in[43];

  // ---- workspace layout (bytes); total ~185 MB ----
  char* p = (char*)d_ws;
  char* RA = p; p += 68255744L;  // aliases: conv [X1P planes|X2] / QKVh / H (hi, full)
  float* X = (float*)p; p += 33619968L;                      // residual [32832,256] f32
  unsigned short* XNh = (unsigned short*)p; p += 16809984L;  // LN out planes (full batch)
  unsigned short* XNl = (unsigned short*)p; p += 16809984L;
  unsigned short* Oh = (unsigned short*)p; p += 16809984L;   // attn out bf16 (full batch)
  unsigned short* Vth = (unsigned short*)p; p += 17825792L;  // DEDICATED Vt [64,8,32,544]
  unsigned short* WQKVh = (unsigned short*)p; p += 1572864L;
  unsigned short* WQKVl = (unsigned short*)p; p += 1572864L;
  unsigned short* WAOh = (unsigned short*)p; p += 524288L;
  unsigned short* WAOl = (unsigned short*)p; p += 524288L;
  unsigned short* WM1h = (unsigned short*)p; p += 2097152L;
  unsigned short* WM1l = (unsigned short*)p; p += 2097152L;
  unsigned short* WM2h = (unsigned short*)p; p += 2097152L;
  unsigned short* WM2l = (unsigned short*)p; p += 2097152L;
  unsigned short* W2Eh = (unsigned short*)p; p += 393216L;
  unsigned short* W2El = (unsigned short*)p; p += 393216L;
  float* EFF = (float*)p;    p += 1024L * 4;
  float* CA = (float*)p;     p += 16384L * 4;
  float* GE = (float*)p;     p += 16384L * 4;
  float* TA = (float*)p;     p += 32768L * 4;
  float* GT = (float*)p;     p += 32768L * 4;
  float* FEATS = (float*)p;  p += 65536L * 4;
  float* CLN = (float*)p;    p += 65536L * 4;
  float* C2 = (float*)p;     p += 16384L * 4;
  float* PE = (float*)p;     p += 131072L * 4;

  // RA aliases (sequential within a layer: QKVh consumed by attn before Hh written)
  unsigned short* X1Ph = (unsigned short*)RA;                 // conv: [64,514,256] hi
  unsigned short* X1Pl = (unsigned short*)(RA + 16842752L);   // lo
  float* X2 = (float*)(RA + 33685504L);                       // [32768,256] f32
  unsigned short* QKVh = (unsigned short*)RA;                 // FULL [32832,768] bf16
  unsigned short* Hh = (unsigned short*)RA;                   // FULL [32832,1024] hi only

  const int GBIG = 1 << 30;

  // weight prep
  prep_kernel<<<1, 256, 0, stream>>>(conv1_b, bn1_g, bn1_b, conv2_b, bn2_g, bn2_b, EFF);
  pe_kernel<<<512, 256, 0, stream>>>(PE);
  vtzero_kernel<<<2048, 256, 0, stream>>>(Vth);
  repack_w2_kernel<<<768, 256, 0, stream>>>(conv2_w, W2Eh, W2El);
  f2bf2_kernel<<<3072, 256, 0, stream>>>(attn_in_w, WQKVh, WQKVl, 786432);
  f2bf2_kernel<<<1024, 256, 0, stream>>>(attn_out_w, WAOh, WAOl, 262144);
  f2bf2_kernel<<<4096, 256, 0, stream>>>(mlp_w1, WM1h, WM1l, 1048576);
  f2bf2_kernel<<<4096, 256, 0, stream>>>(mlp_w2, WM2h, WM2l, 1048576);

  // conv encoder
  zeropad_kernel<<<64, 256, 0, stream>>>(X1Ph, X1Pl);
  conv1_kernel<<<dim3(8, 64), 256, 0, stream>>>(acc_data, conv1_w, EFF, X1Ph, X1Pl);
  bgemm3_kernel<0, false, true, true, true><<<dim3(2, 256), 256, 0, stream>>>(
      X1Ph, X1Pl, W2Eh, W2El, EFF + 768, EFF + 512, X2, nullptr, nullptr, nullptr,
      32768, 256, 768, 256, 768, 512, 514);
  // SE gates + sequence build (fp32)
  ca_mean_kernel<<<64, 256, 0, stream>>>(X2, CA);
  gate1_kernel<<<64, 256, 0, stream>>>(CA, sa_w1, sa_b1, sa_ln_g, sa_ln_b, sa_w2, sa_b2, GE);
  ta_mean_kernel<<<64, 256, 0, stream>>>(X2, GE, TA);
  gate2_kernel<<<64, 256, 0, stream>>>(TA, ca_w1, ca_b1, ca_ln_g, ca_ln_b, ca_w2, ca_b2, GT);
  xseq_kernel<<<dim3(513, 64), 256, 0, stream>>>(X2, GE, GT, cls_token, PE, X);

  for (int i = 0; i < 4; ++i) {
    ln256p_kernel<<<32832, 256, 0, stream>>>(X, n1_g + i * 256, n1_b + i * 256, XNh, XNl);
    // QKV full-batch GEMM with fused V-transpose (n-tiles 4..5 -> Vth)
    bgemm3_kernel<3, false, false, false, true><<<dim3(6, 257), 256, 0, stream>>>(
        XNh, XNl, WQKVh + (long)i * 196608, WQKVl + (long)i * 196608,
        attn_in_b + i * 768, nullptr, nullptr, QKVh, nullptr, Vth,
        32832, 768, 256, 256, 256, GBIG, 0);
    attn_bf16_kernel<<<4608, 256, 0, stream>>>(QKVh, Vth, Oh);
    bgemm3_kernel<0, true, false, false, false><<<dim3(2, 257), 256, 0, stream>>>(
        Oh, nullptr, WAOh + (long)i * 65536, WAOl + (long)i * 65536,
        attn_out_b + i * 256, nullptr, X, nullptr, nullptr, nullptr,
        32832, 256, 256, 256, 256, GBIG, 0);
    ln256p_kernel<<<32832, 256, 0, stream>>>(X, n2_g + i * 256, n2_b + i * 256, XNh, XNl);
    // MLP full-batch; H hi-only (overwrites QKVh in RA — attn already consumed it)
    bgemm3_kernel<1, false, true, false, true><<<dim3(8, 257), 256, 0, stream>>>(
        XNh, XNl, WM1h + (long)i * 262144, WM1l + (long)i * 262144,
        mlp_b1 + i * 1024, nullptr, nullptr, Hh, nullptr, nullptr,
        32832, 1024, 256, 256, 256, GBIG, 0);
    bgemm3_kernel<0, true, false, false, false><<<dim3(2, 257), 256, 0, stream>>>(
        Hh, nullptr, WM2h + (long)i * 262144, WM2l + (long)i * 262144,
        mlp_b2 + i * 256, nullptr, X, nullptr, nullptr, nullptr,
        32832, 256, 1024, 1024, 1024, GBIG, 0);
    fushead_kernel<<<64, 256, 0, stream>>>(X, fus_w + (long)i * 65536, fus_b + i * 256,
                                           fus_ln_g + i * 256, fus_ln_b + i * 256,
                                           FEATS + i * 256);
  }
  ln_kernel<false><<<64, 256, 0, stream>>>(FEATS, clf_ln_g, clf_ln_b, CLN, 1024, 1024);
  gemm_kernel<false, true, false><<<dim3(1, 4), 256, 0, stream>>>(
      CLN, clf_w1, clf_b1, nullptr, C2, 64, 256, 1024, GBIG, 0, 0);
  final_kernel<<<1, 128, 0, stream>>>(C2, clf_w2, clf_b2, (float*)d_out);
}

// Round 12
// 2033.612 us; speedup vs baseline: 1.2641x; 1.0467x over previous
//
#include <hip/hip_runtime.h>
#include <math.h>

#define EPS 1e-5f

// Model dims: B=64, T=512, CIN=4, E=256, H=8, dh=32, S=513, L=4, NC=2.
// GEMMs: split-bf16 (hi+lo planes); conv2/QKV/MLP1 3-term, AO/MLP2 2-term.
// bgemm3 grid: 1D XCD swizzle — all n-tiles of an m-tile on ONE XCD (A-tile L2-resident).
// Attention: r8 kernel (LDS packed-P, XCD swizzle). V-transpose fused in QKV epilogue.

typedef __attribute__((ext_vector_type(8))) short short8;
typedef __attribute__((ext_vector_type(4))) float f32x4;

__device__ __forceinline__ float gelu_f(float x) {
  return 0.5f * x * (1.0f + erff(x * 0.70710678118654752440f));
}
__device__ __forceinline__ float sigmoid_f(float x) {
  return 1.0f / (1.0f + __expf(-x));
}
__device__ __forceinline__ unsigned short f2bf(float f) {
  unsigned int u = __float_as_uint(f);
  u = (u + 0x7FFFu + ((u >> 16) & 1u)) >> 16;
  return (unsigned short)u;
}
__device__ __forceinline__ float bf2f(unsigned short s) {
  return __uint_as_float(((unsigned int)s) << 16);
}
__device__ __forceinline__ float fexp2(float x) {
#if __has_builtin(__builtin_amdgcn_exp2f)
  return __builtin_amdgcn_exp2f(x);
#else
  return exp2f(x);
#endif
}
__device__ __forceinline__ void gl_lds16(const unsigned short* g, unsigned short* l) {
  __builtin_amdgcn_global_load_lds(
      (const __attribute__((address_space(1))) void*)g,
      (__attribute__((address_space(3))) void*)l, 16, 0, 0);
}

// ---------------- prep: fold conv bias + eval-BN into scale/shift ----------------
__global__ void prep_kernel(const float* __restrict__ c1b, const float* __restrict__ g1,
                            const float* __restrict__ b1, const float* __restrict__ c2b,
                            const float* __restrict__ g2, const float* __restrict__ b2,
                            float* __restrict__ eff) {
  const int t = threadIdx.x;
  const float bninv = rsqrtf(1.0f + EPS);
  const float e1g = bninv * g1[t];
  eff[t]       = e1g;
  eff[256 + t] = c1b[t] * e1g + b1[t];
  const float e2g = bninv * g2[t];
  eff[512 + t] = e2g;
  eff[768 + t] = c2b[t] * e2g + b2[t];
}

// positional embedding table [512][256]
__global__ void pe_kernel(float* __restrict__ pe) {
  const int t = blockIdx.x, e = threadIdx.x;
  const float freq = __expf((float)(e & ~1) * (-0.03597789207803197f));  // -ln(10000)/256
  const float ang = (float)t * freq;
  pe[t * 256 + e] = (e & 1) ? cosf(ang) : sinf(ang);
}

// zero Vt tail (k in [512,544)) once; k=512 is rewritten by QKV each layer
__global__ void vtzero_kernel(unsigned short* __restrict__ vth) {
  const int i = blockIdx.x * 256 + threadIdx.x;  // 16384 rows x 32
  if (i < 524288) vth[(long)(i >> 5) * 544 + 512 + (i & 31)] = 0;
}

// f32 -> bf16 hi+lo planes
__global__ void f2bf2_kernel(const float* __restrict__ src, unsigned short* __restrict__ dh,
                             unsigned short* __restrict__ dl, int n) {
  const int i = blockIdx.x * 256 + threadIdx.x;
  if (i < n) {
    const float x = src[i];
    const unsigned short h = f2bf(x);
    dh[i] = h;
    dl[i] = f2bf(x - bf2f(h));
  }
}

// w2e[e][s*256+ci] = conv2_w[e][ci][s]  (hi/lo), so conv2 == one K=768 GEMM
__global__ void repack_w2_kernel(const float* __restrict__ w2, unsigned short* __restrict__ w2h,
                                 unsigned short* __restrict__ w2l) {
  const int idx = blockIdx.x * 256 + threadIdx.x;  // 256*768
  const int e = idx / 768, rem = idx % 768;
  const int s = rem >> 8, ci = rem & 255;
  const float x = w2[e * 768 + ci * 3 + s];
  const unsigned short h = f2bf(x);
  w2h[idx] = h;
  w2l[idx] = f2bf(x - bf2f(h));
}

// zero padding rows of x1p planes [B][T+2][E]
__global__ void zeropad_kernel(unsigned short* __restrict__ xh, unsigned short* __restrict__ xl) {
  const int b = blockIdx.x, tid = threadIdx.x;
  const long r0 = ((long)b * 514) * 256 + tid;
  const long r1 = ((long)b * 514 + 513) * 256 + tid;
  xh[r0] = 0; xh[r1] = 0; xl[r0] = 0; xl[r1] = 0;
}

// ---------------- conv1 + BN + GELU -> x1p hi/lo planes (rows 1..T) ----------------
__global__ __launch_bounds__(256) void conv1_kernel(const float* __restrict__ in,
                                                    const float* __restrict__ w1,
                                                    const float* __restrict__ eff,
                                                    unsigned short* __restrict__ xh,
                                                    unsigned short* __restrict__ xl) {
  const int b = blockIdx.y, t0 = blockIdx.x * 64;
  const int tid = threadIdx.x;
  __shared__ float4 Ls[66];
  __shared__ float Wl[3072];
  if (tid < 66) {
    const int t = t0 - 1 + tid;
    float4 v = make_float4(0.f, 0.f, 0.f, 0.f);
    if (t >= 0 && t < 512) v = *(const float4*)(in + ((long)b * 512 + t) * 4);
    Ls[tid] = v;
  }
#pragma unroll
  for (int i = 0; i < 12; ++i) Wl[i * 256 + tid] = w1[i * 256 + tid];
  __syncthreads();
  float w[12];
#pragma unroll
  for (int i = 0; i < 12; ++i) w[i] = Wl[tid * 12 + i];  // [c*3+k]
  const float eg = eff[tid], eb = eff[256 + tid];
  const long ob = ((long)b * 514 + t0 + 1) * 256 + tid;
  for (int tl = 0; tl < 64; ++tl) {
    const float4 i0 = Ls[tl], i1 = Ls[tl + 1], i2 = Ls[tl + 2];
    float s = i0.x * w[0] + i1.x * w[1] + i2.x * w[2]
            + i0.y * w[3] + i1.y * w[4] + i2.y * w[5]
            + i0.z * w[6] + i1.z * w[7] + i2.z * w[8]
            + i0.w * w[9] + i1.w * w[10] + i2.w * w[11];
    const float y = gelu_f(s * eg + eb);
    const unsigned short h = f2bf(y);
    xh[ob + (long)tl * 256] = h;
    xl[ob + (long)tl * 256] = f2bf(y - bf2f(h));
  }
}

// ---------------- split-bf16 MFMA GEMM: C[M,N] = epi(A@W^T) ----------------
// 1D grid = NT * ceil(MT/8) * 8, XCD swizzle: group = flat/(8*NT),
// mt = 8*group + flat%8, nt = (flat%(8*NT))/8  =>  XCD(flat%8) == mt%8:
// all n-tiles of one m-tile land on one XCD, 8 apart in dispatch order.
// OUT: 0 = fp32 Cf; 1 = bf16 hi only; 2 = bf16 hi+lo; 3 = QKV fused (n<512: bf16 hi
// rows; n>=512: V written transposed into vth[b][h][d][kpad=544], k = row % 513).
template <int OUT, bool ACC, bool GELU_, bool SCALE, bool SPLITA>
__global__ __launch_bounds__(256) void bgemm3_kernel(
    const unsigned short* __restrict__ Ah, const unsigned short* __restrict__ Al,
    const unsigned short* __restrict__ Wh, const unsigned short* __restrict__ Wlo,
    const float* __restrict__ bias, const float* __restrict__ scale,
    float* __restrict__ Cf, unsigned short* __restrict__ Cbh, unsigned short* __restrict__ Cbl,
    unsigned short* __restrict__ vth,
    int M, int N, int K, int lda, int ldw, int groupT, int strideA, int NT, int MT) {
  __shared__ __align__(16) unsigned short SH[4][4096];  // Ah, Al, Wh, Wl tiles [128][32]
  const int flat = blockIdx.x;
  const int grpsz = NT << 3;
  const int grp = flat / grpsz;
  const int rres = flat - grp * grpsz;
  const int mt = (grp << 3) + (rres & 7);
  const int nt = rres >> 3;
  if (mt >= MT) return;
  const int tid = threadIdx.x;
  const int lane = tid & 63;
  const int m0 = mt << 7, n0 = nt << 7;
  const int g = m0 / groupT;
  const long abase = (long)(g * strideA + (m0 - g * groupT)) * lda;
  const int c0 = tid, c1 = tid + 256;
  const int r0c = c0 >> 2, k0c = (c0 & 3) << 3;
  const int r1c = c1 >> 2, k1c = (c1 & 3) << 3;
  const int mEdge = M - m0 - 1;
  const int r0a = r0c <= mEdge ? r0c : mEdge;
  const int r1a = r1c <= mEdge ? r1c : mEdge;
  const long offA0 = abase + (long)r0a * lda + k0c;
  const long offA1 = abase + (long)r1a * lda + k1c;
  const long offB0 = (long)(n0 + r0c) * ldw + k0c;
  const long offB1 = (long)(n0 + r1c) * ldw + k1c;
  unsigned short* s0 = &SH[0][c0 * 8];
  unsigned short* s1 = &SH[0][c1 * 8];
  const int fr = lane & 15, kg = lane >> 4;
  const int aoff = (((tid >> 7) << 6) + fr) * 32 + kg * 8;
  const int boff = ((((tid >> 6) & 1) << 6) + fr) * 32 + kg * 8;
  f32x4 acc[4][4];
#pragma unroll
  for (int i = 0; i < 4; ++i)
#pragma unroll
    for (int j = 0; j < 4; ++j) acc[i][j] = f32x4{0.f, 0.f, 0.f, 0.f};
  for (int k0 = 0; k0 < K; k0 += 32) {
    gl_lds16(Ah + offA0 + k0, s0);
    gl_lds16(Ah + offA1 + k0, s1);
    if (SPLITA) {
      gl_lds16(Al + offA0 + k0, s0 + 4096);
      gl_lds16(Al + offA1 + k0, s1 + 4096);
    }
    gl_lds16(Wh + offB0 + k0, s0 + 8192);
    gl_lds16(Wh + offB1 + k0, s1 + 8192);
    gl_lds16(Wlo + offB0 + k0, s0 + 12288);
    gl_lds16(Wlo + offB1 + k0, s1 + 12288);
    __syncthreads();
    short8 ah[4], al[4], bh[4], bl[4];
#pragma unroll
    for (int i = 0; i < 4; ++i) {
      ah[i] = *(const short8*)&SH[0][aoff + i * 512];
      if (SPLITA) al[i] = *(const short8*)&SH[1][aoff + i * 512];
    }
#pragma unroll
    for (int j = 0; j < 4; ++j) {
      bh[j] = *(const short8*)&SH[2][boff + j * 512];
      bl[j] = *(const short8*)&SH[3][boff + j * 512];
    }
#pragma unroll
    for (int i = 0; i < 4; ++i)
#pragma unroll
      for (int j = 0; j < 4; ++j) {
        acc[i][j] = __builtin_amdgcn_mfma_f32_16x16x32_bf16(ah[i], bl[j], acc[i][j], 0, 0, 0);
        if (SPLITA)
          acc[i][j] = __builtin_amdgcn_mfma_f32_16x16x32_bf16(al[i], bh[j], acc[i][j], 0, 0, 0);
        acc[i][j] = __builtin_amdgcn_mfma_f32_16x16x32_bf16(ah[i], bh[j], acc[i][j], 0, 0, 0);
      }
    __syncthreads();
  }
  const int colb = n0 + (((tid >> 6) & 1) << 6) + fr;
  float bj[4], sj[4];
#pragma unroll
  for (int j = 0; j < 4; ++j) {
    bj[j] = bias ? bias[colb + j * 16] : 0.f;
    sj[j] = SCALE ? scale[colb + j * 16] : 1.f;
  }
  const int rowb = m0 + ((tid >> 7) << 6) + kg * 4;
  if (OUT == 3 && n0 >= 512) {
    // V path: write transposed into vth[b][h][d][544]; rows = k (per batch of 513)
#pragma unroll
    for (int i = 0; i < 4; ++i) {
      const int row0 = rowb + i * 16;
      const int b0 = row0 / 513;
      const int sq0 = row0 - b0 * 513;
#pragma unroll
      for (int j = 0; j < 4; ++j) {
        const int col = colb + j * 16;
        const int hh = (col - 512) >> 5;
        const int dd = col & 31;
        ushort4 pk;
        pk.x = f2bf(acc[i][j][0] + bj[j]);
        pk.y = f2bf(acc[i][j][1] + bj[j]);
        pk.z = f2bf(acc[i][j][2] + bj[j]);
        pk.w = f2bf(acc[i][j][3] + bj[j]);
        if (row0 + 3 < M && sq0 <= 509) {
          *(ushort4*)(vth + (((long)(b0 * 8 + hh)) * 32 + dd) * 544 + sq0) = pk;
        } else {
          const unsigned short pr[4] = {pk.x, pk.y, pk.z, pk.w};
#pragma unroll
          for (int r = 0; r < 4; ++r) {
            const int row = row0 + r;
            if (row < M) {
              const int bb = row / 513, ss = row - bb * 513;
              vth[(((long)(bb * 8 + hh)) * 32 + dd) * 544 + ss] = pr[r];
            }
          }
        }
      }
    }
    return;
  }
#pragma unroll
  for (int i = 0; i < 4; ++i) {
#pragma unroll
    for (int r = 0; r < 4; ++r) {
      const int row = rowb + i * 16 + r;
      if (row < M) {
#pragma unroll
        for (int j = 0; j < 4; ++j) {
          const long off = (long)row * N + colb + j * 16;
          float v = acc[i][j][r];
          if (ACC) v += Cf[off];
          if (SCALE) v *= sj[j];
          v += bj[j];
          if (GELU_) v = gelu_f(v);
          if (OUT == 0) {
            Cf[off] = v;
          } else if (OUT == 2) {
            const unsigned short h = f2bf(v);
            Cbh[off] = h;
            Cbl[off] = f2bf(v - bf2f(h));
          } else {
            Cbh[off] = f2bf(v);
          }
        }
      }
    }
  }
}

// ---------------- fp32 GEMM (tiny tail mats only) ----------------
template <bool ACC, bool GELU_, bool SCALE>
__global__ __launch_bounds__(256) void gemm_kernel(const float* __restrict__ A,
                                                   const float* __restrict__ W,
                                                   const float* __restrict__ bias,
                                                   const float* __restrict__ scale,
                                                   float* __restrict__ C, int M, int N, int K,
                                                   int groupT, int strideA, int rowOff) {
  __shared__ float As[16][68];
  __shared__ float Bs[16][68];
  const int m0 = blockIdx.x * 64, n0 = blockIdx.y * 64;
  const int g = m0 / groupT, r0 = m0 - g * groupT;
  const float* Ab = A + (long)(g * strideA + r0 + rowOff) * K;
  const float* Wb = W + (long)n0 * K;
  const int tid = threadIdx.x;
  const int lr = tid >> 2;
  const int lk = (tid & 3) << 2;
  const int tr = (tid >> 4) << 2;
  const int tc = (tid & 15) << 2;
  float acc[4][4] = {{0.f}};
  for (int k0 = 0; k0 < K; k0 += 16) {
    const float4 a4 = *(const float4*)(Ab + (long)lr * K + k0 + lk);
    const float4 b4 = *(const float4*)(Wb + (long)lr * K + k0 + lk);
    __syncthreads();
    As[lk + 0][lr] = a4.x; As[lk + 1][lr] = a4.y; As[lk + 2][lr] = a4.z; As[lk + 3][lr] = a4.w;
    Bs[lk + 0][lr] = b4.x; Bs[lk + 1][lr] = b4.y; Bs[lk + 2][lr] = b4.z; Bs[lk + 3][lr] = b4.w;
    __syncthreads();
#pragma unroll
    for (int kk = 0; kk < 16; ++kk) {
      const float4 av = *(const float4*)&As[kk][tr];
      const float4 bv = *(const float4*)&Bs[kk][tc];
      acc[0][0] += av.x * bv.x; acc[0][1] += av.x * bv.y; acc[0][2] += av.x * bv.z; acc[0][3] += av.x * bv.w;
      acc[1][0] += av.y * bv.x; acc[1][1] += av.y * bv.y; acc[1][2] += av.y * bv.z; acc[1][3] += av.y * bv.w;
      acc[2][0] += av.z * bv.x; acc[2][1] += av.z * bv.y; acc[2][2] += av.z * bv.z; acc[2][3] += av.z * bv.w;
      acc[3][0] += av.w * bv.x; acc[3][1] += av.w * bv.y; acc[3][2] += av.w * bv.z; acc[3][3] += av.w * bv.w;
    }
  }
  float4 bb = make_float4(0.f, 0.f, 0.f, 0.f);
  if (bias) bb = *(const float4*)(bias + n0 + tc);
  float4 sv = make_float4(1.f, 1.f, 1.f, 1.f);
  if (SCALE) sv = *(const float4*)(scale + n0 + tc);
#pragma unroll
  for (int i = 0; i < 4; ++i) {
    float* cp = C + (long)(m0 + tr + i) * N + n0 + tc;
    float4 v = make_float4(acc[i][0], acc[i][1], acc[i][2], acc[i][3]);
    if (ACC) {
      const float4 c4 = *(const float4*)cp;
      v.x += c4.x; v.y += c4.y; v.z += c4.z; v.w += c4.w;
    }
    if (SCALE) { v.x *= sv.x; v.y *= sv.y; v.z *= sv.z; v.w *= sv.w; }
    v.x += bb.x; v.y += bb.y; v.z += bb.z; v.w += bb.w;
    if (GELU_) { v.x = gelu_f(v.x); v.y = gelu_f(v.y); v.z = gelu_f(v.z); v.w = gelu_f(v.w); }
    *(float4*)cp = v;
  }
}

// ---------------- SE gates (fp32) ----------------
__global__ __launch_bounds__(256) void ca_mean_kernel(const float* __restrict__ x2,
                                                      float* __restrict__ ca) {
  const int b = blockIdx.x, tid = threadIdx.x;
  float s = 0.f;
  for (int t = 0; t < 512; ++t) s += x2[((long)(b * 512 + t)) * 256 + tid];
  ca[b * 256 + tid] = s * (1.0f / 512.0f);
}

__global__ __launch_bounds__(256) void gate1_kernel(const float* __restrict__ ca,
    const float* __restrict__ w1, const float* __restrict__ b1,
    const float* __restrict__ lng, const float* __restrict__ lnb,
    const float* __restrict__ w2, const float* __restrict__ b2, float* __restrict__ ge) {
  const int b = blockIdx.x, tid = threadIdx.x;
  __shared__ float caL[256];
  __shared__ float zL[32];
  caL[tid] = ca[b * 256 + tid];
  __syncthreads();
  if (tid < 32) {
    float s = b1[tid];
    for (int e = 0; e < 256; ++e) s += caL[e] * w1[tid * 256 + e];
    float mean = s;
    for (int msk = 1; msk < 32; msk <<= 1) mean += __shfl_xor(mean, msk);
    mean *= (1.0f / 32.0f);
    const float d = s - mean;
    float v = d * d;
    for (int msk = 1; msk < 32; msk <<= 1) v += __shfl_xor(v, msk);
    v *= (1.0f / 32.0f);
    zL[tid] = gelu_f(d * rsqrtf(v + EPS) * lng[tid] + lnb[tid]);
  }
  __syncthreads();
  float a = b2[tid];
#pragma unroll
  for (int j = 0; j < 32; ++j) a += zL[j] * w2[tid * 32 + j];
  ge[b * 256 + tid] = sigmoid_f(a);
}

__global__ __launch_bounds__(256) void ta_mean_kernel(const float* __restrict__ x2,
                                                      const float* __restrict__ ge,
                                                      float* __restrict__ ta) {
  const int b = blockIdx.x, tid = threadIdx.x;
  const int w = tid >> 6, lane = tid & 63;
  const float4 g4 = *(const float4*)(ge + b * 256 + lane * 4);
  for (int t = w; t < 512; t += 4) {
    const float4 x4 = *(const float4*)(x2 + ((long)(b * 512 + t)) * 256 + lane * 4);
    float s = x4.x * g4.x + x4.y * g4.y + x4.z * g4.z + x4.w * g4.w;
#pragma unroll
    for (int msk = 32; msk; msk >>= 1) s += __shfl_xor(s, msk);
    if (lane == 0) ta[b * 512 + t] = s * (1.0f / 256.0f);
  }
}

__global__ __launch_bounds__(256) void gate2_kernel(const float* __restrict__ ta,
    const float* __restrict__ w1, const float* __restrict__ b1,
    const float* __restrict__ lng, const float* __restrict__ lnb,
    const float* __restrict__ w2, const float* __restrict__ b2, float* __restrict__ gt) {
  const int b = blockIdx.x, tid = threadIdx.x;
  __shared__ float taL[512];
  __shared__ float zL[64];
  taL[tid] = ta[b * 512 + tid];
  taL[256 + tid] = ta[b * 512 + 256 + tid];
  __syncthreads();
  if (tid < 64) {
    float s = b1[tid];
    for (int t = 0; t < 512; ++t) s += taL[t] * w1[tid * 512 + t];
    float mean = s;
    for (int msk = 1; msk < 64; msk <<= 1) mean += __shfl_xor(mean, msk);
    mean *= (1.0f / 64.0f);
    const float d = s - mean;
    float v = d * d;
    for (int msk = 1; msk < 64; msk <<= 1) v += __shfl_xor(v, msk);
    v *= (1.0f / 64.0f);
    zL[tid] = gelu_f(d * rsqrtf(v + EPS) * lng[tid] + lnb[tid]);
  }
  __syncthreads();
#pragma unroll
  for (int r = 0; r < 2; ++r) {
    const int t = tid + r * 256;
    float a = b2[t];
    for (int j = 0; j < 64; ++j) a += zL[j] * w2[t * 64 + j];
    gt[b * 512 + t] = sigmoid_f(a);
  }
}

// x_seq build (fp32 residual stream); PE precomputed
__global__ __launch_bounds__(256) void xseq_kernel(const float* __restrict__ x2,
    const float* __restrict__ ge, const float* __restrict__ gt,
    const float* __restrict__ cls, const float* __restrict__ pe, float* __restrict__ x) {
  const int srow = blockIdx.x, b = blockIdx.y, e = threadIdx.x;
  float* outp = x + ((long)(b * 513 + srow)) * 256 + e;
  if (srow == 0) { *outp = cls[e]; return; }
  const int t = srow - 1;
  *outp = x2[((long)(b * 512 + t)) * 256 + e] * ge[b * 256 + e] * gt[b * 512 + t]
        + pe[t * 256 + e];
}

// ---------------- LayerNorm fp32 -> fp32 (tail) ----------------
template <bool GELU_>
__global__ __launch_bounds__(256) void ln_kernel(const float* __restrict__ in,
                                                 const float* __restrict__ g,
                                                 const float* __restrict__ bta,
                                                 float* __restrict__ out, int D, int ostride) {
  const int row = blockIdx.x, tid = threadIdx.x;
  __shared__ float red[8];
  const float* x = in + (long)row * D;
  const int nv = D >> 8;
  float xv[4];
  float s = 0.f;
  for (int i = 0; i < nv; ++i) { xv[i] = x[tid + (i << 8)]; s += xv[i]; }
#pragma unroll
  for (int msk = 32; msk; msk >>= 1) s += __shfl_xor(s, msk);
  if ((tid & 63) == 0) red[tid >> 6] = s;
  __syncthreads();
  s = red[0] + red[1] + red[2] + red[3];
  const float mean = s / (float)D;
  float vs = 0.f;
  for (int i = 0; i < nv; ++i) { const float d = xv[i] - mean; vs += d * d; }
#pragma unroll
  for (int msk = 32; msk; msk >>= 1) vs += __shfl_xor(vs, msk);
  if ((tid & 63) == 0) red[4 + (tid >> 6)] = vs;
  __syncthreads();
  vs = red[4] + red[5] + red[6] + red[7];
  const float inv = rsqrtf(vs / (float)D + EPS);
  for (int i = 0; i < nv; ++i) {
    const int col = tid + (i << 8);
    float y = (xv[i] - mean) * inv * g[col] + bta[col];
    if (GELU_) y = gelu_f(y);
    out[(long)row * ostride + col] = y;
  }
}

// ---------------- LayerNorm D=256, fp32 -> bf16 hi/lo planes ----------------
__global__ __launch_bounds__(256) void ln256p_kernel(const float* __restrict__ in,
                                                     const float* __restrict__ g,
                                                     const float* __restrict__ bta,
                                                     unsigned short* __restrict__ oh,
                                                     unsigned short* __restrict__ ol) {
  const int row = blockIdx.x, tid = threadIdx.x;
  __shared__ float red[8];
  const float xv = in[(long)row * 256 + tid];
  float s = xv;
#pragma unroll
  for (int msk = 32; msk; msk >>= 1) s += __shfl_xor(s, msk);
  if ((tid & 63) == 0) red[tid >> 6] = s;
  __syncthreads();
  s = red[0] + red[1] + red[2] + red[3];
  const float mean = s * (1.0f / 256.0f);
  const float d = xv - mean;
  float vs = d * d;
#pragma unroll
  for (int msk = 32; msk; msk >>= 1) vs += __shfl_xor(vs, msk);
  if ((tid & 63) == 0) red[4 + (tid >> 6)] = vs;
  __syncthreads();
  vs = red[4] + red[5] + red[6] + red[7];
  const float inv = rsqrtf(vs * (1.0f / 256.0f) + EPS);
  const float y = d * inv * g[tid] + bta[tid];
  const unsigned short h = f2bf(y);
  oh[(long)row * 256 + tid] = h;
  ol[(long)row * 256 + tid] = f2bf(y - bf2f(h));
}

// ---------------- MFMA flash attention (r8 version — proven optimum) ----------------
__global__ __launch_bounds__(256) void attn_bf16_kernel(
    const unsigned short* __restrict__ qkvh, const unsigned short* __restrict__ vth,
    unsigned short* __restrict__ oh) {
  const int flat = blockIdx.x;
  const int h = flat & 7;
  const int t_ = flat >> 3;
  const int qb = t_ % 9;
  const int b = t_ / 9;
  const int tid = threadIdx.x;
  const int wave = tid >> 6, lane = tid & 63;
  const int quad = lane >> 4, l16 = lane & 15;
  __shared__ __align__(16) unsigned short PhS[4][16][40];
  unsigned short (*Ph)[40] = PhS[wave];

  const long base = (long)b * 513;
  const int qrow = qb * 64 + wave * 16 + l16;
  const int qsafe = qrow < 513 ? qrow : 512;
  const short8 qh8 = *(const short8*)(qkvh + (base + qsafe) * 768 + h * 32 + quad * 8);
  const long vtb = ((long)(b * 8 + h)) * 32 * 544;

  const unsigned short* kp0 = qkvh + (base + 2 * l16) * 768 + 256 + h * 32 + quad * 8;
  const unsigned short* kp1 = kp0 + 768;
  const unsigned short* vp0 = vth + vtb + (long)l16 * 544 + quad * 8;
  const unsigned short* vp1 = vth + vtb + (long)(16 + l16) * 544 + quad * 8;
  unsigned int* php = (unsigned int*)&Ph[quad * 4][2 * l16];  // packed pair, row stride 20 uint
  const short8* prd = (const short8*)&Ph[l16][quad * 8];

  float lrow[4] = {0.f, 0.f, 0.f, 0.f};
  const f32x4 zf = {0.f, 0.f, 0.f, 0.f};
  f32x4 oacc[2] = {zf, zf};
  const float sf2 = 0.25506994362f;  // log2(e)/sqrt(32)

  for (int c = 0; c < 16; ++c) {
    const f32x4 sc0 = __builtin_amdgcn_mfma_f32_16x16x32_bf16(qh8, *(const short8*)kp0, zf, 0, 0, 0);
    const f32x4 sc1 = __builtin_amdgcn_mfma_f32_16x16x32_bf16(qh8, *(const short8*)kp1, zf, 0, 0, 0);
    kp0 += 32 * 768;
    kp1 += 32 * 768;
#pragma unroll
    for (int r = 0; r < 4; ++r) {
      const float p0 = fexp2(sc0[r] * sf2);
      const float p1 = fexp2(sc1[r] * sf2);
      const unsigned int pk = ((unsigned int)f2bf(p1) << 16) | f2bf(p0);
      php[r * 20] = pk;
      lrow[r] += __uint_as_float(pk << 16) + __uint_as_float(pk & 0xFFFF0000u);
    }
    asm volatile("" ::: "memory");  // DS writes stay before DS reads (same-wave order)
    const short8 ph8 = *prd;
    oacc[0] = __builtin_amdgcn_mfma_f32_16x16x32_bf16(ph8, *(const short8*)vp0, oacc[0], 0, 0, 0);
    oacc[1] = __builtin_amdgcn_mfma_f32_16x16x32_bf16(ph8, *(const short8*)vp1, oacc[1], 0, 0, 0);
    vp0 += 32;
    vp1 += 32;
    asm volatile("" ::: "memory");  // next chunk's DS writes stay after these reads
  }
  // tail: key 512 only (all lanes load key-512 row; only l16==0 col is real)
  {
    const short8 k512 = *(const short8*)(qkvh + (base + 512) * 768 + 256 + h * 32 + quad * 8);
    const f32x4 sc0 = __builtin_amdgcn_mfma_f32_16x16x32_bf16(qh8, k512, zf, 0, 0, 0);
#pragma unroll
    for (int r = 0; r < 4; ++r) {
      const float p0 = (l16 == 0) ? fexp2(sc0[r] * sf2) : 0.f;
      const unsigned int pk = (unsigned int)f2bf(p0);
      php[r * 20] = pk;
      lrow[r] += __uint_as_float(pk << 16);
    }
    asm volatile("" ::: "memory");
    const short8 ph8 = *prd;
    oacc[0] = __builtin_amdgcn_mfma_f32_16x16x32_bf16(ph8, *(const short8*)vp0, oacc[0], 0, 0, 0);
    oacc[1] = __builtin_amdgcn_mfma_f32_16x16x32_bf16(ph8, *(const short8*)vp1, oacc[1], 0, 0, 0);
  }
#pragma unroll
  for (int r = 0; r < 4; ++r) {
    lrow[r] += __shfl_xor(lrow[r], 1);
    lrow[r] += __shfl_xor(lrow[r], 2);
    lrow[r] += __shfl_xor(lrow[r], 4);
    lrow[r] += __shfl_xor(lrow[r], 8);
  }
  const int orow0 = qb * 64 + wave * 16 + quad * 4;
#pragma unroll
  for (int r = 0; r < 4; ++r) {
    const int qr = orow0 + r;
    if (qr < 513) {
      const float inv = 1.0f / lrow[r];
      oh[(base + qr) * 256 + h * 32 + l16] = f2bf(oacc[0][r] * inv);
      oh[(base + qr) * 256 + h * 32 + 16 + l16] = f2bf(oacc[1][r] * inv);
    }
  }
}

// ---------------- fused fusion head: f = GELU(LN(CLS @ fus_w^T + fus_b)) ----------------
__global__ __launch_bounds__(256) void fushead_kernel(const float* __restrict__ x,
    const float* __restrict__ fw, const float* __restrict__ fb,
    const float* __restrict__ lng, const float* __restrict__ lnb,
    float* __restrict__ feats) {
  const int b = blockIdx.x, tid = threadIdx.x;
  __shared__ float cls[256];
  __shared__ float red[8];
  cls[tid] = x[(long)b * 513 * 256 + tid];
  __syncthreads();
  float s = fb[tid];
  const float* wr = fw + (long)tid * 256;
  for (int j = 0; j < 256; j += 4) {
    const float4 w4 = *(const float4*)(wr + j);
    s += cls[j] * w4.x + cls[j + 1] * w4.y + cls[j + 2] * w4.z + cls[j + 3] * w4.w;
  }
  float m = s;
#pragma unroll
  for (int msk = 32; msk; msk >>= 1) m += __shfl_xor(m, msk);
  if ((tid & 63) == 0) red[tid >> 6] = m;
  __syncthreads();
  m = (red[0] + red[1] + red[2] + red[3]) * (1.0f / 256.0f);
  const float d = s - m;
  float vs = d * d;
#pragma unroll
  for (int msk = 32; msk; msk >>= 1) vs += __shfl_xor(vs, msk);
  if ((tid & 63) == 0) red[4 + (tid >> 6)] = vs;
  __syncthreads();
  vs = red[4] + red[5] + red[6] + red[7];
  const float inv = rsqrtf(vs * (1.0f / 256.0f) + EPS);
  feats[b * 1024 + tid] = gelu_f(d * inv * lng[tid] + lnb[tid]);
}

__global__ void final_kernel(const float* __restrict__ c2, const float* __restrict__ w,
                             const float* __restrict__ bias, float* __restrict__ out) {
  const int tid = threadIdx.x;  // 128 threads: (b, n)
  const int b = tid >> 1, n = tid & 1;
  float s = bias[n];
  for (int j = 0; j < 256; ++j) s += c2[b * 256 + j] * w[n * 256 + j];
  out[b * 2 + n] = s;
}

extern "C" void kernel_launch(void* const* d_in, const int* in_sizes, int n_in, void* d_out,
                              int out_size, void* d_ws, size_t ws_size, hipStream_t stream) {
  const float* acc_data = (const float*)d_in[0];
  const float* conv1_w = (const float*)d_in[1];
  const float* conv1_b = (const float*)d_in[2];
  const float* bn1_g = (const float*)d_in[3];
  const float* bn1_b = (const float*)d_in[4];
  const float* conv2_w = (const float*)d_in[5];
  const float* conv2_b = (const float*)d_in[6];
  const float* bn2_g = (const float*)d_in[7];
  const float* bn2_b = (const float*)d_in[8];
  const float* sa_w1 = (const float*)d_in[9];
  const float* sa_b1 = (const float*)d_in[10];
  const float* sa_ln_g = (const float*)d_in[11];
  const float* sa_ln_b = (const float*)d_in[12];
  const float* sa_w2 = (const float*)d_in[13];
  const float* sa_b2 = (const float*)d_in[14];
  const float* ca_w1 = (const float*)d_in[15];
  const float* ca_b1 = (const float*)d_in[16];
  const float* ca_ln_g = (const float*)d_in[17];
  const float* ca_ln_b = (const float*)d_in[18];
  const float* ca_w2 = (const float*)d_in[19];
  const float* ca_b2 = (const float*)d_in[20];
  const float* cls_token = (const float*)d_in[21];
  const float* n1_g = (const float*)d_in[22];
  const float* n1_b = (const float*)d_in[23];
  const float* attn_in_w = (const float*)d_in[24];
  const float* attn_in_b = (const float*)d_in[25];
  const float* attn_out_w = (const float*)d_in[26];
  const float* attn_out_b = (const float*)d_in[27];
  const float* n2_g = (const float*)d_in[28];
  const float* n2_b = (const float*)d_in[29];
  const float* mlp_w1 = (const float*)d_in[30];
  const float* mlp_b1 = (const float*)d_in[31];
  const float* mlp_w2 = (const float*)d_in[32];
  const float* mlp_b2 = (const float*)d_in[33];
  const float* fus_w = (const float*)d_in[34];
  const float* fus_b = (const float*)d_in[35];
  const float* fus_ln_g = (const float*)d_in[36];
  const float* fus_ln_b = (const float*)d_in[37];
  const float* clf_ln_g = (const float*)d_in[38];
  const float* clf_ln_b = (const float*)d_in[39];
  const float* clf_w1 = (const float*)d_in[40];
  const float* clf_b1 = (const float*)d_in[41];
  const float* clf_w2 = (const float*)d_in[42];
  const float* clf_b2 = (const float*)d_in[43];

  // ---- workspace layout (bytes); total ~185 MB ----
  char* p = (char*)d_ws;
  char* RA = p; p += 68255744L;  // aliases: conv [X1P planes|X2] / QKVh / H (hi, full)
  float* X = (float*)p; p += 33619968L;                      // residual [32832,256] f32
  unsigned short* XNh = (unsigned short*)p; p += 16809984L;  // LN out planes (full batch)
  unsigned short* XNl = (unsigned short*)p; p += 16809984L;
  unsigned short* Oh = (unsigned short*)p; p += 16809984L;   // attn out bf16 (full batch)
  unsigned short* Vth = (unsigned short*)p; p += 17825792L;  // DEDICATED Vt [64,8,32,544]
  unsigned short* WQKVh = (unsigned short*)p; p += 1572864L;
  unsigned short* WQKVl = (unsigned short*)p; p += 1572864L;
  unsigned short* WAOh = (unsigned short*)p; p += 524288L;
  unsigned short* WAOl = (unsigned short*)p; p += 524288L;
  unsigned short* WM1h = (unsigned short*)p; p += 2097152L;
  unsigned short* WM1l = (unsigned short*)p; p += 2097152L;
  unsigned short* WM2h = (unsigned short*)p; p += 2097152L;
  unsigned short* WM2l = (unsigned short*)p; p += 2097152L;
  unsigned short* W2Eh = (unsigned short*)p; p += 393216L;
  unsigned short* W2El = (unsigned short*)p; p += 393216L;
  float* EFF = (float*)p;    p += 1024L * 4;
  float* CA = (float*)p;     p += 16384L * 4;
  float* GE = (float*)p;     p += 16384L * 4;
  float* TA = (float*)p;     p += 32768L * 4;
  float* GT = (float*)p;     p += 32768L * 4;
  float* FEATS = (float*)p;  p += 65536L * 4;
  float* CLN = (float*)p;    p += 65536L * 4;
  float* C2 = (float*)p;     p += 16384L * 4;
  float* PE = (float*)p;     p += 131072L * 4;

  // RA aliases (sequential within a layer: QKVh consumed by attn before Hh written)
  unsigned short* X1Ph = (unsigned short*)RA;                 // conv: [64,514,256] hi
  unsigned short* X1Pl = (unsigned short*)(RA + 16842752L);   // lo
  float* X2 = (float*)(RA + 33685504L);                       // [32768,256] f32
  unsigned short* QKVh = (unsigned short*)RA;                 // FULL [32832,768] bf16
  unsigned short* Hh = (unsigned short*)RA;                   // FULL [32832,1024] hi only

  const int GBIG = 1 << 30;

  // weight prep
  prep_kernel<<<1, 256, 0, stream>>>(conv1_b, bn1_g, bn1_b, conv2_b, bn2_g, bn2_b, EFF);
  pe_kernel<<<512, 256, 0, stream>>>(PE);
  vtzero_kernel<<<2048, 256, 0, stream>>>(Vth);
  repack_w2_kernel<<<768, 256, 0, stream>>>(conv2_w, W2Eh, W2El);
  f2bf2_kernel<<<3072, 256, 0, stream>>>(attn_in_w, WQKVh, WQKVl, 786432);
  f2bf2_kernel<<<1024, 256, 0, stream>>>(attn_out_w, WAOh, WAOl, 262144);
  f2bf2_kernel<<<4096, 256, 0, stream>>>(mlp_w1, WM1h, WM1l, 1048576);
  f2bf2_kernel<<<4096, 256, 0, stream>>>(mlp_w2, WM2h, WM2l, 1048576);

  // conv encoder (MT=256, NT=2 -> grid 512)
  zeropad_kernel<<<64, 256, 0, stream>>>(X1Ph, X1Pl);
  conv1_kernel<<<dim3(8, 64), 256, 0, stream>>>(acc_data, conv1_w, EFF, X1Ph, X1Pl);
  bgemm3_kernel<0, false, true, true, true><<<512, 256, 0, stream>>>(
      X1Ph, X1Pl, W2Eh, W2El, EFF + 768, EFF + 512, X2, nullptr, nullptr, nullptr,
      32768, 256, 768, 256, 768, 512, 514, 2, 256);
  // SE gates + sequence build (fp32)
  ca_mean_kernel<<<64, 256, 0, stream>>>(X2, CA);
  gate1_kernel<<<64, 256, 0, stream>>>(CA, sa_w1, sa_b1, sa_ln_g, sa_ln_b, sa_w2, sa_b2, GE);
  ta_mean_kernel<<<64, 256, 0, stream>>>(X2, GE, TA);
  gate2_kernel<<<64, 256, 0, stream>>>(TA, ca_w1, ca_b1, ca_ln_g, ca_ln_b, ca_w2, ca_b2, GT);
  xseq_kernel<<<dim3(513, 64), 256, 0, stream>>>(X2, GE, GT, cls_token, PE, X);

  // transformer layers; MT=257 -> 33 groups of 8 m-slots
  for (int i = 0; i < 4; ++i) {
    ln256p_kernel<<<32832, 256, 0, stream>>>(X, n1_g + i * 256, n1_b + i * 256, XNh, XNl);
    // QKV full-batch GEMM with fused V-transpose (NT=6 -> grid 6*33*8=1584)
    bgemm3_kernel<3, false, false, false, true><<<1584, 256, 0, stream>>>(
        XNh, XNl, WQKVh + (long)i * 196608, WQKVl + (long)i * 196608,
        attn_in_b + i * 768, nullptr, nullptr, QKVh, nullptr, Vth,
        32832, 768, 256, 256, 256, GBIG, 0, 6, 257);
    attn_bf16_kernel<<<4608, 256, 0, stream>>>(QKVh, Vth, Oh);
    bgemm3_kernel<0, true, false, false, false><<<528, 256, 0, stream>>>(
        Oh, nullptr, WAOh + (long)i * 65536, WAOl + (long)i * 65536,
        attn_out_b + i * 256, nullptr, X, nullptr, nullptr, nullptr,
        32832, 256, 256, 256, 256, GBIG, 0, 2, 257);
    ln256p_kernel<<<32832, 256, 0, stream>>>(X, n2_g + i * 256, n2_b + i * 256, XNh, XNl);
    // MLP full-batch; H hi-only (overwrites QKVh in RA — attn already consumed it)
    bgemm3_kernel<1, false, true, false, true><<<2112, 256, 0, stream>>>(
        XNh, XNl, WM1h + (long)i * 262144, WM1l + (long)i * 262144,
        mlp_b1 + i * 1024, nullptr, nullptr, Hh, nullptr, nullptr,
        32832, 1024, 256, 256, 256, GBIG, 0, 8, 257);
    bgemm3_kernel<0, true, false, false, false><<<528, 256, 0, stream>>>(
        Hh, nullptr, WM2h + (long)i * 262144, WM2l + (long)i * 262144,
        mlp_b2 + i * 256, nullptr, X, nullptr, nullptr, nullptr,
        32832, 256, 1024, 1024, 1024, GBIG, 0, 2, 257);
    fushead_kernel<<<64, 256, 0, stream>>>(X, fus_w + (long)i * 65536, fus_b + i * 256,
                                           fus_ln_g + i * 256, fus_ln_b + i * 256,
                                           FEATS + i * 256);
  }
  ln_kernel<false><<<64, 256, 0, stream>>>(FEATS, clf_ln_g, clf_ln_b, CLN, 1024, 1024);
  gemm_kernel<false, true, false><<<dim3(1, 4), 256, 0, stream>>>(
      CLN, clf_w1, clf_b1, nullptr, C2, 64, 256, 1024, GBIG, 0, 0);
  final_kernel<<<1, 128, 0, stream>>>(C2, clf_w2, clf_b2, (float*)d_out);
}

// Round 13
// 1901.952 us; speedup vs baseline: 1.3516x; 1.0692x over previous
//
#include <hip/hip_runtime.h>
#include <math.h>

#define EPS 1e-5f

// Model dims: B=64, T=512, CIN=4, E=256, H=8, dh=32, S=513, L=4, NC=2.
// GEMMs: split-bf16 (hi+lo planes); conv2/QKV/MLP1 3-term, AO/MLP2 2-term.
// bgemm3 grid: 1D XCD swizzle — all n-tiles of an m-tile on ONE XCD (A-tile L2-resident).
// Attention: r8 structure, 2 Q-frags per wave (2 independent chains = ILP; K/V shared).

typedef __attribute__((ext_vector_type(8))) short short8;
typedef __attribute__((ext_vector_type(4))) float f32x4;

__device__ __forceinline__ float gelu_f(float x) {
  return 0.5f * x * (1.0f + erff(x * 0.70710678118654752440f));
}
__device__ __forceinline__ float sigmoid_f(float x) {
  return 1.0f / (1.0f + __expf(-x));
}
__device__ __forceinline__ unsigned short f2bf(float f) {
  unsigned int u = __float_as_uint(f);
  u = (u + 0x7FFFu + ((u >> 16) & 1u)) >> 16;
  return (unsigned short)u;
}
__device__ __forceinline__ float bf2f(unsigned short s) {
  return __uint_as_float(((unsigned int)s) << 16);
}
__device__ __forceinline__ float fexp2(float x) {
#if __has_builtin(__builtin_amdgcn_exp2f)
  return __builtin_amdgcn_exp2f(x);
#else
  return exp2f(x);
#endif
}
__device__ __forceinline__ void gl_lds16(const unsigned short* g, unsigned short* l) {
  __builtin_amdgcn_global_load_lds(
      (const __attribute__((address_space(1))) void*)g,
      (__attribute__((address_space(3))) void*)l, 16, 0, 0);
}

// ---------------- prep: fold conv bias + eval-BN into scale/shift ----------------
__global__ void prep_kernel(const float* __restrict__ c1b, const float* __restrict__ g1,
                            const float* __restrict__ b1, const float* __restrict__ c2b,
                            const float* __restrict__ g2, const float* __restrict__ b2,
                            float* __restrict__ eff) {
  const int t = threadIdx.x;
  const float bninv = rsqrtf(1.0f + EPS);
  const float e1g = bninv * g1[t];
  eff[t]       = e1g;
  eff[256 + t] = c1b[t] * e1g + b1[t];
  const float e2g = bninv * g2[t];
  eff[512 + t] = e2g;
  eff[768 + t] = c2b[t] * e2g + b2[t];
}

// positional embedding table [512][256]
__global__ void pe_kernel(float* __restrict__ pe) {
  const int t = blockIdx.x, e = threadIdx.x;
  const float freq = __expf((float)(e & ~1) * (-0.03597789207803197f));  // -ln(10000)/256
  const float ang = (float)t * freq;
  pe[t * 256 + e] = (e & 1) ? cosf(ang) : sinf(ang);
}

// zero Vt tail (k in [512,544)) once; k=512 is rewritten by QKV each layer
__global__ void vtzero_kernel(unsigned short* __restrict__ vth) {
  const int i = blockIdx.x * 256 + threadIdx.x;  // 16384 rows x 32
  if (i < 524288) vth[(long)(i >> 5) * 544 + 512 + (i & 31)] = 0;
}

// f32 -> bf16 hi+lo planes
__global__ void f2bf2_kernel(const float* __restrict__ src, unsigned short* __restrict__ dh,
                             unsigned short* __restrict__ dl, int n) {
  const int i = blockIdx.x * 256 + threadIdx.x;
  if (i < n) {
    const float x = src[i];
    const unsigned short h = f2bf(x);
    dh[i] = h;
    dl[i] = f2bf(x - bf2f(h));
  }
}

// w2e[e][s*256+ci] = conv2_w[e][ci][s]  (hi/lo), so conv2 == one K=768 GEMM
__global__ void repack_w2_kernel(const float* __restrict__ w2, unsigned short* __restrict__ w2h,
                                 unsigned short* __restrict__ w2l) {
  const int idx = blockIdx.x * 256 + threadIdx.x;  // 256*768
  const int e = idx / 768, rem = idx % 768;
  const int s = rem >> 8, ci = rem & 255;
  const float x = w2[e * 768 + ci * 3 + s];
  const unsigned short h = f2bf(x);
  w2h[idx] = h;
  w2l[idx] = f2bf(x - bf2f(h));
}

// zero padding rows of x1p planes [B][T+2][E]
__global__ void zeropad_kernel(unsigned short* __restrict__ xh, unsigned short* __restrict__ xl) {
  const int b = blockIdx.x, tid = threadIdx.x;
  const long r0 = ((long)b * 514) * 256 + tid;
  const long r1 = ((long)b * 514 + 513) * 256 + tid;
  xh[r0] = 0; xh[r1] = 0; xl[r0] = 0; xl[r1] = 0;
}

// ---------------- conv1 + BN + GELU -> x1p hi/lo planes (rows 1..T) ----------------
__global__ __launch_bounds__(256) void conv1_kernel(const float* __restrict__ in,
                                                    const float* __restrict__ w1,
                                                    const float* __restrict__ eff,
                                                    unsigned short* __restrict__ xh,
                                                    unsigned short* __restrict__ xl) {
  const int b = blockIdx.y, t0 = blockIdx.x * 64;
  const int tid = threadIdx.x;
  __shared__ float4 Ls[66];
  __shared__ float Wl[3072];
  if (tid < 66) {
    const int t = t0 - 1 + tid;
    float4 v = make_float4(0.f, 0.f, 0.f, 0.f);
    if (t >= 0 && t < 512) v = *(const float4*)(in + ((long)b * 512 + t) * 4);
    Ls[tid] = v;
  }
#pragma unroll
  for (int i = 0; i < 12; ++i) Wl[i * 256 + tid] = w1[i * 256 + tid];
  __syncthreads();
  float w[12];
#pragma unroll
  for (int i = 0; i < 12; ++i) w[i] = Wl[tid * 12 + i];  // [c*3+k]
  const float eg = eff[tid], eb = eff[256 + tid];
  const long ob = ((long)b * 514 + t0 + 1) * 256 + tid;
  for (int tl = 0; tl < 64; ++tl) {
    const float4 i0 = Ls[tl], i1 = Ls[tl + 1], i2 = Ls[tl + 2];
    float s = i0.x * w[0] + i1.x * w[1] + i2.x * w[2]
            + i0.y * w[3] + i1.y * w[4] + i2.y * w[5]
            + i0.z * w[6] + i1.z * w[7] + i2.z * w[8]
            + i0.w * w[9] + i1.w * w[10] + i2.w * w[11];
    const float y = gelu_f(s * eg + eb);
    const unsigned short h = f2bf(y);
    xh[ob + (long)tl * 256] = h;
    xl[ob + (long)tl * 256] = f2bf(y - bf2f(h));
  }
}

// ---------------- split-bf16 MFMA GEMM: C[M,N] = epi(A@W^T) ----------------
// 1D grid = NT * ceil(MT/8) * 8, XCD swizzle: group = flat/(8*NT),
// mt = 8*group + flat%8, nt = (flat%(8*NT))/8  =>  XCD(flat%8) == mt%8.
// OUT: 0 = fp32 Cf; 1 = bf16 hi only; 2 = bf16 hi+lo; 3 = QKV fused (n<512: bf16 hi
// rows; n>=512: V written transposed into vth[b][h][d][kpad=544], k = row % 513).
template <int OUT, bool ACC, bool GELU_, bool SCALE, bool SPLITA>
__global__ __launch_bounds__(256) void bgemm3_kernel(
    const unsigned short* __restrict__ Ah, const unsigned short* __restrict__ Al,
    const unsigned short* __restrict__ Wh, const unsigned short* __restrict__ Wlo,
    const float* __restrict__ bias, const float* __restrict__ scale,
    float* __restrict__ Cf, unsigned short* __restrict__ Cbh, unsigned short* __restrict__ Cbl,
    unsigned short* __restrict__ vth,
    int M, int N, int K, int lda, int ldw, int groupT, int strideA, int NT, int MT) {
  __shared__ __align__(16) unsigned short SH[4][4096];  // Ah, Al, Wh, Wl tiles [128][32]
  const int flat = blockIdx.x;
  const int grpsz = NT << 3;
  const int grp = flat / grpsz;
  const int rres = flat - grp * grpsz;
  const int mt = (grp << 3) + (rres & 7);
  const int nt = rres >> 3;
  if (mt >= MT) return;
  const int tid = threadIdx.x;
  const int lane = tid & 63;
  const int m0 = mt << 7, n0 = nt << 7;
  const int g = m0 / groupT;
  const long abase = (long)(g * strideA + (m0 - g * groupT)) * lda;
  const int c0 = tid, c1 = tid + 256;
  const int r0c = c0 >> 2, k0c = (c0 & 3) << 3;
  const int r1c = c1 >> 2, k1c = (c1 & 3) << 3;
  const int mEdge = M - m0 - 1;
  const int r0a = r0c <= mEdge ? r0c : mEdge;
  const int r1a = r1c <= mEdge ? r1c : mEdge;
  const long offA0 = abase + (long)r0a * lda + k0c;
  const long offA1 = abase + (long)r1a * lda + k1c;
  const long offB0 = (long)(n0 + r0c) * ldw + k0c;
  const long offB1 = (long)(n0 + r1c) * ldw + k1c;
  unsigned short* s0 = &SH[0][c0 * 8];
  unsigned short* s1 = &SH[0][c1 * 8];
  const int fr = lane & 15, kg = lane >> 4;
  const int aoff = (((tid >> 7) << 6) + fr) * 32 + kg * 8;
  const int boff = ((((tid >> 6) & 1) << 6) + fr) * 32 + kg * 8;
  f32x4 acc[4][4];
#pragma unroll
  for (int i = 0; i < 4; ++i)
#pragma unroll
    for (int j = 0; j < 4; ++j) acc[i][j] = f32x4{0.f, 0.f, 0.f, 0.f};
  for (int k0 = 0; k0 < K; k0 += 32) {
    gl_lds16(Ah + offA0 + k0, s0);
    gl_lds16(Ah + offA1 + k0, s1);
    if (SPLITA) {
      gl_lds16(Al + offA0 + k0, s0 + 4096);
      gl_lds16(Al + offA1 + k0, s1 + 4096);
    }
    gl_lds16(Wh + offB0 + k0, s0 + 8192);
    gl_lds16(Wh + offB1 + k0, s1 + 8192);
    gl_lds16(Wlo + offB0 + k0, s0 + 12288);
    gl_lds16(Wlo + offB1 + k0, s1 + 12288);
    __syncthreads();
    short8 ah[4], al[4], bh[4], bl[4];
#pragma unroll
    for (int i = 0; i < 4; ++i) {
      ah[i] = *(const short8*)&SH[0][aoff + i * 512];
      if (SPLITA) al[i] = *(const short8*)&SH[1][aoff + i * 512];
    }
#pragma unroll
    for (int j = 0; j < 4; ++j) {
      bh[j] = *(const short8*)&SH[2][boff + j * 512];
      bl[j] = *(const short8*)&SH[3][boff + j * 512];
    }
#pragma unroll
    for (int i = 0; i < 4; ++i)
#pragma unroll
      for (int j = 0; j < 4; ++j) {
        acc[i][j] = __builtin_amdgcn_mfma_f32_16x16x32_bf16(ah[i], bl[j], acc[i][j], 0, 0, 0);
        if (SPLITA)
          acc[i][j] = __builtin_amdgcn_mfma_f32_16x16x32_bf16(al[i], bh[j], acc[i][j], 0, 0, 0);
        acc[i][j] = __builtin_amdgcn_mfma_f32_16x16x32_bf16(ah[i], bh[j], acc[i][j], 0, 0, 0);
      }
    __syncthreads();
  }
  const int colb = n0 + (((tid >> 6) & 1) << 6) + fr;
  float bj[4], sj[4];
#pragma unroll
  for (int j = 0; j < 4; ++j) {
    bj[j] = bias ? bias[colb + j * 16] : 0.f;
    sj[j] = SCALE ? scale[colb + j * 16] : 1.f;
  }
  const int rowb = m0 + ((tid >> 7) << 6) + kg * 4;
  if (OUT == 3 && n0 >= 512) {
    // V path: write transposed into vth[b][h][d][544]; rows = k (per batch of 513)
#pragma unroll
    for (int i = 0; i < 4; ++i) {
      const int row0 = rowb + i * 16;
      const int b0 = row0 / 513;
      const int sq0 = row0 - b0 * 513;
#pragma unroll
      for (int j = 0; j < 4; ++j) {
        const int col = colb + j * 16;
        const int hh = (col - 512) >> 5;
        const int dd = col & 31;
        ushort4 pk;
        pk.x = f2bf(acc[i][j][0] + bj[j]);
        pk.y = f2bf(acc[i][j][1] + bj[j]);
        pk.z = f2bf(acc[i][j][2] + bj[j]);
        pk.w = f2bf(acc[i][j][3] + bj[j]);
        if (row0 + 3 < M && sq0 <= 509) {
          *(ushort4*)(vth + (((long)(b0 * 8 + hh)) * 32 + dd) * 544 + sq0) = pk;
        } else {
          const unsigned short pr[4] = {pk.x, pk.y, pk.z, pk.w};
#pragma unroll
          for (int r = 0; r < 4; ++r) {
            const int row = row0 + r;
            if (row < M) {
              const int bb = row / 513, ss = row - bb * 513;
              vth[(((long)(bb * 8 + hh)) * 32 + dd) * 544 + ss] = pr[r];
            }
          }
        }
      }
    }
    return;
  }
#pragma unroll
  for (int i = 0; i < 4; ++i) {
#pragma unroll
    for (int r = 0; r < 4; ++r) {
      const int row = rowb + i * 16 + r;
      if (row < M) {
#pragma unroll
        for (int j = 0; j < 4; ++j) {
          const long off = (long)row * N + colb + j * 16;
          float v = acc[i][j][r];
          if (ACC) v += Cf[off];
          if (SCALE) v *= sj[j];
          v += bj[j];
          if (GELU_) v = gelu_f(v);
          if (OUT == 0) {
            Cf[off] = v;
          } else if (OUT == 2) {
            const unsigned short h = f2bf(v);
            Cbh[off] = h;
            Cbl[off] = f2bf(v - bf2f(h));
          } else {
            Cbh[off] = f2bf(v);
          }
        }
      }
    }
  }
}

// ---------------- fp32 GEMM (tiny tail mats only) ----------------
template <bool ACC, bool GELU_, bool SCALE>
__global__ __launch_bounds__(256) void gemm_kernel(const float* __restrict__ A,
                                                   const float* __restrict__ W,
                                                   const float* __restrict__ bias,
                                                   const float* __restrict__ scale,
                                                   float* __restrict__ C, int M, int N, int K,
                                                   int groupT, int strideA, int rowOff) {
  __shared__ float As[16][68];
  __shared__ float Bs[16][68];
  const int m0 = blockIdx.x * 64, n0 = blockIdx.y * 64;
  const int g = m0 / groupT, r0 = m0 - g * groupT;
  const float* Ab = A + (long)(g * strideA + r0 + rowOff) * K;
  const float* Wb = W + (long)n0 * K;
  const int tid = threadIdx.x;
  const int lr = tid >> 2;
  const int lk = (tid & 3) << 2;
  const int tr = (tid >> 4) << 2;
  const int tc = (tid & 15) << 2;
  float acc[4][4] = {{0.f}};
  for (int k0 = 0; k0 < K; k0 += 16) {
    const float4 a4 = *(const float4*)(Ab + (long)lr * K + k0 + lk);
    const float4 b4 = *(const float4*)(Wb + (long)lr * K + k0 + lk);
    __syncthreads();
    As[lk + 0][lr] = a4.x; As[lk + 1][lr] = a4.y; As[lk + 2][lr] = a4.z; As[lk + 3][lr] = a4.w;
    Bs[lk + 0][lr] = b4.x; Bs[lk + 1][lr] = b4.y; Bs[lk + 2][lr] = b4.z; Bs[lk + 3][lr] = b4.w;
    __syncthreads();
#pragma unroll
    for (int kk = 0; kk < 16; ++kk) {
      const float4 av = *(const float4*)&As[kk][tr];
      const float4 bv = *(const float4*)&Bs[kk][tc];
      acc[0][0] += av.x * bv.x; acc[0][1] += av.x * bv.y; acc[0][2] += av.x * bv.z; acc[0][3] += av.x * bv.w;
      acc[1][0] += av.y * bv.x; acc[1][1] += av.y * bv.y; acc[1][2] += av.y * bv.z; acc[1][3] += av.y * bv.w;
      acc[2][0] += av.z * bv.x; acc[2][1] += av.z * bv.y; acc[2][2] += av.z * bv.z; acc[2][3] += av.z * bv.w;
      acc[3][0] += av.w * bv.x; acc[3][1] += av.w * bv.y; acc[3][2] += av.w * bv.z; acc[3][3] += av.w * bv.w;
    }
  }
  float4 bb = make_float4(0.f, 0.f, 0.f, 0.f);
  if (bias) bb = *(const float4*)(bias + n0 + tc);
  float4 sv = make_float4(1.f, 1.f, 1.f, 1.f);
  if (SCALE) sv = *(const float4*)(scale + n0 + tc);
#pragma unroll
  for (int i = 0; i < 4; ++i) {
    float* cp = C + (long)(m0 + tr + i) * N + n0 + tc;
    float4 v = make_float4(acc[i][0], acc[i][1], acc[i][2], acc[i][3]);
    if (ACC) {
      const float4 c4 = *(const float4*)cp;
      v.x += c4.x; v.y += c4.y; v.z += c4.z; v.w += c4.w;
    }
    if (SCALE) { v.x *= sv.x; v.y *= sv.y; v.z *= sv.z; v.w *= sv.w; }
    v.x += bb.x; v.y += bb.y; v.z += bb.z; v.w += bb.w;
    if (GELU_) { v.x = gelu_f(v.x); v.y = gelu_f(v.y); v.z = gelu_f(v.z); v.w = gelu_f(v.w); }
    *(float4*)cp = v;
  }
}

// ---------------- SE gates (fp32) ----------------
__global__ __launch_bounds__(256) void ca_mean_kernel(const float* __restrict__ x2,
                                                      float* __restrict__ ca) {
  const int b = blockIdx.x, tid = threadIdx.x;
  float s = 0.f;
  for (int t = 0; t < 512; ++t) s += x2[((long)(b * 512 + t)) * 256 + tid];
  ca[b * 256 + tid] = s * (1.0f / 512.0f);
}

__global__ __launch_bounds__(256) void gate1_kernel(const float* __restrict__ ca,
    const float* __restrict__ w1, const float* __restrict__ b1,
    const float* __restrict__ lng, const float* __restrict__ lnb,
    const float* __restrict__ w2, const float* __restrict__ b2, float* __restrict__ ge) {
  const int b = blockIdx.x, tid = threadIdx.x;
  __shared__ float caL[256];
  __shared__ float zL[32];
  caL[tid] = ca[b * 256 + tid];
  __syncthreads();
  if (tid < 32) {
    float s = b1[tid];
    for (int e = 0; e < 256; ++e) s += caL[e] * w1[tid * 256 + e];
    float mean = s;
    for (int msk = 1; msk < 32; msk <<= 1) mean += __shfl_xor(mean, msk);
    mean *= (1.0f / 32.0f);
    const float d = s - mean;
    float v = d * d;
    for (int msk = 1; msk < 32; msk <<= 1) v += __shfl_xor(v, msk);
    v *= (1.0f / 32.0f);
    zL[tid] = gelu_f(d * rsqrtf(v + EPS) * lng[tid] + lnb[tid]);
  }
  __syncthreads();
  float a = b2[tid];
#pragma unroll
  for (int j = 0; j < 32; ++j) a += zL[j] * w2[tid * 32 + j];
  ge[b * 256 + tid] = sigmoid_f(a);
}

__global__ __launch_bounds__(256) void ta_mean_kernel(const float* __restrict__ x2,
                                                      const float* __restrict__ ge,
                                                      float* __restrict__ ta) {
  const int b = blockIdx.x, tid = threadIdx.x;
  const int w = tid >> 6, lane = tid & 63;
  const float4 g4 = *(const float4*)(ge + b * 256 + lane * 4);
  for (int t = w; t < 512; t += 4) {
    const float4 x4 = *(const float4*)(x2 + ((long)(b * 512 + t)) * 256 + lane * 4);
    float s = x4.x * g4.x + x4.y * g4.y + x4.z * g4.z + x4.w * g4.w;
#pragma unroll
    for (int msk = 32; msk; msk >>= 1) s += __shfl_xor(s, msk);
    if (lane == 0) ta[b * 512 + t] = s * (1.0f / 256.0f);
  }
}

__global__ __launch_bounds__(256) void gate2_kernel(const float* __restrict__ ta,
    const float* __restrict__ w1, const float* __restrict__ b1,
    const float* __restrict__ lng, const float* __restrict__ lnb,
    const float* __restrict__ w2, const float* __restrict__ b2, float* __restrict__ gt) {
  const int b = blockIdx.x, tid = threadIdx.x;
  __shared__ float taL[512];
  __shared__ float zL[64];
  taL[tid] = ta[b * 512 + tid];
  taL[256 + tid] = ta[b * 512 + 256 + tid];
  __syncthreads();
  if (tid < 64) {
    float s = b1[tid];
    for (int t = 0; t < 512; ++t) s += taL[t] * w1[tid * 512 + t];
    float mean = s;
    for (int msk = 1; msk < 64; msk <<= 1) mean += __shfl_xor(mean, msk);
    mean *= (1.0f / 64.0f);
    const float d = s - mean;
    float v = d * d;
    for (int msk = 1; msk < 64; msk <<= 1) v += __shfl_xor(v, msk);
    v *= (1.0f / 64.0f);
    zL[tid] = gelu_f(d * rsqrtf(v + EPS) * lng[tid] + lnb[tid]);
  }
  __syncthreads();
#pragma unroll
  for (int r = 0; r < 2; ++r) {
    const int t = tid + r * 256;
    float a = b2[t];
    for (int j = 0; j < 64; ++j) a += zL[j] * w2[t * 64 + j];
    gt[b * 512 + t] = sigmoid_f(a);
  }
}

// x_seq build (fp32 residual stream); PE precomputed
__global__ __launch_bounds__(256) void xseq_kernel(const float* __restrict__ x2,
    const float* __restrict__ ge, const float* __restrict__ gt,
    const float* __restrict__ cls, const float* __restrict__ pe, float* __restrict__ x) {
  const int srow = blockIdx.x, b = blockIdx.y, e = threadIdx.x;
  float* outp = x + ((long)(b * 513 + srow)) * 256 + e;
  if (srow == 0) { *outp = cls[e]; return; }
  const int t = srow - 1;
  *outp = x2[((long)(b * 512 + t)) * 256 + e] * ge[b * 256 + e] * gt[b * 512 + t]
        + pe[t * 256 + e];
}

// ---------------- LayerNorm fp32 -> fp32 (tail) ----------------
template <bool GELU_>
__global__ __launch_bounds__(256) void ln_kernel(const float* __restrict__ in,
                                                 const float* __restrict__ g,
                                                 const float* __restrict__ bta,
                                                 float* __restrict__ out, int D, int ostride) {
  const int row = blockIdx.x, tid = threadIdx.x;
  __shared__ float red[8];
  const float* x = in + (long)row * D;
  const int nv = D >> 8;
  float xv[4];
  float s = 0.f;
  for (int i = 0; i < nv; ++i) { xv[i] = x[tid + (i << 8)]; s += xv[i]; }
#pragma unroll
  for (int msk = 32; msk; msk >>= 1) s += __shfl_xor(s, msk);
  if ((tid & 63) == 0) red[tid >> 6] = s;
  __syncthreads();
  s = red[0] + red[1] + red[2] + red[3];
  const float mean = s / (float)D;
  float vs = 0.f;
  for (int i = 0; i < nv; ++i) { const float d = xv[i] - mean; vs += d * d; }
#pragma unroll
  for (int msk = 32; msk; msk >>= 1) vs += __shfl_xor(vs, msk);
  if ((tid & 63) == 0) red[4 + (tid >> 6)] = vs;
  __syncthreads();
  vs = red[4] + red[5] + red[6] + red[7];
  const float inv = rsqrtf(vs / (float)D + EPS);
  for (int i = 0; i < nv; ++i) {
    const int col = tid + (i << 8);
    float y = (xv[i] - mean) * inv * g[col] + bta[col];
    if (GELU_) y = gelu_f(y);
    out[(long)row * ostride + col] = y;
  }
}

// ---------------- LayerNorm D=256, fp32 -> bf16 hi/lo planes ----------------
__global__ __launch_bounds__(256) void ln256p_kernel(const float* __restrict__ in,
                                                     const float* __restrict__ g,
                                                     const float* __restrict__ bta,
                                                     unsigned short* __restrict__ oh,
                                                     unsigned short* __restrict__ ol) {
  const int row = blockIdx.x, tid = threadIdx.x;
  __shared__ float red[8];
  const float xv = in[(long)row * 256 + tid];
  float s = xv;
#pragma unroll
  for (int msk = 32; msk; msk >>= 1) s += __shfl_xor(s, msk);
  if ((tid & 63) == 0) red[tid >> 6] = s;
  __syncthreads();
  s = red[0] + red[1] + red[2] + red[3];
  const float mean = s * (1.0f / 256.0f);
  const float d = xv - mean;
  float vs = d * d;
#pragma unroll
  for (int msk = 32; msk; msk >>= 1) vs += __shfl_xor(vs, msk);
  if ((tid & 63) == 0) red[4 + (tid >> 6)] = vs;
  __syncthreads();
  vs = red[4] + red[5] + red[6] + red[7];
  const float inv = rsqrtf(vs * (1.0f / 256.0f) + EPS);
  const float y = d * inv * g[tid] + bta[tid];
  const unsigned short h = f2bf(y);
  oh[(long)row * 256 + tid] = h;
  ol[(long)row * 256 + tid] = f2bf(y - bf2f(h));
}

// ---------------- MFMA flash attention: 2 Q-frags per wave (ILP) ----------------
// 1D grid 2560: flat = h + 8*(qb + 5*b); blocks sharing (b,h) K/V are 8 apart
// (same XCD). 256 thr = 4 waves; wave owns 32 q rows (2 fragments); k-chunk 32.
// Keys interleaved per half (key = k0 + 2*l16 + hh) -> P pair packs to one u32.
// Per-row math bit-identical to the r8 kernel.
__global__ __launch_bounds__(256) void attn_bf16_kernel(
    const unsigned short* __restrict__ qkvh, const unsigned short* __restrict__ vth,
    unsigned short* __restrict__ oh) {
  const int flat = blockIdx.x;
  const int h = flat & 7;
  const int t_ = flat >> 3;
  const int qb = t_ % 5;
  const int b = t_ / 5;
  const int tid = threadIdx.x;
  const int wave = tid >> 6, lane = tid & 63;
  const int quad = lane >> 4, l16 = lane & 15;
  __shared__ __align__(16) unsigned short PhS[4][2][16][40];
  unsigned short (*Ph0)[40] = PhS[wave][0];
  unsigned short (*Ph1)[40] = PhS[wave][1];

  const long base = (long)b * 513;
  const int qbase = qb * 128 + wave * 32;
  const int qr0 = qbase + l16;
  const int qr1 = qbase + 16 + l16;
  const short8 qA = *(const short8*)(qkvh + (base + (qr0 < 513 ? qr0 : 512)) * 768 + h * 32 + quad * 8);
  const short8 qB = *(const short8*)(qkvh + (base + (qr1 < 513 ? qr1 : 512)) * 768 + h * 32 + quad * 8);
  const long vtb = ((long)(b * 8 + h)) * 32 * 544;

  const unsigned short* kp0 = qkvh + (base + 2 * l16) * 768 + 256 + h * 32 + quad * 8;
  const unsigned short* kp1 = kp0 + 768;
  const unsigned short* vp0 = vth + vtb + (long)l16 * 544 + quad * 8;
  const unsigned short* vp1 = vth + vtb + (long)(16 + l16) * 544 + quad * 8;
  unsigned int* phpA = (unsigned int*)&Ph0[quad * 4][2 * l16];  // row stride 20 uint
  unsigned int* phpB = (unsigned int*)&Ph1[quad * 4][2 * l16];
  const short8* prdA = (const short8*)&Ph0[l16][quad * 8];
  const short8* prdB = (const short8*)&Ph1[l16][quad * 8];

  float lrowA[4] = {0.f, 0.f, 0.f, 0.f};
  float lrowB[4] = {0.f, 0.f, 0.f, 0.f};
  const f32x4 zf = {0.f, 0.f, 0.f, 0.f};
  f32x4 oaccA[2] = {zf, zf};
  f32x4 oaccB[2] = {zf, zf};
  const float sf2 = 0.25506994362f;  // log2(e)/sqrt(32)

  for (int c = 0; c < 16; ++c) {
    const short8 k0r = *(const short8*)kp0;
    const short8 k1r = *(const short8*)kp1;
    kp0 += 32 * 768;
    kp1 += 32 * 768;
    const f32x4 sA0 = __builtin_amdgcn_mfma_f32_16x16x32_bf16(qA, k0r, zf, 0, 0, 0);
    const f32x4 sA1 = __builtin_amdgcn_mfma_f32_16x16x32_bf16(qA, k1r, zf, 0, 0, 0);
    const f32x4 sB0 = __builtin_amdgcn_mfma_f32_16x16x32_bf16(qB, k0r, zf, 0, 0, 0);
    const f32x4 sB1 = __builtin_amdgcn_mfma_f32_16x16x32_bf16(qB, k1r, zf, 0, 0, 0);
#pragma unroll
    for (int r = 0; r < 4; ++r) {
      const float pA0 = fexp2(sA0[r] * sf2);
      const float pA1 = fexp2(sA1[r] * sf2);
      const unsigned int pkA = ((unsigned int)f2bf(pA1) << 16) | f2bf(pA0);
      phpA[r * 20] = pkA;
      lrowA[r] += __uint_as_float(pkA << 16) + __uint_as_float(pkA & 0xFFFF0000u);
      const float pB0 = fexp2(sB0[r] * sf2);
      const float pB1 = fexp2(sB1[r] * sf2);
      const unsigned int pkB = ((unsigned int)f2bf(pB1) << 16) | f2bf(pB0);
      phpB[r * 20] = pkB;
      lrowB[r] += __uint_as_float(pkB << 16) + __uint_as_float(pkB & 0xFFFF0000u);
    }
    asm volatile("" ::: "memory");  // DS writes stay before DS reads (same-wave order)
    const short8 pa = *prdA;
    const short8 pb = *prdB;
    const short8 v0r = *(const short8*)vp0;
    const short8 v1r = *(const short8*)vp1;
    vp0 += 32;
    vp1 += 32;
    oaccA[0] = __builtin_amdgcn_mfma_f32_16x16x32_bf16(pa, v0r, oaccA[0], 0, 0, 0);
    oaccA[1] = __builtin_amdgcn_mfma_f32_16x16x32_bf16(pa, v1r, oaccA[1], 0, 0, 0);
    oaccB[0] = __builtin_amdgcn_mfma_f32_16x16x32_bf16(pb, v0r, oaccB[0], 0, 0, 0);
    oaccB[1] = __builtin_amdgcn_mfma_f32_16x16x32_bf16(pb, v1r, oaccB[1], 0, 0, 0);
    asm volatile("" ::: "memory");  // next chunk's DS writes stay after these reads
  }
  // tail: key 512 only (all lanes load key-512 row; only l16==0 col is real)
  {
    const short8 k512 = *(const short8*)(qkvh + (base + 512) * 768 + 256 + h * 32 + quad * 8);
    const f32x4 sA0 = __builtin_amdgcn_mfma_f32_16x16x32_bf16(qA, k512, zf, 0, 0, 0);
    const f32x4 sB0 = __builtin_amdgcn_mfma_f32_16x16x32_bf16(qB, k512, zf, 0, 0, 0);
#pragma unroll
    for (int r = 0; r < 4; ++r) {
      const float pA0 = (l16 == 0) ? fexp2(sA0[r] * sf2) : 0.f;
      const unsigned int pkA = (unsigned int)f2bf(pA0);
      phpA[r * 20] = pkA;
      lrowA[r] += __uint_as_float(pkA << 16);
      const float pB0 = (l16 == 0) ? fexp2(sB0[r] * sf2) : 0.f;
      const unsigned int pkB = (unsigned int)f2bf(pB0);
      phpB[r * 20] = pkB;
      lrowB[r] += __uint_as_float(pkB << 16);
    }
    asm volatile("" ::: "memory");
    const short8 pa = *prdA;
    const short8 pb = *prdB;
    const short8 v0r = *(const short8*)vp0;
    const short8 v1r = *(const short8*)vp1;
    oaccA[0] = __builtin_amdgcn_mfma_f32_16x16x32_bf16(pa, v0r, oaccA[0], 0, 0, 0);
    oaccA[1] = __builtin_amdgcn_mfma_f32_16x16x32_bf16(pa, v1r, oaccA[1], 0, 0, 0);
    oaccB[0] = __builtin_amdgcn_mfma_f32_16x16x32_bf16(pb, v0r, oaccB[0], 0, 0, 0);
    oaccB[1] = __builtin_amdgcn_mfma_f32_16x16x32_bf16(pb, v1r, oaccB[1], 0, 0, 0);
  }
#pragma unroll
  for (int r = 0; r < 4; ++r) {
    lrowA[r] += __shfl_xor(lrowA[r], 1);
    lrowA[r] += __shfl_xor(lrowA[r], 2);
    lrowA[r] += __shfl_xor(lrowA[r], 4);
    lrowA[r] += __shfl_xor(lrowA[r], 8);
    lrowB[r] += __shfl_xor(lrowB[r], 1);
    lrowB[r] += __shfl_xor(lrowB[r], 2);
    lrowB[r] += __shfl_xor(lrowB[r], 4);
    lrowB[r] += __shfl_xor(lrowB[r], 8);
  }
  const int orowA = qbase + quad * 4;
  const int orowB = qbase + 16 + quad * 4;
#pragma unroll
  for (int r = 0; r < 4; ++r) {
    const int qrA = orowA + r;
    if (qrA < 513) {
      const float inv = 1.0f / lrowA[r];
      oh[(base + qrA) * 256 + h * 32 + l16] = f2bf(oaccA[0][r] * inv);
      oh[(base + qrA) * 256 + h * 32 + 16 + l16] = f2bf(oaccA[1][r] * inv);
    }
    const int qrB = orowB + r;
    if (qrB < 513) {
      const float inv = 1.0f / lrowB[r];
      oh[(base + qrB) * 256 + h * 32 + l16] = f2bf(oaccB[0][r] * inv);
      oh[(base + qrB) * 256 + h * 32 + 16 + l16] = f2bf(oaccB[1][r] * inv);
    }
  }
}

// ---------------- fused fusion head: f = GELU(LN(CLS @ fus_w^T + fus_b)) ----------------
__global__ __launch_bounds__(256) void fushead_kernel(const float* __restrict__ x,
    const float* __restrict__ fw, const float* __restrict__ fb,
    const float* __restrict__ lng, const float* __restrict__ lnb,
    float* __restrict__ feats) {
  const int b = blockIdx.x, tid = threadIdx.x;
  __shared__ float cls[256];
  __shared__ float red[8];
  cls[tid] = x[(long)b * 513 * 256 + tid];
  __syncthreads();
  float s = fb[tid];
  const float* wr = fw + (long)tid * 256;
  for (int j = 0; j < 256; j += 4) {
    const float4 w4 = *(const float4*)(wr + j);
    s += cls[j] * w4.x + cls[j + 1] * w4.y + cls[j + 2] * w4.z + cls[j + 3] * w4.w;
  }
  float m = s;
#pragma unroll
  for (int msk = 32; msk; msk >>= 1) m += __shfl_xor(m, msk);
  if ((tid & 63) == 0) red[tid >> 6] = m;
  __syncthreads();
  m = (red[0] + red[1] + red[2] + red[3]) * (1.0f / 256.0f);
  const float d = s - m;
  float vs = d * d;
#pragma unroll
  for (int msk = 32; msk; msk >>= 1) vs += __shfl_xor(vs, msk);
  if ((tid & 63) == 0) red[4 + (tid >> 6)] = vs;
  __syncthreads();
  vs = red[4] + red[5] + red[6] + red[7];
  const float inv = rsqrtf(vs * (1.0f / 256.0f) + EPS);
  feats[b * 1024 + tid] = gelu_f(d * inv * lng[tid] + lnb[tid]);
}

__global__ void final_kernel(const float* __restrict__ c2, const float* __restrict__ w,
                             const float* __restrict__ bias, float* __restrict__ out) {
  const int tid = threadIdx.x;  // 128 threads: (b, n)
  const int b = tid >> 1, n = tid & 1;
  float s = bias[n];
  for (int j = 0; j < 256; ++j) s += c2[b * 256 + j] * w[n * 256 + j];
  out[b * 2 + n] = s;
}

extern "C" void kernel_launch(void* const* d_in, const int* in_sizes, int n_in, void* d_out,
                              int out_size, void* d_ws, size_t ws_size, hipStream_t stream) {
  const float* acc_data = (const float*)d_in[0];
  const float* conv1_w = (const float*)d_in[1];
  const float* conv1_b = (const float*)d_in[2];
  const float* bn1_g = (const float*)d_in[3];
  const float* bn1_b = (const float*)d_in[4];
  const float* conv2_w = (const float*)d_in[5];
  const float* conv2_b = (const float*)d_in[6];
  const float* bn2_g = (const float*)d_in[7];
  const float* bn2_b = (const float*)d_in[8];
  const float* sa_w1 = (const float*)d_in[9];
  const float* sa_b1 = (const float*)d_in[10];
  const float* sa_ln_g = (const float*)d_in[11];
  const float* sa_ln_b = (const float*)d_in[12];
  const float* sa_w2 = (const float*)d_in[13];
  const float* sa_b2 = (const float*)d_in[14];
  const float* ca_w1 = (const float*)d_in[15];
  const float* ca_b1 = (const float*)d_in[16];
  const float* ca_ln_g = (const float*)d_in[17];
  const float* ca_ln_b = (const float*)d_in[18];
  const float* ca_w2 = (const float*)d_in[19];
  const float* ca_b2 = (const float*)d_in[20];
  const float* cls_token = (const float*)d_in[21];
  const float* n1_g = (const float*)d_in[22];
  const float* n1_b = (const float*)d_in[23];
  const float* attn_in_w = (const float*)d_in[24];
  const float* attn_in_b = (const float*)d_in[25];
  const float* attn_out_w = (const float*)d_in[26];
  const float* attn_out_b = (const float*)d_in[27];
  const float* n2_g = (const float*)d_in[28];
  const float* n2_b = (const float*)d_in[29];
  const float* mlp_w1 = (const float*)d_in[30];
  const float* mlp_b1 = (const float*)d_in[31];
  const float* mlp_w2 = (const float*)d_in[32];
  const float* mlp_b2 = (const float*)d_in[33];
  const float* fus_w = (const float*)d_in[34];
  const float* fus_b = (const float*)d_in[35];
  const float* fus_ln_g = (const float*)d_in[36];
  const float* fus_ln_b = (const float*)d_in[37];
  const float* clf_ln_g = (const float*)d_in[38];
  const float* clf_ln_b = (const float*)d_in[39];
  const float* clf_w1 = (const float*)d_in[40];
  const float* clf_b1 = (const float*)d_in[41];
  const float* clf_w2 = (const float*)d_in[42];
  const float* clf_b2 = (const float*)d_in[43];

  // ---- workspace layout (bytes); total ~185 MB ----
  char* p = (char*)d_ws;
  char* RA = p; p += 68255744L;  // aliases: conv [X1P planes|X2] / QKVh / H (hi, full)
  float* X = (float*)p; p += 33619968L;                      // residual [32832,256] f32
  unsigned short* XNh = (unsigned short*)p; p += 16809984L;  // LN out planes (full batch)
  unsigned short* XNl = (unsigned short*)p; p += 16809984L;
  unsigned short* Oh = (unsigned short*)p; p += 16809984L;   // attn out bf16 (full batch)
  unsigned short* Vth = (unsigned short*)p; p += 17825792L;  // DEDICATED Vt [64,8,32,544]
  unsigned short* WQKVh = (unsigned short*)p; p += 1572864L;
  unsigned short* WQKVl = (unsigned short*)p; p += 1572864L;
  unsigned short* WAOh = (unsigned short*)p; p += 524288L;
  unsigned short* WAOl = (unsigned short*)p; p += 524288L;
  unsigned short* WM1h = (unsigned short*)p; p += 2097152L;
  unsigned short* WM1l = (unsigned short*)p; p += 2097152L;
  unsigned short* WM2h = (unsigned short*)p; p += 2097152L;
  unsigned short* WM2l = (unsigned short*)p; p += 2097152L;
  unsigned short* W2Eh = (unsigned short*)p; p += 393216L;
  unsigned short* W2El = (unsigned short*)p; p += 393216L;
  float* EFF = (float*)p;    p += 1024L * 4;
  float* CA = (float*)p;     p += 16384L * 4;
  float* GE = (float*)p;     p += 16384L * 4;
  float* TA = (float*)p;     p += 32768L * 4;
  float* GT = (float*)p;     p += 32768L * 4;
  float* FEATS = (float*)p;  p += 65536L * 4;
  float* CLN = (float*)p;    p += 65536L * 4;
  float* C2 = (float*)p;     p += 16384L * 4;
  float* PE = (float*)p;     p += 131072L * 4;

  // RA aliases (sequential within a layer: QKVh consumed by attn before Hh written)
  unsigned short* X1Ph = (unsigned short*)RA;                 // conv: [64,514,256] hi
  unsigned short* X1Pl = (unsigned short*)(RA + 16842752L);   // lo
  float* X2 = (float*)(RA + 33685504L);                       // [32768,256] f32
  unsigned short* QKVh = (unsigned short*)RA;                 // FULL [32832,768] bf16
  unsigned short* Hh = (unsigned short*)RA;                   // FULL [32832,1024] hi only

  const int GBIG = 1 << 30;

  // weight prep
  prep_kernel<<<1, 256, 0, stream>>>(conv1_b, bn1_g, bn1_b, conv2_b, bn2_g, bn2_b, EFF);
  pe_kernel<<<512, 256, 0, stream>>>(PE);
  vtzero_kernel<<<2048, 256, 0, stream>>>(Vth);
  repack_w2_kernel<<<768, 256, 0, stream>>>(conv2_w, W2Eh, W2El);
  f2bf2_kernel<<<3072, 256, 0, stream>>>(attn_in_w, WQKVh, WQKVl, 786432);
  f2bf2_kernel<<<1024, 256, 0, stream>>>(attn_out_w, WAOh, WAOl, 262144);
  f2bf2_kernel<<<4096, 256, 0, stream>>>(mlp_w1, WM1h, WM1l, 1048576);
  f2bf2_kernel<<<4096, 256, 0, stream>>>(mlp_w2, WM2h, WM2l, 1048576);

  // conv encoder (MT=256, NT=2 -> grid 512)
  zeropad_kernel<<<64, 256, 0, stream>>>(X1Ph, X1Pl);
  conv1_kernel<<<dim3(8, 64), 256, 0, stream>>>(acc_data, conv1_w, EFF, X1Ph, X1Pl);
  bgemm3_kernel<0, false, true, true, true><<<512, 256, 0, stream>>>(
      X1Ph, X1Pl, W2Eh, W2El, EFF + 768, EFF + 512, X2, nullptr, nullptr, nullptr,
      32768, 256, 768, 256, 768, 512, 514, 2, 256);
  // SE gates + sequence build (fp32)
  ca_mean_kernel<<<64, 256, 0, stream>>>(X2, CA);
  gate1_kernel<<<64, 256, 0, stream>>>(CA, sa_w1, sa_b1, sa_ln_g, sa_ln_b, sa_w2, sa_b2, GE);
  ta_mean_kernel<<<64, 256, 0, stream>>>(X2, GE, TA);
  gate2_kernel<<<64, 256, 0, stream>>>(TA, ca_w1, ca_b1, ca_ln_g, ca_ln_b, ca_w2, ca_b2, GT);
  xseq_kernel<<<dim3(513, 64), 256, 0, stream>>>(X2, GE, GT, cls_token, PE, X);

  // transformer layers; MT=257 -> 33 groups of 8 m-slots
  for (int i = 0; i < 4; ++i) {
    ln256p_kernel<<<32832, 256, 0, stream>>>(X, n1_g + i * 256, n1_b + i * 256, XNh, XNl);
    // QKV full-batch GEMM with fused V-transpose (NT=6 -> grid 6*33*8=1584)
    bgemm3_kernel<3, false, false, false, true><<<1584, 256, 0, stream>>>(
        XNh, XNl, WQKVh + (long)i * 196608, WQKVl + (long)i * 196608,
        attn_in_b + i * 768, nullptr, nullptr, QKVh, nullptr, Vth,
        32832, 768, 256, 256, 256, GBIG, 0, 6, 257);
    attn_bf16_kernel<<<2560, 256, 0, stream>>>(QKVh, Vth, Oh);
    bgemm3_kernel<0, true, false, false, false><<<528, 256, 0, stream>>>(
        Oh, nullptr, WAOh + (long)i * 65536, WAOl + (long)i * 65536,
        attn_out_b + i * 256, nullptr, X, nullptr, nullptr, nullptr,
        32832, 256, 256, 256, 256, GBIG, 0, 2, 257);
    ln256p_kernel<<<32832, 256, 0, stream>>>(X, n2_g + i * 256, n2_b + i * 256, XNh, XNl);
    // MLP full-batch; H hi-only (overwrites QKVh in RA — attn already consumed it)
    bgemm3_kernel<1, false, true, false, true><<<2112, 256, 0, stream>>>(
        XNh, XNl, WM1h + (long)i * 262144, WM1l + (long)i * 262144,
        mlp_b1 + i * 1024, nullptr, nullptr, Hh, nullptr, nullptr,
        32832, 1024, 256, 256, 256, GBIG, 0, 8, 257);
    bgemm3_kernel<0, true, false, false, false><<<528, 256, 0, stream>>>(
        Hh, nullptr, WM2h + (long)i * 262144, WM2l + (long)i * 262144,
        mlp_b2 + i * 256, nullptr, X, nullptr, nullptr, nullptr,
        32832, 256, 1024, 1024, 1024, GBIG, 0, 2, 257);
    fushead_kernel<<<64, 256, 0, stream>>>(X, fus_w + (long)i * 65536, fus_b + i * 256,
                                           fus_ln_g + i * 256, fus_ln_b + i * 256,
                                           FEATS + i * 256);
  }
  ln_kernel<false><<<64, 256, 0, stream>>>(FEATS, clf_ln_g, clf_ln_b, CLN, 1024, 1024);
  gemm_kernel<false, true, false><<<dim3(1, 4), 256, 0, stream>>>(
      CLN, clf_w1, clf_b1, nullptr, C2, 64, 256, 1024, GBIG, 0, 0);
  final_kernel<<<1, 128, 0, stream>>>(C2, clf_w2, clf_b2, (float*)d_out);
}

// Round 14
// 1891.399 us; speedup vs baseline: 1.3592x; 1.0056x over previous
//
#include <hip/hip_runtime.h>
#include <math.h>

#define EPS 1e-5f

// Model dims: B=64, T=512, CIN=4, E=256, H=8, dh=32, S=513, L=4, NC=2.
// GEMMs: split-bf16 weight planes; conv2/MLP1 3-term, QKV/AO/MLP2 2-term.
// bgemm3 grid: 1D XCD swizzle — all n-tiles of an m-tile on ONE XCD.
// Attention: 2 Q-frags per wave (ILP), LDS packed-P, XCD swizzle.

typedef __attribute__((ext_vector_type(8))) short short8;
typedef __attribute__((ext_vector_type(4))) float f32x4;

__device__ __forceinline__ float gelu_f(float x) {
  return 0.5f * x * (1.0f + erff(x * 0.70710678118654752440f));
}
__device__ __forceinline__ float sigmoid_f(float x) {
  return 1.0f / (1.0f + __expf(-x));
}
__device__ __forceinline__ unsigned short f2bf(float f) {
  unsigned int u = __float_as_uint(f);
  u = (u + 0x7FFFu + ((u >> 16) & 1u)) >> 16;
  return (unsigned short)u;
}
__device__ __forceinline__ float bf2f(unsigned short s) {
  return __uint_as_float(((unsigned int)s) << 16);
}
__device__ __forceinline__ float fexp2(float x) {
#if __has_builtin(__builtin_amdgcn_exp2f)
  return __builtin_amdgcn_exp2f(x);
#else
  return exp2f(x);
#endif
}
__device__ __forceinline__ void gl_lds16(const unsigned short* g, unsigned short* l) {
  __builtin_amdgcn_global_load_lds(
      (const __attribute__((address_space(1))) void*)g,
      (__attribute__((address_space(3))) void*)l, 16, 0, 0);
}

// ---------------- prep: fold conv bias + eval-BN into scale/shift ----------------
__global__ void prep_kernel(const float* __restrict__ c1b, const float* __restrict__ g1,
                            const float* __restrict__ b1, const float* __restrict__ c2b,
                            const float* __restrict__ g2, const float* __restrict__ b2,
                            float* __restrict__ eff) {
  const int t = threadIdx.x;
  const float bninv = rsqrtf(1.0f + EPS);
  const float e1g = bninv * g1[t];
  eff[t]       = e1g;
  eff[256 + t] = c1b[t] * e1g + b1[t];
  const float e2g = bninv * g2[t];
  eff[512 + t] = e2g;
  eff[768 + t] = c2b[t] * e2g + b2[t];
}

// positional embedding table [512][256]
__global__ void pe_kernel(float* __restrict__ pe) {
  const int t = blockIdx.x, e = threadIdx.x;
  const float freq = __expf((float)(e & ~1) * (-0.03597789207803197f));  // -ln(10000)/256
  const float ang = (float)t * freq;
  pe[t * 256 + e] = (e & 1) ? cosf(ang) : sinf(ang);
}

// zero Vt tail (k in [512,544)) once; k=512 is rewritten by QKV each layer
__global__ void vtzero_kernel(unsigned short* __restrict__ vth) {
  const int i = blockIdx.x * 256 + threadIdx.x;  // 16384 rows x 32
  if (i < 524288) vth[(long)(i >> 5) * 544 + 512 + (i & 31)] = 0;
}

// f32 -> bf16 hi+lo planes
__global__ void f2bf2_kernel(const float* __restrict__ src, unsigned short* __restrict__ dh,
                             unsigned short* __restrict__ dl, int n) {
  const int i = blockIdx.x * 256 + threadIdx.x;
  if (i < n) {
    const float x = src[i];
    const unsigned short h = f2bf(x);
    dh[i] = h;
    dl[i] = f2bf(x - bf2f(h));
  }
}

// w2e[e][s*256+ci] = conv2_w[e][ci][s]  (hi/lo), so conv2 == one K=768 GEMM
__global__ void repack_w2_kernel(const float* __restrict__ w2, unsigned short* __restrict__ w2h,
                                 unsigned short* __restrict__ w2l) {
  const int idx = blockIdx.x * 256 + threadIdx.x;  // 256*768
  const int e = idx / 768, rem = idx % 768;
  const int s = rem >> 8, ci = rem & 255;
  const float x = w2[e * 768 + ci * 3 + s];
  const unsigned short h = f2bf(x);
  w2h[idx] = h;
  w2l[idx] = f2bf(x - bf2f(h));
}

// zero padding rows of x1p planes [B][T+2][E]
__global__ void zeropad_kernel(unsigned short* __restrict__ xh, unsigned short* __restrict__ xl) {
  const int b = blockIdx.x, tid = threadIdx.x;
  const long r0 = ((long)b * 514) * 256 + tid;
  const long r1 = ((long)b * 514 + 513) * 256 + tid;
  xh[r0] = 0; xh[r1] = 0; xl[r0] = 0; xl[r1] = 0;
}

// ---------------- conv1 + BN + GELU -> x1p hi/lo planes (rows 1..T) ----------------
__global__ __launch_bounds__(256) void conv1_kernel(const float* __restrict__ in,
                                                    const float* __restrict__ w1,
                                                    const float* __restrict__ eff,
                                                    unsigned short* __restrict__ xh,
                                                    unsigned short* __restrict__ xl) {
  const int b = blockIdx.y, t0 = blockIdx.x * 64;
  const int tid = threadIdx.x;
  __shared__ float4 Ls[66];
  __shared__ float Wl[3072];
  if (tid < 66) {
    const int t = t0 - 1 + tid;
    float4 v = make_float4(0.f, 0.f, 0.f, 0.f);
    if (t >= 0 && t < 512) v = *(const float4*)(in + ((long)b * 512 + t) * 4);
    Ls[tid] = v;
  }
#pragma unroll
  for (int i = 0; i < 12; ++i) Wl[i * 256 + tid] = w1[i * 256 + tid];
  __syncthreads();
  float w[12];
#pragma unroll
  for (int i = 0; i < 12; ++i) w[i] = Wl[tid * 12 + i];  // [c*3+k]
  const float eg = eff[tid], eb = eff[256 + tid];
  const long ob = ((long)b * 514 + t0 + 1) * 256 + tid;
  for (int tl = 0; tl < 64; ++tl) {
    const float4 i0 = Ls[tl], i1 = Ls[tl + 1], i2 = Ls[tl + 2];
    float s = i0.x * w[0] + i1.x * w[1] + i2.x * w[2]
            + i0.y * w[3] + i1.y * w[4] + i2.y * w[5]
            + i0.z * w[6] + i1.z * w[7] + i2.z * w[8]
            + i0.w * w[9] + i1.w * w[10] + i2.w * w[11];
    const float y = gelu_f(s * eg + eb);
    const unsigned short h = f2bf(y);
    xh[ob + (long)tl * 256] = h;
    xl[ob + (long)tl * 256] = f2bf(y - bf2f(h));
  }
}

// ---------------- split-bf16 MFMA GEMM: C[M,N] = epi(A@W^T) ----------------
// 1D grid = NT * ceil(MT/8) * 8, XCD swizzle: group = flat/(8*NT),
// mt = 8*group + flat%8, nt = (flat%(8*NT))/8  =>  XCD(flat%8) == mt%8.
// OUT: 0 = fp32 Cf; 1 = bf16 hi only; 2 = bf16 hi+lo; 3 = QKV fused (n<512: bf16 hi
// rows; n>=512: V written transposed into vth[b][h][d][kpad=544], k = row % 513).
template <int OUT, bool ACC, bool GELU_, bool SCALE, bool SPLITA>
__global__ __launch_bounds__(256) void bgemm3_kernel(
    const unsigned short* __restrict__ Ah, const unsigned short* __restrict__ Al,
    const unsigned short* __restrict__ Wh, const unsigned short* __restrict__ Wlo,
    const float* __restrict__ bias, const float* __restrict__ scale,
    float* __restrict__ Cf, unsigned short* __restrict__ Cbh, unsigned short* __restrict__ Cbl,
    unsigned short* __restrict__ vth,
    int M, int N, int K, int lda, int ldw, int groupT, int strideA, int NT, int MT) {
  __shared__ __align__(16) unsigned short SH[4][4096];  // Ah, Al, Wh, Wl tiles [128][32]
  const int flat = blockIdx.x;
  const int grpsz = NT << 3;
  const int grp = flat / grpsz;
  const int rres = flat - grp * grpsz;
  const int mt = (grp << 3) + (rres & 7);
  const int nt = rres >> 3;
  if (mt >= MT) return;
  const int tid = threadIdx.x;
  const int lane = tid & 63;
  const int m0 = mt << 7, n0 = nt << 7;
  const int g = m0 / groupT;
  const long abase = (long)(g * strideA + (m0 - g * groupT)) * lda;
  const int c0 = tid, c1 = tid + 256;
  const int r0c = c0 >> 2, k0c = (c0 & 3) << 3;
  const int r1c = c1 >> 2, k1c = (c1 & 3) << 3;
  const int mEdge = M - m0 - 1;
  const int r0a = r0c <= mEdge ? r0c : mEdge;
  const int r1a = r1c <= mEdge ? r1c : mEdge;
  const long offA0 = abase + (long)r0a * lda + k0c;
  const long offA1 = abase + (long)r1a * lda + k1c;
  const long offB0 = (long)(n0 + r0c) * ldw + k0c;
  const long offB1 = (long)(n0 + r1c) * ldw + k1c;
  unsigned short* s0 = &SH[0][c0 * 8];
  unsigned short* s1 = &SH[0][c1 * 8];
  const int fr = lane & 15, kg = lane >> 4;
  const int aoff = (((tid >> 7) << 6) + fr) * 32 + kg * 8;
  const int boff = ((((tid >> 6) & 1) << 6) + fr) * 32 + kg * 8;
  f32x4 acc[4][4];
#pragma unroll
  for (int i = 0; i < 4; ++i)
#pragma unroll
    for (int j = 0; j < 4; ++j) acc[i][j] = f32x4{0.f, 0.f, 0.f, 0.f};
  for (int k0 = 0; k0 < K; k0 += 32) {
    gl_lds16(Ah + offA0 + k0, s0);
    gl_lds16(Ah + offA1 + k0, s1);
    if (SPLITA) {
      gl_lds16(Al + offA0 + k0, s0 + 4096);
      gl_lds16(Al + offA1 + k0, s1 + 4096);
    }
    gl_lds16(Wh + offB0 + k0, s0 + 8192);
    gl_lds16(Wh + offB1 + k0, s1 + 8192);
    gl_lds16(Wlo + offB0 + k0, s0 + 12288);
    gl_lds16(Wlo + offB1 + k0, s1 + 12288);
    __syncthreads();
    short8 ah[4], al[4], bh[4], bl[4];
#pragma unroll
    for (int i = 0; i < 4; ++i) {
      ah[i] = *(const short8*)&SH[0][aoff + i * 512];
      if (SPLITA) al[i] = *(const short8*)&SH[1][aoff + i * 512];
    }
#pragma unroll
    for (int j = 0; j < 4; ++j) {
      bh[j] = *(const short8*)&SH[2][boff + j * 512];
      bl[j] = *(const short8*)&SH[3][boff + j * 512];
    }
#pragma unroll
    for (int i = 0; i < 4; ++i)
#pragma unroll
      for (int j = 0; j < 4; ++j) {
        acc[i][j] = __builtin_amdgcn_mfma_f32_16x16x32_bf16(ah[i], bl[j], acc[i][j], 0, 0, 0);
        if (SPLITA)
          acc[i][j] = __builtin_amdgcn_mfma_f32_16x16x32_bf16(al[i], bh[j], acc[i][j], 0, 0, 0);
        acc[i][j] = __builtin_amdgcn_mfma_f32_16x16x32_bf16(ah[i], bh[j], acc[i][j], 0, 0, 0);
      }
    __syncthreads();
  }
  const int colb = n0 + (((tid >> 6) & 1) << 6) + fr;
  float bj[4], sj[4];
#pragma unroll
  for (int j = 0; j < 4; ++j) {
    bj[j] = bias ? bias[colb + j * 16] : 0.f;
    sj[j] = SCALE ? scale[colb + j * 16] : 1.f;
  }
  const int rowb = m0 + ((tid >> 7) << 6) + kg * 4;
  if (OUT == 3 && n0 >= 512) {
    // V path: write transposed into vth[b][h][d][544]; rows = k (per batch of 513)
#pragma unroll
    for (int i = 0; i < 4; ++i) {
      const int row0 = rowb + i * 16;
      const int b0 = row0 / 513;
      const int sq0 = row0 - b0 * 513;
#pragma unroll
      for (int j = 0; j < 4; ++j) {
        const int col = colb + j * 16;
        const int hh = (col - 512) >> 5;
        const int dd = col & 31;
        ushort4 pk;
        pk.x = f2bf(acc[i][j][0] + bj[j]);
        pk.y = f2bf(acc[i][j][1] + bj[j]);
        pk.z = f2bf(acc[i][j][2] + bj[j]);
        pk.w = f2bf(acc[i][j][3] + bj[j]);
        if (row0 + 3 < M && sq0 <= 509) {
          *(ushort4*)(vth + (((long)(b0 * 8 + hh)) * 32 + dd) * 544 + sq0) = pk;
        } else {
          const unsigned short pr[4] = {pk.x, pk.y, pk.z, pk.w};
#pragma unroll
          for (int r = 0; r < 4; ++r) {
            const int row = row0 + r;
            if (row < M) {
              const int bb = row / 513, ss = row - bb * 513;
              vth[(((long)(bb * 8 + hh)) * 32 + dd) * 544 + ss] = pr[r];
            }
          }
        }
      }
    }
    return;
  }
#pragma unroll
  for (int i = 0; i < 4; ++i) {
#pragma unroll
    for (int r = 0; r < 4; ++r) {
      const int row = rowb + i * 16 + r;
      if (row < M) {
#pragma unroll
        for (int j = 0; j < 4; ++j) {
          const long off = (long)row * N + colb + j * 16;
          float v = acc[i][j][r];
          if (ACC) v += Cf[off];
          if (SCALE) v *= sj[j];
          v += bj[j];
          if (GELU_) v = gelu_f(v);
          if (OUT == 0) {
            Cf[off] = v;
          } else if (OUT == 2) {
            const unsigned short h = f2bf(v);
            Cbh[off] = h;
            Cbl[off] = f2bf(v - bf2f(h));
          } else {
            Cbh[off] = f2bf(v);
          }
        }
      }
    }
  }
}

// ---------------- fp32 GEMM (tiny tail mats only) ----------------
template <bool ACC, bool GELU_, bool SCALE>
__global__ __launch_bounds__(256) void gemm_kernel(const float* __restrict__ A,
                                                   const float* __restrict__ W,
                                                   const float* __restrict__ bias,
                                                   const float* __restrict__ scale,
                                                   float* __restrict__ C, int M, int N, int K,
                                                   int groupT, int strideA, int rowOff) {
  __shared__ float As[16][68];
  __shared__ float Bs[16][68];
  const int m0 = blockIdx.x * 64, n0 = blockIdx.y * 64;
  const int g = m0 / groupT, r0 = m0 - g * groupT;
  const float* Ab = A + (long)(g * strideA + r0 + rowOff) * K;
  const float* Wb = W + (long)n0 * K;
  const int tid = threadIdx.x;
  const int lr = tid >> 2;
  const int lk = (tid & 3) << 2;
  const int tr = (tid >> 4) << 2;
  const int tc = (tid & 15) << 2;
  float acc[4][4] = {{0.f}};
  for (int k0 = 0; k0 < K; k0 += 16) {
    const float4 a4 = *(const float4*)(Ab + (long)lr * K + k0 + lk);
    const float4 b4 = *(const float4*)(Wb + (long)lr * K + k0 + lk);
    __syncthreads();
    As[lk + 0][lr] = a4.x; As[lk + 1][lr] = a4.y; As[lk + 2][lr] = a4.z; As[lk + 3][lr] = a4.w;
    Bs[lk + 0][lr] = b4.x; Bs[lk + 1][lr] = b4.y; Bs[lk + 2][lr] = b4.z; Bs[lk + 3][lr] = b4.w;
    __syncthreads();
#pragma unroll
    for (int kk = 0; kk < 16; ++kk) {
      const float4 av = *(const float4*)&As[kk][tr];
      const float4 bv = *(const float4*)&Bs[kk][tc];
      acc[0][0] += av.x * bv.x; acc[0][1] += av.x * bv.y; acc[0][2] += av.x * bv.z; acc[0][3] += av.x * bv.w;
      acc[1][0] += av.y * bv.x; acc[1][1] += av.y * bv.y; acc[1][2] += av.y * bv.z; acc[1][3] += av.y * bv.w;
      acc[2][0] += av.z * bv.x; acc[2][1] += av.z * bv.y; acc[2][2] += av.z * bv.z; acc[2][3] += av.z * bv.w;
      acc[3][0] += av.w * bv.x; acc[3][1] += av.w * bv.y; acc[3][2] += av.w * bv.z; acc[3][3] += av.w * bv.w;
    }
  }
  float4 bb = make_float4(0.f, 0.f, 0.f, 0.f);
  if (bias) bb = *(const float4*)(bias + n0 + tc);
  float4 sv = make_float4(1.f, 1.f, 1.f, 1.f);
  if (SCALE) sv = *(const float4*)(scale + n0 + tc);
#pragma unroll
  for (int i = 0; i < 4; ++i) {
    float* cp = C + (long)(m0 + tr + i) * N + n0 + tc;
    float4 v = make_float4(acc[i][0], acc[i][1], acc[i][2], acc[i][3]);
    if (ACC) {
      const float4 c4 = *(const float4*)cp;
      v.x += c4.x; v.y += c4.y; v.z += c4.z; v.w += c4.w;
    }
    if (SCALE) { v.x *= sv.x; v.y *= sv.y; v.z *= sv.z; v.w *= sv.w; }
    v.x += bb.x; v.y += bb.y; v.z += bb.z; v.w += bb.w;
    if (GELU_) { v.x = gelu_f(v.x); v.y = gelu_f(v.y); v.z = gelu_f(v.z); v.w = gelu_f(v.w); }
    *(float4*)cp = v;
  }
}

// ---------------- SE gates (fp32) ----------------
__global__ __launch_bounds__(256) void ca_mean_kernel(const float* __restrict__ x2,
                                                      float* __restrict__ ca) {
  const int b = blockIdx.x, tid = threadIdx.x;
  float s = 0.f;
  for (int t = 0; t < 512; ++t) s += x2[((long)(b * 512 + t)) * 256 + tid];
  ca[b * 256 + tid] = s * (1.0f / 512.0f);
}

__global__ __launch_bounds__(256) void gate1_kernel(const float* __restrict__ ca,
    const float* __restrict__ w1, const float* __restrict__ b1,
    const float* __restrict__ lng, const float* __restrict__ lnb,
    const float* __restrict__ w2, const float* __restrict__ b2, float* __restrict__ ge) {
  const int b = blockIdx.x, tid = threadIdx.x;
  __shared__ float caL[256];
  __shared__ float zL[32];
  caL[tid] = ca[b * 256 + tid];
  __syncthreads();
  if (tid < 32) {
    float s = b1[tid];
    for (int e = 0; e < 256; ++e) s += caL[e] * w1[tid * 256 + e];
    float mean = s;
    for (int msk = 1; msk < 32; msk <<= 1) mean += __shfl_xor(mean, msk);
    mean *= (1.0f / 32.0f);
    const float d = s - mean;
    float v = d * d;
    for (int msk = 1; msk < 32; msk <<= 1) v += __shfl_xor(v, msk);
    v *= (1.0f / 32.0f);
    zL[tid] = gelu_f(d * rsqrtf(v + EPS) * lng[tid] + lnb[tid]);
  }
  __syncthreads();
  float a = b2[tid];
#pragma unroll
  for (int j = 0; j < 32; ++j) a += zL[j] * w2[tid * 32 + j];
  ge[b * 256 + tid] = sigmoid_f(a);
}

__global__ __launch_bounds__(256) void ta_mean_kernel(const float* __restrict__ x2,
                                                      const float* __restrict__ ge,
                                                      float* __restrict__ ta) {
  const int b = blockIdx.x, tid = threadIdx.x;
  const int w = tid >> 6, lane = tid & 63;
  const float4 g4 = *(const float4*)(ge + b * 256 + lane * 4);
  for (int t = w; t < 512; t += 4) {
    const float4 x4 = *(const float4*)(x2 + ((long)(b * 512 + t)) * 256 + lane * 4);
    float s = x4.x * g4.x + x4.y * g4.y + x4.z * g4.z + x4.w * g4.w;
#pragma unroll
    for (int msk = 32; msk; msk >>= 1) s += __shfl_xor(s, msk);
    if (lane == 0) ta[b * 512 + t] = s * (1.0f / 256.0f);
  }
}

__global__ __launch_bounds__(256) void gate2_kernel(const float* __restrict__ ta,
    const float* __restrict__ w1, const float* __restrict__ b1,
    const float* __restrict__ lng, const float* __restrict__ lnb,
    const float* __restrict__ w2, const float* __restrict__ b2, float* __restrict__ gt) {
  const int b = blockIdx.x, tid = threadIdx.x;
  __shared__ float taL[512];
  __shared__ float zL[64];
  taL[tid] = ta[b * 512 + tid];
  taL[256 + tid] = ta[b * 512 + 256 + tid];
  __syncthreads();
  if (tid < 64) {
    float s = b1[tid];
    for (int t = 0; t < 512; ++t) s += taL[t] * w1[tid * 512 + t];
    float mean = s;
    for (int msk = 1; msk < 64; msk <<= 1) mean += __shfl_xor(mean, msk);
    mean *= (1.0f / 64.0f);
    const float d = s - mean;
    float v = d * d;
    for (int msk = 1; msk < 64; msk <<= 1) v += __shfl_xor(v, msk);
    v *= (1.0f / 64.0f);
    zL[tid] = gelu_f(d * rsqrtf(v + EPS) * lng[tid] + lnb[tid]);
  }
  __syncthreads();
#pragma unroll
  for (int r = 0; r < 2; ++r) {
    const int t = tid + r * 256;
    float a = b2[t];
    for (int j = 0; j < 64; ++j) a += zL[j] * w2[t * 64 + j];
    gt[b * 512 + t] = sigmoid_f(a);
  }
}

// x_seq build (fp32 residual stream); PE precomputed
__global__ __launch_bounds__(256) void xseq_kernel(const float* __restrict__ x2,
    const float* __restrict__ ge, const float* __restrict__ gt,
    const float* __restrict__ cls, const float* __restrict__ pe, float* __restrict__ x) {
  const int srow = blockIdx.x, b = blockIdx.y, e = threadIdx.x;
  float* outp = x + ((long)(b * 513 + srow)) * 256 + e;
  if (srow == 0) { *outp = cls[e]; return; }
  const int t = srow - 1;
  *outp = x2[((long)(b * 512 + t)) * 256 + e] * ge[b * 256 + e] * gt[b * 512 + t]
        + pe[t * 256 + e];
}

// ---------------- LayerNorm fp32 -> fp32 (tail) ----------------
template <bool GELU_>
__global__ __launch_bounds__(256) void ln_kernel(const float* __restrict__ in,
                                                 const float* __restrict__ g,
                                                 const float* __restrict__ bta,
                                                 float* __restrict__ out, int D, int ostride) {
  const int row = blockIdx.x, tid = threadIdx.x;
  __shared__ float red[8];
  const float* x = in + (long)row * D;
  const int nv = D >> 8;
  float xv[4];
  float s = 0.f;
  for (int i = 0; i < nv; ++i) { xv[i] = x[tid + (i << 8)]; s += xv[i]; }
#pragma unroll
  for (int msk = 32; msk; msk >>= 1) s += __shfl_xor(s, msk);
  if ((tid & 63) == 0) red[tid >> 6] = s;
  __syncthreads();
  s = red[0] + red[1] + red[2] + red[3];
  const float mean = s / (float)D;
  float vs = 0.f;
  for (int i = 0; i < nv; ++i) { const float d = xv[i] - mean; vs += d * d; }
#pragma unroll
  for (int msk = 32; msk; msk >>= 1) vs += __shfl_xor(vs, msk);
  if ((tid & 63) == 0) red[4 + (tid >> 6)] = vs;
  __syncthreads();
  vs = red[4] + red[5] + red[6] + red[7];
  const float inv = rsqrtf(vs / (float)D + EPS);
  for (int i = 0; i < nv; ++i) {
    const int col = tid + (i << 8);
    float y = (xv[i] - mean) * inv * g[col] + bta[col];
    if (GELU_) y = gelu_f(y);
    out[(long)row * ostride + col] = y;
  }
}

// ---------------- LayerNorm D=256, fp32 -> bf16 planes (hi+lo or hi only) ----------------
template <bool WRITELO>
__global__ __launch_bounds__(256) void ln256p_kernel(const float* __restrict__ in,
                                                     const float* __restrict__ g,
                                                     const float* __restrict__ bta,
                                                     unsigned short* __restrict__ oh,
                                                     unsigned short* __restrict__ ol) {
  const int row = blockIdx.x, tid = threadIdx.x;
  __shared__ float red[8];
  const float xv = in[(long)row * 256 + tid];
  float s = xv;
#pragma unroll
  for (int msk = 32; msk; msk >>= 1) s += __shfl_xor(s, msk);
  if ((tid & 63) == 0) red[tid >> 6] = s;
  __syncthreads();
  s = red[0] + red[1] + red[2] + red[3];
  const float mean = s * (1.0f / 256.0f);
  const float d = xv - mean;
  float vs = d * d;
#pragma unroll
  for (int msk = 32; msk; msk >>= 1) vs += __shfl_xor(vs, msk);
  if ((tid & 63) == 0) red[4 + (tid >> 6)] = vs;
  __syncthreads();
  vs = red[4] + red[5] + red[6] + red[7];
  const float inv = rsqrtf(vs * (1.0f / 256.0f) + EPS);
  const float y = d * inv * g[tid] + bta[tid];
  const unsigned short h = f2bf(y);
  oh[(long)row * 256 + tid] = h;
  if (WRITELO) ol[(long)row * 256 + tid] = f2bf(y - bf2f(h));
}

// ---------------- MFMA flash attention: 2 Q-frags per wave (ILP) ----------------
// 1D grid 2560: flat = h + 8*(qb + 5*b); blocks sharing (b,h) K/V are 8 apart
// (same XCD). 256 thr = 4 waves; wave owns 32 q rows (2 fragments); k-chunk 32.
__global__ __launch_bounds__(256) void attn_bf16_kernel(
    const unsigned short* __restrict__ qkvh, const unsigned short* __restrict__ vth,
    unsigned short* __restrict__ oh) {
  const int flat = blockIdx.x;
  const int h = flat & 7;
  const int t_ = flat >> 3;
  const int qb = t_ % 5;
  const int b = t_ / 5;
  const int tid = threadIdx.x;
  const int wave = tid >> 6, lane = tid & 63;
  const int quad = lane >> 4, l16 = lane & 15;
  __shared__ __align__(16) unsigned short PhS[4][2][16][40];
  unsigned short (*Ph0)[40] = PhS[wave][0];
  unsigned short (*Ph1)[40] = PhS[wave][1];

  const long base = (long)b * 513;
  const int qbase = qb * 128 + wave * 32;
  const int qr0 = qbase + l16;
  const int qr1 = qbase + 16 + l16;
  const short8 qA = *(const short8*)(qkvh + (base + (qr0 < 513 ? qr0 : 512)) * 768 + h * 32 + quad * 8);
  const short8 qB = *(const short8*)(qkvh + (base + (qr1 < 513 ? qr1 : 512)) * 768 + h * 32 + quad * 8);
  const long vtb = ((long)(b * 8 + h)) * 32 * 544;

  const unsigned short* kp0 = qkvh + (base + 2 * l16) * 768 + 256 + h * 32 + quad * 8;
  const unsigned short* kp1 = kp0 + 768;
  const unsigned short* vp0 = vth + vtb + (long)l16 * 544 + quad * 8;
  const unsigned short* vp1 = vth + vtb + (long)(16 + l16) * 544 + quad * 8;
  unsigned int* phpA = (unsigned int*)&Ph0[quad * 4][2 * l16];  // row stride 20 uint
  unsigned int* phpB = (unsigned int*)&Ph1[quad * 4][2 * l16];
  const short8* prdA = (const short8*)&Ph0[l16][quad * 8];
  const short8* prdB = (const short8*)&Ph1[l16][quad * 8];

  float lrowA[4] = {0.f, 0.f, 0.f, 0.f};
  float lrowB[4] = {0.f, 0.f, 0.f, 0.f};
  const f32x4 zf = {0.f, 0.f, 0.f, 0.f};
  f32x4 oaccA[2] = {zf, zf};
  f32x4 oaccB[2] = {zf, zf};
  const float sf2 = 0.25506994362f;  // log2(e)/sqrt(32)

  for (int c = 0; c < 16; ++c) {
    const short8 k0r = *(const short8*)kp0;
    const short8 k1r = *(const short8*)kp1;
    kp0 += 32 * 768;
    kp1 += 32 * 768;
    const f32x4 sA0 = __builtin_amdgcn_mfma_f32_16x16x32_bf16(qA, k0r, zf, 0, 0, 0);
    const f32x4 sA1 = __builtin_amdgcn_mfma_f32_16x16x32_bf16(qA, k1r, zf, 0, 0, 0);
    const f32x4 sB0 = __builtin_amdgcn_mfma_f32_16x16x32_bf16(qB, k0r, zf, 0, 0, 0);
    const f32x4 sB1 = __builtin_amdgcn_mfma_f32_16x16x32_bf16(qB, k1r, zf, 0, 0, 0);
#pragma unroll
    for (int r = 0; r < 4; ++r) {
      const float pA0 = fexp2(sA0[r] * sf2);
      const float pA1 = fexp2(sA1[r] * sf2);
      const unsigned int pkA = ((unsigned int)f2bf(pA1) << 16) | f2bf(pA0);
      phpA[r * 20] = pkA;
      lrowA[r] += __uint_as_float(pkA << 16) + __uint_as_float(pkA & 0xFFFF0000u);
      const float pB0 = fexp2(sB0[r] * sf2);
      const float pB1 = fexp2(sB1[r] * sf2);
      const unsigned int pkB = ((unsigned int)f2bf(pB1) << 16) | f2bf(pB0);
      phpB[r * 20] = pkB;
      lrowB[r] += __uint_as_float(pkB << 16) + __uint_as_float(pkB & 0xFFFF0000u);
    }
    asm volatile("" ::: "memory");  // DS writes stay before DS reads (same-wave order)
    const short8 pa = *prdA;
    const short8 pb = *prdB;
    const short8 v0r = *(const short8*)vp0;
    const short8 v1r = *(const short8*)vp1;
    vp0 += 32;
    vp1 += 32;
    oaccA[0] = __builtin_amdgcn_mfma_f32_16x16x32_bf16(pa, v0r, oaccA[0], 0, 0, 0);
    oaccA[1] = __builtin_amdgcn_mfma_f32_16x16x32_bf16(pa, v1r, oaccA[1], 0, 0, 0);
    oaccB[0] = __builtin_amdgcn_mfma_f32_16x16x32_bf16(pb, v0r, oaccB[0], 0, 0, 0);
    oaccB[1] = __builtin_amdgcn_mfma_f32_16x16x32_bf16(pb, v1r, oaccB[1], 0, 0, 0);
    asm volatile("" ::: "memory");  // next chunk's DS writes stay after these reads
  }
  // tail: key 512 only (all lanes load key-512 row; only l16==0 col is real)
  {
    const short8 k512 = *(const short8*)(qkvh + (base + 512) * 768 + 256 + h * 32 + quad * 8);
    const f32x4 sA0 = __builtin_amdgcn_mfma_f32_16x16x32_bf16(qA, k512, zf, 0, 0, 0);
    const f32x4 sB0 = __builtin_amdgcn_mfma_f32_16x16x32_bf16(qB, k512, zf, 0, 0, 0);
#pragma unroll
    for (int r = 0; r < 4; ++r) {
      const float pA0 = (l16 == 0) ? fexp2(sA0[r] * sf2) : 0.f;
      const unsigned int pkA = (unsigned int)f2bf(pA0);
      phpA[r * 20] = pkA;
      lrowA[r] += __uint_as_float(pkA << 16);
      const float pB0 = (l16 == 0) ? fexp2(sB0[r] * sf2) : 0.f;
      const unsigned int pkB = (unsigned int)f2bf(pB0);
      phpB[r * 20] = pkB;
      lrowB[r] += __uint_as_float(pkB << 16);
    }
    asm volatile("" ::: "memory");
    const short8 pa = *prdA;
    const short8 pb = *prdB;
    const short8 v0r = *(const short8*)vp0;
    const short8 v1r = *(const short8*)vp1;
    oaccA[0] = __builtin_amdgcn_mfma_f32_16x16x32_bf16(pa, v0r, oaccA[0], 0, 0, 0);
    oaccA[1] = __builtin_amdgcn_mfma_f32_16x16x32_bf16(pa, v1r, oaccA[1], 0, 0, 0);
    oaccB[0] = __builtin_amdgcn_mfma_f32_16x16x32_bf16(pb, v0r, oaccB[0], 0, 0, 0);
    oaccB[1] = __builtin_amdgcn_mfma_f32_16x16x32_bf16(pb, v1r, oaccB[1], 0, 0, 0);
  }
#pragma unroll
  for (int r = 0; r < 4; ++r) {
    lrowA[r] += __shfl_xor(lrowA[r], 1);
    lrowA[r] += __shfl_xor(lrowA[r], 2);
    lrowA[r] += __shfl_xor(lrowA[r], 4);
    lrowA[r] += __shfl_xor(lrowA[r], 8);
    lrowB[r] += __shfl_xor(lrowB[r], 1);
    lrowB[r] += __shfl_xor(lrowB[r], 2);
    lrowB[r] += __shfl_xor(lrowB[r], 4);
    lrowB[r] += __shfl_xor(lrowB[r], 8);
  }
  const int orowA = qbase + quad * 4;
  const int orowB = qbase + 16 + quad * 4;
#pragma unroll
  for (int r = 0; r < 4; ++r) {
    const int qrA = orowA + r;
    if (qrA < 513) {
      const float inv = 1.0f / lrowA[r];
      oh[(base + qrA) * 256 + h * 32 + l16] = f2bf(oaccA[0][r] * inv);
      oh[(base + qrA) * 256 + h * 32 + 16 + l16] = f2bf(oaccA[1][r] * inv);
    }
    const int qrB = orowB + r;
    if (qrB < 513) {
      const float inv = 1.0f / lrowB[r];
      oh[(base + qrB) * 256 + h * 32 + l16] = f2bf(oaccB[0][r] * inv);
      oh[(base + qrB) * 256 + h * 32 + 16 + l16] = f2bf(oaccB[1][r] * inv);
    }
  }
}

// ---------------- fused fusion head: f = GELU(LN(CLS @ fus_w^T + fus_b)) ----------------
__global__ __launch_bounds__(256) void fushead_kernel(const float* __restrict__ x,
    const float* __restrict__ fw, const float* __restrict__ fb,
    const float* __restrict__ lng, const float* __restrict__ lnb,
    float* __restrict__ feats) {
  const int b = blockIdx.x, tid = threadIdx.x;
  __shared__ float cls[256];
  __shared__ float red[8];
  cls[tid] = x[(long)b * 513 * 256 + tid];
  __syncthreads();
  float s = fb[tid];
  const float* wr = fw + (long)tid * 256;
  for (int j = 0; j < 256; j += 4) {
    const float4 w4 = *(const float4*)(wr + j);
    s += cls[j] * w4.x + cls[j + 1] * w4.y + cls[j + 2] * w4.z + cls[j + 3] * w4.w;
  }
  float m = s;
#pragma unroll
  for (int msk = 32; msk; msk >>= 1) m += __shfl_xor(m, msk);
  if ((tid & 63) == 0) red[tid >> 6] = m;
  __syncthreads();
  m = (red[0] + red[1] + red[2] + red[3]) * (1.0f / 256.0f);
  const float d = s - m;
  float vs = d * d;
#pragma unroll
  for (int msk = 32; msk; msk >>= 1) vs += __shfl_xor(vs, msk);
  if ((tid & 63) == 0) red[4 + (tid >> 6)] = vs;
  __syncthreads();
  vs = red[4] + red[5] + red[6] + red[7];
  const float inv = rsqrtf(vs * (1.0f / 256.0f) + EPS);
  feats[b * 1024 + tid] = gelu_f(d * inv * lng[tid] + lnb[tid]);
}

__global__ void final_kernel(const float* __restrict__ c2, const float* __restrict__ w,
                             const float* __restrict__ bias, float* __restrict__ out) {
  const int tid = threadIdx.x;  // 128 threads: (b, n)
  const int b = tid >> 1, n = tid & 1;
  float s = bias[n];
  for (int j = 0; j < 256; ++j) s += c2[b * 256 + j] * w[n * 256 + j];
  out[b * 2 + n] = s;
}

extern "C" void kernel_launch(void* const* d_in, const int* in_sizes, int n_in, void* d_out,
                              int out_size, void* d_ws, size_t ws_size, hipStream_t stream) {
  const float* acc_data = (const float*)d_in[0];
  const float* conv1_w = (const float*)d_in[1];
  const float* conv1_b = (const float*)d_in[2];
  const float* bn1_g = (const float*)d_in[3];
  const float* bn1_b = (const float*)d_in[4];
  const float* conv2_w = (const float*)d_in[5];
  const float* conv2_b = (const float*)d_in[6];
  const float* bn2_g = (const float*)d_in[7];
  const float* bn2_b = (const float*)d_in[8];
  const float* sa_w1 = (const float*)d_in[9];
  const float* sa_b1 = (const float*)d_in[10];
  const float* sa_ln_g = (const float*)d_in[11];
  const float* sa_ln_b = (const float*)d_in[12];
  const float* sa_w2 = (const float*)d_in[13];
  const float* sa_b2 = (const float*)d_in[14];
  const float* ca_w1 = (const float*)d_in[15];
  const float* ca_b1 = (const float*)d_in[16];
  const float* ca_ln_g = (const float*)d_in[17];
  const float* ca_ln_b = (const float*)d_in[18];
  const float* ca_w2 = (const float*)d_in[19];
  const float* ca_b2 = (const float*)d_in[20];
  const float* cls_token = (const float*)d_in[21];
  const float* n1_g = (const float*)d_in[22];
  const float* n1_b = (const float*)d_in[23];
  const float* attn_in_w = (const float*)d_in[24];
  const float* attn_in_b = (const float*)d_in[25];
  const float* attn_out_w = (const float*)d_in[26];
  const float* attn_out_b = (const float*)d_in[27];
  const float* n2_g = (const float*)d_in[28];
  const float* n2_b = (const float*)d_in[29];
  const float* mlp_w1 = (const float*)d_in[30];
  const float* mlp_b1 = (const float*)d_in[31];
  const float* mlp_w2 = (const float*)d_in[32];
  const float* mlp_b2 = (const float*)d_in[33];
  const float* fus_w = (const float*)d_in[34];
  const float* fus_b = (const float*)d_in[35];
  const float* fus_ln_g = (const float*)d_in[36];
  const float* fus_ln_b = (const float*)d_in[37];
  const float* clf_ln_g = (const float*)d_in[38];
  const float* clf_ln_b = (const float*)d_in[39];
  const float* clf_w1 = (const float*)d_in[40];
  const float* clf_b1 = (const float*)d_in[41];
  const float* clf_w2 = (const float*)d_in[42];
  const float* clf_b2 = (const float*)d_in[43];

  // ---- workspace layout (bytes); total ~185 MB ----
  char* p = (char*)d_ws;
  char* RA = p; p += 68255744L;  // aliases: conv [X1P planes|X2] / QKVh / H (hi, full)
  float* X = (float*)p; p += 33619968L;                      // residual [32832,256] f32
  unsigned short* XNh = (unsigned short*)p; p += 16809984L;  // LN out planes (full batch)
  unsigned short* XNl = (unsigned short*)p; p += 16809984L;
  unsigned short* Oh = (unsigned short*)p; p += 16809984L;   // attn out bf16 (full batch)
  unsigned short* Vth = (unsigned short*)p; p += 17825792L;  // DEDICATED Vt [64,8,32,544]
  unsigned short* WQKVh = (unsigned short*)p; p += 1572864L;
  unsigned short* WQKVl = (unsigned short*)p; p += 1572864L;
  unsigned short* WAOh = (unsigned short*)p; p += 524288L;
  unsigned short* WAOl = (unsigned short*)p; p += 524288L;
  unsigned short* WM1h = (unsigned short*)p; p += 2097152L;
  unsigned short* WM1l = (unsigned short*)p; p += 2097152L;
  unsigned short* WM2h = (unsigned short*)p; p += 2097152L;
  unsigned short* WM2l = (unsigned short*)p; p += 2097152L;
  unsigned short* W2Eh = (unsigned short*)p; p += 393216L;
  unsigned short* W2El = (unsigned short*)p; p += 393216L;
  float* EFF = (float*)p;    p += 1024L * 4;
  float* CA = (float*)p;     p += 16384L * 4;
  float* GE = (float*)p;     p += 16384L * 4;
  float* TA = (float*)p;     p += 32768L * 4;
  float* GT = (float*)p;     p += 32768L * 4;
  float* FEATS = (float*)p;  p += 65536L * 4;
  float* CLN = (float*)p;    p += 65536L * 4;
  float* C2 = (float*)p;     p += 16384L * 4;
  float* PE = (float*)p;     p += 131072L * 4;

  // RA aliases (sequential within a layer: QKVh consumed by attn before Hh written)
  unsigned short* X1Ph = (unsigned short*)RA;                 // conv: [64,514,256] hi
  unsigned short* X1Pl = (unsigned short*)(RA + 16842752L);   // lo
  float* X2 = (float*)(RA + 33685504L);                       // [32768,256] f32
  unsigned short* QKVh = (unsigned short*)RA;                 // FULL [32832,768] bf16
  unsigned short* Hh = (unsigned short*)RA;                   // FULL [32832,1024] hi only

  const int GBIG = 1 << 30;

  // weight prep
  prep_kernel<<<1, 256, 0, stream>>>(conv1_b, bn1_g, bn1_b, conv2_b, bn2_g, bn2_b, EFF);
  pe_kernel<<<512, 256, 0, stream>>>(PE);
  vtzero_kernel<<<2048, 256, 0, stream>>>(Vth);
  repack_w2_kernel<<<768, 256, 0, stream>>>(conv2_w, W2Eh, W2El);
  f2bf2_kernel<<<3072, 256, 0, stream>>>(attn_in_w, WQKVh, WQKVl, 786432);
  f2bf2_kernel<<<1024, 256, 0, stream>>>(attn_out_w, WAOh, WAOl, 262144);
  f2bf2_kernel<<<4096, 256, 0, stream>>>(mlp_w1, WM1h, WM1l, 1048576);
  f2bf2_kernel<<<4096, 256, 0, stream>>>(mlp_w2, WM2h, WM2l, 1048576);

  // conv encoder (MT=256, NT=2 -> grid 512)
  zeropad_kernel<<<64, 256, 0, stream>>>(X1Ph, X1Pl);
  conv1_kernel<<<dim3(8, 64), 256, 0, stream>>>(acc_data, conv1_w, EFF, X1Ph, X1Pl);
  bgemm3_kernel<0, false, true, true, true><<<512, 256, 0, stream>>>(
      X1Ph, X1Pl, W2Eh, W2El, EFF + 768, EFF + 512, X2, nullptr, nullptr, nullptr,
      32768, 256, 768, 256, 768, 512, 514, 2, 256);
  // SE gates + sequence build (fp32)
  ca_mean_kernel<<<64, 256, 0, stream>>>(X2, CA);
  gate1_kernel<<<64, 256, 0, stream>>>(CA, sa_w1, sa_b1, sa_ln_g, sa_ln_b, sa_w2, sa_b2, GE);
  ta_mean_kernel<<<64, 256, 0, stream>>>(X2, GE, TA);
  gate2_kernel<<<64, 256, 0, stream>>>(TA, ca_w1, ca_b1, ca_ln_g, ca_ln_b, ca_w2, ca_b2, GT);
  xseq_kernel<<<dim3(513, 64), 256, 0, stream>>>(X2, GE, GT, cls_token, PE, X);

  // transformer layers; MT=257 -> 33 groups of 8 m-slots
  for (int i = 0; i < 4; ++i) {
    // pre-attn LN: hi plane only (QKV GEMM is 2-term, never reads XNl)
    ln256p_kernel<false><<<32832, 256, 0, stream>>>(X, n1_g + i * 256, n1_b + i * 256, XNh, nullptr);
    // QKV full-batch 2-term GEMM with fused V-transpose (NT=6 -> grid 1584)
    bgemm3_kernel<3, false, false, false, false><<<1584, 256, 0, stream>>>(
        XNh, nullptr, WQKVh + (long)i * 196608, WQKVl + (long)i * 196608,
        attn_in_b + i * 768, nullptr, nullptr, QKVh, nullptr, Vth,
        32832, 768, 256, 256, 256, GBIG, 0, 6, 257);
    attn_bf16_kernel<<<2560, 256, 0, stream>>>(QKVh, Vth, Oh);
    bgemm3_kernel<0, true, false, false, false><<<528, 256, 0, stream>>>(
        Oh, nullptr, WAOh + (long)i * 65536, WAOl + (long)i * 65536,
        attn_out_b + i * 256, nullptr, X, nullptr, nullptr, nullptr,
        32832, 256, 256, 256, 256, GBIG, 0, 2, 257);
    // pre-MLP LN: hi+lo (MLP1 stays 3-term)
    ln256p_kernel<true><<<32832, 256, 0, stream>>>(X, n2_g + i * 256, n2_b + i * 256, XNh, XNl);
    bgemm3_kernel<1, false, true, false, true><<<2112, 256, 0, stream>>>(
        XNh, XNl, WM1h + (long)i * 262144, WM1l + (long)i * 262144,
        mlp_b1 + i * 1024, nullptr, nullptr, Hh, nullptr, nullptr,
        32832, 1024, 256, 256, 256, GBIG, 0, 8, 257);
    bgemm3_kernel<0, true, false, false, false><<<528, 256, 0, stream>>>(
        Hh, nullptr, WM2h + (long)i * 262144, WM2l + (long)i * 262144,
        mlp_b2 + i * 256, nullptr, X, nullptr, nullptr, nullptr,
        32832, 256, 1024, 1024, 1024, GBIG, 0, 2, 257);
    fushead_kernel<<<64, 256, 0, stream>>>(X, fus_w + (long)i * 65536, fus_b + i * 256,
                                           fus_ln_g + i * 256, fus_ln_b + i * 256,
                                           FEATS + i * 256);
  }
  ln_kernel<false><<<64, 256, 0, stream>>>(FEATS, clf_ln_g, clf_ln_b, CLN, 1024, 1024);
  gemm_kernel<false, true, false><<<dim3(1, 4), 256, 0, stream>>>(
      CLN, clf_w1, clf_b1, nullptr, C2, 64, 256, 1024, GBIG, 0, 0);
  final_kernel<<<1, 128, 0, stream>>>(C2, clf_w2, clf_b2, (float*)d_out);
}

// Round 15
// 1705.662 us; speedup vs baseline: 1.5072x; 1.1089x over previous
//
#include <hip/hip_runtime.h>
#include <math.h>

#define EPS 1e-5f

// Model dims: B=64, T=512, CIN=4, E=256, H=8, dh=32, S=513, L=4, NC=2.
// GEMMs: split-bf16 weight planes; conv2/MLP1 3-term, AO/MLP2 2-term, QKV 1-term.
// GELU: tanh approximation (|err|<~3e-4; outputs bf16-rounded or margin-covered).
// bgemm3 grid: 1D XCD swizzle. Attention: 2 Q-frags/wave ILP, LDS packed-P.

typedef __attribute__((ext_vector_type(8))) short short8;
typedef __attribute__((ext_vector_type(4))) float f32x4;

__device__ __forceinline__ float gelu_f(float x) {
  // tanh-form GELU: max abs dev from exact erf-GELU ~3e-4 (within error budget)
  const float u = 0.7978845608028654f * (x + 0.044715f * x * x * x);
  const float e = __expf(2.f * u);
  return x * (1.f - 1.f / (e + 1.f));  // 0.5x(1+tanh(u)) == x*(1 - 1/(e^{2u}+1))
}
__device__ __forceinline__ float sigmoid_f(float x) {
  return 1.0f / (1.0f + __expf(-x));
}
__device__ __forceinline__ unsigned short f2bf(float f) {
  unsigned int u = __float_as_uint(f);
  u = (u + 0x7FFFu + ((u >> 16) & 1u)) >> 16;
  return (unsigned short)u;
}
__device__ __forceinline__ float bf2f(unsigned short s) {
  return __uint_as_float(((unsigned int)s) << 16);
}
__device__ __forceinline__ float fexp2(float x) {
#if __has_builtin(__builtin_amdgcn_exp2f)
  return __builtin_amdgcn_exp2f(x);
#else
  return exp2f(x);
#endif
}
__device__ __forceinline__ void gl_lds16(const unsigned short* g, unsigned short* l) {
  __builtin_amdgcn_global_load_lds(
      (const __attribute__((address_space(1))) void*)g,
      (__attribute__((address_space(3))) void*)l, 16, 0, 0);
}

// ---------------- prep: fold conv bias + eval-BN into scale/shift ----------------
__global__ void prep_kernel(const float* __restrict__ c1b, const float* __restrict__ g1,
                            const float* __restrict__ b1, const float* __restrict__ c2b,
                            const float* __restrict__ g2, const float* __restrict__ b2,
                            float* __restrict__ eff) {
  const int t = threadIdx.x;
  const float bninv = rsqrtf(1.0f + EPS);
  const float e1g = bninv * g1[t];
  eff[t]       = e1g;
  eff[256 + t] = c1b[t] * e1g + b1[t];
  const float e2g = bninv * g2[t];
  eff[512 + t] = e2g;
  eff[768 + t] = c2b[t] * e2g + b2[t];
}

// positional embedding table [512][256]
__global__ void pe_kernel(float* __restrict__ pe) {
  const int t = blockIdx.x, e = threadIdx.x;
  const float freq = __expf((float)(e & ~1) * (-0.03597789207803197f));  // -ln(10000)/256
  const float ang = (float)t * freq;
  pe[t * 256 + e] = (e & 1) ? cosf(ang) : sinf(ang);
}

// zero Vt tail (k in [512,544)) once; k=512 is rewritten by QKV each layer
__global__ void vtzero_kernel(unsigned short* __restrict__ vth) {
  const int i = blockIdx.x * 256 + threadIdx.x;  // 16384 rows x 32
  if (i < 524288) vth[(long)(i >> 5) * 544 + 512 + (i & 31)] = 0;
}

// f32 -> bf16 hi+lo planes
__global__ void f2bf2_kernel(const float* __restrict__ src, unsigned short* __restrict__ dh,
                             unsigned short* __restrict__ dl, int n) {
  const int i = blockIdx.x * 256 + threadIdx.x;
  if (i < n) {
    const float x = src[i];
    const unsigned short h = f2bf(x);
    dh[i] = h;
    dl[i] = f2bf(x - bf2f(h));
  }
}

// f32 -> bf16 hi plane only
__global__ void f2bf1_kernel(const float* __restrict__ src, unsigned short* __restrict__ dh,
                             int n) {
  const int i = blockIdx.x * 256 + threadIdx.x;
  if (i < n) dh[i] = f2bf(src[i]);
}

// w2e[e][s*256+ci] = conv2_w[e][ci][s]  (hi/lo), so conv2 == one K=768 GEMM
__global__ void repack_w2_kernel(const float* __restrict__ w2, unsigned short* __restrict__ w2h,
                                 unsigned short* __restrict__ w2l) {
  const int idx = blockIdx.x * 256 + threadIdx.x;  // 256*768
  const int e = idx / 768, rem = idx % 768;
  const int s = rem >> 8, ci = rem & 255;
  const float x = w2[e * 768 + ci * 3 + s];
  const unsigned short h = f2bf(x);
  w2h[idx] = h;
  w2l[idx] = f2bf(x - bf2f(h));
}

// zero padding rows of x1p planes [B][T+2][E]
__global__ void zeropad_kernel(unsigned short* __restrict__ xh, unsigned short* __restrict__ xl) {
  const int b = blockIdx.x, tid = threadIdx.x;
  const long r0 = ((long)b * 514) * 256 + tid;
  const long r1 = ((long)b * 514 + 513) * 256 + tid;
  xh[r0] = 0; xh[r1] = 0; xl[r0] = 0; xl[r1] = 0;
}

// ---------------- conv1 + BN + GELU -> x1p hi/lo planes (rows 1..T) ----------------
__global__ __launch_bounds__(256) void conv1_kernel(const float* __restrict__ in,
                                                    const float* __restrict__ w1,
                                                    const float* __restrict__ eff,
                                                    unsigned short* __restrict__ xh,
                                                    unsigned short* __restrict__ xl) {
  const int b = blockIdx.y, t0 = blockIdx.x * 64;
  const int tid = threadIdx.x;
  __shared__ float4 Ls[66];
  __shared__ float Wl[3072];
  if (tid < 66) {
    const int t = t0 - 1 + tid;
    float4 v = make_float4(0.f, 0.f, 0.f, 0.f);
    if (t >= 0 && t < 512) v = *(const float4*)(in + ((long)b * 512 + t) * 4);
    Ls[tid] = v;
  }
#pragma unroll
  for (int i = 0; i < 12; ++i) Wl[i * 256 + tid] = w1[i * 256 + tid];
  __syncthreads();
  float w[12];
#pragma unroll
  for (int i = 0; i < 12; ++i) w[i] = Wl[tid * 12 + i];  // [c*3+k]
  const float eg = eff[tid], eb = eff[256 + tid];
  const long ob = ((long)b * 514 + t0 + 1) * 256 + tid;
  for (int tl = 0; tl < 64; ++tl) {
    const float4 i0 = Ls[tl], i1 = Ls[tl + 1], i2 = Ls[tl + 2];
    float s = i0.x * w[0] + i1.x * w[1] + i2.x * w[2]
            + i0.y * w[3] + i1.y * w[4] + i2.y * w[5]
            + i0.z * w[6] + i1.z * w[7] + i2.z * w[8]
            + i0.w * w[9] + i1.w * w[10] + i2.w * w[11];
    const float y = gelu_f(s * eg + eb);
    const unsigned short h = f2bf(y);
    xh[ob + (long)tl * 256] = h;
    xl[ob + (long)tl * 256] = f2bf(y - bf2f(h));
  }
}

// ---------------- split-bf16 MFMA GEMM: C[M,N] = epi(A@W^T) ----------------
// 1D grid = NT * ceil(MT/8) * 8, XCD swizzle: group = flat/(8*NT),
// mt = 8*group + flat%8, nt = (flat%(8*NT))/8  =>  XCD(flat%8) == mt%8.
// Terms: ah*wh always; + ah*wl if SPLITW; + al*wh if SPLITA.
// OUT: 0 = fp32 Cf; 1 = bf16 hi only; 2 = bf16 hi+lo; 3 = QKV fused (n<512: bf16 hi
// rows; n>=512: V written transposed into vth[b][h][d][kpad=544], k = row % 513).
template <int OUT, bool ACC, bool GELU_, bool SCALE, bool SPLITA, bool SPLITW>
__global__ __launch_bounds__(256) void bgemm3_kernel(
    const unsigned short* __restrict__ Ah, const unsigned short* __restrict__ Al,
    const unsigned short* __restrict__ Wh, const unsigned short* __restrict__ Wlo,
    const float* __restrict__ bias, const float* __restrict__ scale,
    float* __restrict__ Cf, unsigned short* __restrict__ Cbh, unsigned short* __restrict__ Cbl,
    unsigned short* __restrict__ vth,
    int M, int N, int K, int lda, int ldw, int groupT, int strideA, int NT, int MT) {
  __shared__ __align__(16) unsigned short SH[4][4096];  // Ah, Al, Wh, Wl tiles [128][32]
  const int flat = blockIdx.x;
  const int grpsz = NT << 3;
  const int grp = flat / grpsz;
  const int rres = flat - grp * grpsz;
  const int mt = (grp << 3) + (rres & 7);
  const int nt = rres >> 3;
  if (mt >= MT) return;
  const int tid = threadIdx.x;
  const int lane = tid & 63;
  const int m0 = mt << 7, n0 = nt << 7;
  const int g = m0 / groupT;
  const long abase = (long)(g * strideA + (m0 - g * groupT)) * lda;
  const int c0 = tid, c1 = tid + 256;
  const int r0c = c0 >> 2, k0c = (c0 & 3) << 3;
  const int r1c = c1 >> 2, k1c = (c1 & 3) << 3;
  const int mEdge = M - m0 - 1;
  const int r0a = r0c <= mEdge ? r0c : mEdge;
  const int r1a = r1c <= mEdge ? r1c : mEdge;
  const long offA0 = abase + (long)r0a * lda + k0c;
  const long offA1 = abase + (long)r1a * lda + k1c;
  const long offB0 = (long)(n0 + r0c) * ldw + k0c;
  const long offB1 = (long)(n0 + r1c) * ldw + k1c;
  unsigned short* s0 = &SH[0][c0 * 8];
  unsigned short* s1 = &SH[0][c1 * 8];
  const int fr = lane & 15, kg = lane >> 4;
  const int aoff = (((tid >> 7) << 6) + fr) * 32 + kg * 8;
  const int boff = ((((tid >> 6) & 1) << 6) + fr) * 32 + kg * 8;
  f32x4 acc[4][4];
#pragma unroll
  for (int i = 0; i < 4; ++i)
#pragma unroll
    for (int j = 0; j < 4; ++j) acc[i][j] = f32x4{0.f, 0.f, 0.f, 0.f};
  for (int k0 = 0; k0 < K; k0 += 32) {
    gl_lds16(Ah + offA0 + k0, s0);
    gl_lds16(Ah + offA1 + k0, s1);
    if (SPLITA) {
      gl_lds16(Al + offA0 + k0, s0 + 4096);
      gl_lds16(Al + offA1 + k0, s1 + 4096);
    }
    gl_lds16(Wh + offB0 + k0, s0 + 8192);
    gl_lds16(Wh + offB1 + k0, s1 + 8192);
    if (SPLITW) {
      gl_lds16(Wlo + offB0 + k0, s0 + 12288);
      gl_lds16(Wlo + offB1 + k0, s1 + 12288);
    }
    __syncthreads();
    short8 ah[4], al[4], bh[4], bl[4];
#pragma unroll
    for (int i = 0; i < 4; ++i) {
      ah[i] = *(const short8*)&SH[0][aoff + i * 512];
      if (SPLITA) al[i] = *(const short8*)&SH[1][aoff + i * 512];
    }
#pragma unroll
    for (int j = 0; j < 4; ++j) {
      bh[j] = *(const short8*)&SH[2][boff + j * 512];
      if (SPLITW) bl[j] = *(const short8*)&SH[3][boff + j * 512];
    }
#pragma unroll
    for (int i = 0; i < 4; ++i)
#pragma unroll
      for (int j = 0; j < 4; ++j) {
        if (SPLITW)
          acc[i][j] = __builtin_amdgcn_mfma_f32_16x16x32_bf16(ah[i], bl[j], acc[i][j], 0, 0, 0);
        if (SPLITA)
          acc[i][j] = __builtin_amdgcn_mfma_f32_16x16x32_bf16(al[i], bh[j], acc[i][j], 0, 0, 0);
        acc[i][j] = __builtin_amdgcn_mfma_f32_16x16x32_bf16(ah[i], bh[j], acc[i][j], 0, 0, 0);
      }
    __syncthreads();
  }
  const int colb = n0 + (((tid >> 6) & 1) << 6) + fr;
  float bj[4], sj[4];
#pragma unroll
  for (int j = 0; j < 4; ++j) {
    bj[j] = bias ? bias[colb + j * 16] : 0.f;
    sj[j] = SCALE ? scale[colb + j * 16] : 1.f;
  }
  const int rowb = m0 + ((tid >> 7) << 6) + kg * 4;
  if (OUT == 3 && n0 >= 512) {
    // V path: write transposed into vth[b][h][d][544]; rows = k (per batch of 513)
#pragma unroll
    for (int i = 0; i < 4; ++i) {
      const int row0 = rowb + i * 16;
      const int b0 = row0 / 513;
      const int sq0 = row0 - b0 * 513;
#pragma unroll
      for (int j = 0; j < 4; ++j) {
        const int col = colb + j * 16;
        const int hh = (col - 512) >> 5;
        const int dd = col & 31;
        ushort4 pk;
        pk.x = f2bf(acc[i][j][0] + bj[j]);
        pk.y = f2bf(acc[i][j][1] + bj[j]);
        pk.z = f2bf(acc[i][j][2] + bj[j]);
        pk.w = f2bf(acc[i][j][3] + bj[j]);
        if (row0 + 3 < M && sq0 <= 509) {
          *(ushort4*)(vth + (((long)(b0 * 8 + hh)) * 32 + dd) * 544 + sq0) = pk;
        } else {
          const unsigned short pr[4] = {pk.x, pk.y, pk.z, pk.w};
#pragma unroll
          for (int r = 0; r < 4; ++r) {
            const int row = row0 + r;
            if (row < M) {
              const int bb = row / 513, ss = row - bb * 513;
              vth[(((long)(bb * 8 + hh)) * 32 + dd) * 544 + ss] = pr[r];
            }
          }
        }
      }
    }
    return;
  }
#pragma unroll
  for (int i = 0; i < 4; ++i) {
#pragma unroll
    for (int r = 0; r < 4; ++r) {
      const int row = rowb + i * 16 + r;
      if (row < M) {
#pragma unroll
        for (int j = 0; j < 4; ++j) {
          const long off = (long)row * N + colb + j * 16;
          float v = acc[i][j][r];
          if (ACC) v += Cf[off];
          if (SCALE) v *= sj[j];
          v += bj[j];
          if (GELU_) v = gelu_f(v);
          if (OUT == 0) {
            Cf[off] = v;
          } else if (OUT == 2) {
            const unsigned short h = f2bf(v);
            Cbh[off] = h;
            Cbl[off] = f2bf(v - bf2f(h));
          } else {
            Cbh[off] = f2bf(v);
          }
        }
      }
    }
  }
}

// ---------------- fp32 GEMM (tiny tail mats only) ----------------
template <bool ACC, bool GELU_, bool SCALE>
__global__ __launch_bounds__(256) void gemm_kernel(const float* __restrict__ A,
                                                   const float* __restrict__ W,
                                                   const float* __restrict__ bias,
                                                   const float* __restrict__ scale,
                                                   float* __restrict__ C, int M, int N, int K,
                                                   int groupT, int strideA, int rowOff) {
  __shared__ float As[16][68];
  __shared__ float Bs[16][68];
  const int m0 = blockIdx.x * 64, n0 = blockIdx.y * 64;
  const int g = m0 / groupT, r0 = m0 - g * groupT;
  const float* Ab = A + (long)(g * strideA + r0 + rowOff) * K;
  const float* Wb = W + (long)n0 * K;
  const int tid = threadIdx.x;
  const int lr = tid >> 2;
  const int lk = (tid & 3) << 2;
  const int tr = (tid >> 4) << 2;
  const int tc = (tid & 15) << 2;
  float acc[4][4] = {{0.f}};
  for (int k0 = 0; k0 < K; k0 += 16) {
    const float4 a4 = *(const float4*)(Ab + (long)lr * K + k0 + lk);
    const float4 b4 = *(const float4*)(Wb + (long)lr * K + k0 + lk);
    __syncthreads();
    As[lk + 0][lr] = a4.x; As[lk + 1][lr] = a4.y; As[lk + 2][lr] = a4.z; As[lk + 3][lr] = a4.w;
    Bs[lk + 0][lr] = b4.x; Bs[lk + 1][lr] = b4.y; Bs[lk + 2][lr] = b4.z; Bs[lk + 3][lr] = b4.w;
    __syncthreads();
#pragma unroll
    for (int kk = 0; kk < 16; ++kk) {
      const float4 av = *(const float4*)&As[kk][tr];
      const float4 bv = *(const float4*)&Bs[kk][tc];
      acc[0][0] += av.x * bv.x; acc[0][1] += av.x * bv.y; acc[0][2] += av.x * bv.z; acc[0][3] += av.x * bv.w;
      acc[1][0] += av.y * bv.x; acc[1][1] += av.y * bv.y; acc[1][2] += av.y * bv.z; acc[1][3] += av.y * bv.w;
      acc[2][0] += av.z * bv.x; acc[2][1] += av.z * bv.y; acc[2][2] += av.z * bv.z; acc[2][3] += av.z * bv.w;
      acc[3][0] += av.w * bv.x; acc[3][1] += av.w * bv.y; acc[3][2] += av.w * bv.z; acc[3][3] += av.w * bv.w;
    }
  }
  float4 bb = make_float4(0.f, 0.f, 0.f, 0.f);
  if (bias) bb = *(const float4*)(bias + n0 + tc);
  float4 sv = make_float4(1.f, 1.f, 1.f, 1.f);
  if (SCALE) sv = *(const float4*)(scale + n0 + tc);
#pragma unroll
  for (int i = 0; i < 4; ++i) {
    float* cp = C + (long)(m0 + tr + i) * N + n0 + tc;
    float4 v = make_float4(acc[i][0], acc[i][1], acc[i][2], acc[i][3]);
    if (ACC) {
      const float4 c4 = *(const float4*)cp;
      v.x += c4.x; v.y += c4.y; v.z += c4.z; v.w += c4.w;
    }
    if (SCALE) { v.x *= sv.x; v.y *= sv.y; v.z *= sv.z; v.w *= sv.w; }
    v.x += bb.x; v.y += bb.y; v.z += bb.z; v.w += bb.w;
    if (GELU_) { v.x = gelu_f(v.x); v.y = gelu_f(v.y); v.z = gelu_f(v.z); v.w = gelu_f(v.w); }
    *(float4*)cp = v;
  }
}

// ---------------- SE gates (fp32) ----------------
__global__ __launch_bounds__(256) void ca_mean_kernel(const float* __restrict__ x2,
                                                      float* __restrict__ ca) {
  const int b = blockIdx.x, tid = threadIdx.x;
  float s = 0.f;
  for (int t = 0; t < 512; ++t) s += x2[((long)(b * 512 + t)) * 256 + tid];
  ca[b * 256 + tid] = s * (1.0f / 512.0f);
}

__global__ __launch_bounds__(256) void gate1_kernel(const float* __restrict__ ca,
    const float* __restrict__ w1, const float* __restrict__ b1,
    const float* __restrict__ lng, const float* __restrict__ lnb,
    const float* __restrict__ w2, const float* __restrict__ b2, float* __restrict__ ge) {
  const int b = blockIdx.x, tid = threadIdx.x;
  __shared__ float caL[256];
  __shared__ float zL[32];
  caL[tid] = ca[b * 256 + tid];
  __syncthreads();
  if (tid < 32) {
    float s = b1[tid];
    for (int e = 0; e < 256; ++e) s += caL[e] * w1[tid * 256 + e];
    float mean = s;
    for (int msk = 1; msk < 32; msk <<= 1) mean += __shfl_xor(mean, msk);
    mean *= (1.0f / 32.0f);
    const float d = s - mean;
    float v = d * d;
    for (int msk = 1; msk < 32; msk <<= 1) v += __shfl_xor(v, msk);
    v *= (1.0f / 32.0f);
    zL[tid] = gelu_f(d * rsqrtf(v + EPS) * lng[tid] + lnb[tid]);
  }
  __syncthreads();
  float a = b2[tid];
#pragma unroll
  for (int j = 0; j < 32; ++j) a += zL[j] * w2[tid * 32 + j];
  ge[b * 256 + tid] = sigmoid_f(a);
}

__global__ __launch_bounds__(256) void ta_mean_kernel(const float* __restrict__ x2,
                                                      const float* __restrict__ ge,
                                                      float* __restrict__ ta) {
  const int b = blockIdx.x, tid = threadIdx.x;
  const int w = tid >> 6, lane = tid & 63;
  const float4 g4 = *(const float4*)(ge + b * 256 + lane * 4);
  for (int t = w; t < 512; t += 4) {
    const float4 x4 = *(const float4*)(x2 + ((long)(b * 512 + t)) * 256 + lane * 4);
    float s = x4.x * g4.x + x4.y * g4.y + x4.z * g4.z + x4.w * g4.w;
#pragma unroll
    for (int msk = 32; msk; msk >>= 1) s += __shfl_xor(s, msk);
    if (lane == 0) ta[b * 512 + t] = s * (1.0f / 256.0f);
  }
}

__global__ __launch_bounds__(256) void gate2_kernel(const float* __restrict__ ta,
    const float* __restrict__ w1, const float* __restrict__ b1,
    const float* __restrict__ lng, const float* __restrict__ lnb,
    const float* __restrict__ w2, const float* __restrict__ b2, float* __restrict__ gt) {
  const int b = blockIdx.x, tid = threadIdx.x;
  __shared__ float taL[512];
  __shared__ float zL[64];
  taL[tid] = ta[b * 512 + tid];
  taL[256 + tid] = ta[b * 512 + 256 + tid];
  __syncthreads();
  if (tid < 64) {
    float s = b1[tid];
    for (int t = 0; t < 512; ++t) s += taL[t] * w1[tid * 512 + t];
    float mean = s;
    for (int msk = 1; msk < 64; msk <<= 1) mean += __shfl_xor(mean, msk);
    mean *= (1.0f / 64.0f);
    const float d = s - mean;
    float v = d * d;
    for (int msk = 1; msk < 64; msk <<= 1) v += __shfl_xor(v, msk);
    v *= (1.0f / 64.0f);
    zL[tid] = gelu_f(d * rsqrtf(v + EPS) * lng[tid] + lnb[tid]);
  }
  __syncthreads();
#pragma unroll
  for (int r = 0; r < 2; ++r) {
    const int t = tid + r * 256;
    float a = b2[t];
    for (int j = 0; j < 64; ++j) a += zL[j] * w2[t * 64 + j];
    gt[b * 512 + t] = sigmoid_f(a);
  }
}

// x_seq build (fp32 residual stream); PE precomputed
__global__ __launch_bounds__(256) void xseq_kernel(const float* __restrict__ x2,
    const float* __restrict__ ge, const float* __restrict__ gt,
    const float* __restrict__ cls, const float* __restrict__ pe, float* __restrict__ x) {
  const int srow = blockIdx.x, b = blockIdx.y, e = threadIdx.x;
  float* outp = x + ((long)(b * 513 + srow)) * 256 + e;
  if (srow == 0) { *outp = cls[e]; return; }
  const int t = srow - 1;
  *outp = x2[((long)(b * 512 + t)) * 256 + e] * ge[b * 256 + e] * gt[b * 512 + t]
        + pe[t * 256 + e];
}

// ---------------- LayerNorm fp32 -> fp32 (tail) ----------------
template <bool GELU_>
__global__ __launch_bounds__(256) void ln_kernel(const float* __restrict__ in,
                                                 const float* __restrict__ g,
                                                 const float* __restrict__ bta,
                                                 float* __restrict__ out, int D, int ostride) {
  const int row = blockIdx.x, tid = threadIdx.x;
  __shared__ float red[8];
  const float* x = in + (long)row * D;
  const int nv = D >> 8;
  float xv[4];
  float s = 0.f;
  for (int i = 0; i < nv; ++i) { xv[i] = x[tid + (i << 8)]; s += xv[i]; }
#pragma unroll
  for (int msk = 32; msk; msk >>= 1) s += __shfl_xor(s, msk);
  if ((tid & 63) == 0) red[tid >> 6] = s;
  __syncthreads();
  s = red[0] + red[1] + red[2] + red[3];
  const float mean = s / (float)D;
  float vs = 0.f;
  for (int i = 0; i < nv; ++i) { const float d = xv[i] - mean; vs += d * d; }
#pragma unroll
  for (int msk = 32; msk; msk >>= 1) vs += __shfl_xor(vs, msk);
  if ((tid & 63) == 0) red[4 + (tid >> 6)] = vs;
  __syncthreads();
  vs = red[4] + red[5] + red[6] + red[7];
  const float inv = rsqrtf(vs / (float)D + EPS);
  for (int i = 0; i < nv; ++i) {
    const int col = tid + (i << 8);
    float y = (xv[i] - mean) * inv * g[col] + bta[col];
    if (GELU_) y = gelu_f(y);
    out[(long)row * ostride + col] = y;
  }
}

// ---------------- LayerNorm D=256, fp32 -> bf16 planes (hi+lo or hi only) ----------------
template <bool WRITELO>
__global__ __launch_bounds__(256) void ln256p_kernel(const float* __restrict__ in,
                                                     const float* __restrict__ g,
                                                     const float* __restrict__ bta,
                                                     unsigned short* __restrict__ oh,
                                                     unsigned short* __restrict__ ol) {
  const int row = blockIdx.x, tid = threadIdx.x;
  __shared__ float red[8];
  const float xv = in[(long)row * 256 + tid];
  float s = xv;
#pragma unroll
  for (int msk = 32; msk; msk >>= 1) s += __shfl_xor(s, msk);
  if ((tid & 63) == 0) red[tid >> 6] = s;
  __syncthreads();
  s = red[0] + red[1] + red[2] + red[3];
  const float mean = s * (1.0f / 256.0f);
  const float d = xv - mean;
  float vs = d * d;
#pragma unroll
  for (int msk = 32; msk; msk >>= 1) vs += __shfl_xor(vs, msk);
  if ((tid & 63) == 0) red[4 + (tid >> 6)] = vs;
  __syncthreads();
  vs = red[4] + red[5] + red[6] + red[7];
  const float inv = rsqrtf(vs * (1.0f / 256.0f) + EPS);
  const float y = d * inv * g[tid] + bta[tid];
  const unsigned short h = f2bf(y);
  oh[(long)row * 256 + tid] = h;
  if (WRITELO) ol[(long)row * 256 + tid] = f2bf(y - bf2f(h));
}

// ---------------- MFMA flash attention: 2 Q-frags per wave (ILP) ----------------
// 1D grid 2560: flat = h + 8*(qb + 5*b); blocks sharing (b,h) K/V are 8 apart
// (same XCD). 256 thr = 4 waves; wave owns 32 q rows (2 fragments); k-chunk 32.
__global__ __launch_bounds__(256) void attn_bf16_kernel(
    const unsigned short* __restrict__ qkvh, const unsigned short* __restrict__ vth,
    unsigned short* __restrict__ oh) {
  const int flat = blockIdx.x;
  const int h = flat & 7;
  const int t_ = flat >> 3;
  const int qb = t_ % 5;
  const int b = t_ / 5;
  const int tid = threadIdx.x;
  const int wave = tid >> 6, lane = tid & 63;
  const int quad = lane >> 4, l16 = lane & 15;
  __shared__ __align__(16) unsigned short PhS[4][2][16][40];
  unsigned short (*Ph0)[40] = PhS[wave][0];
  unsigned short (*Ph1)[40] = PhS[wave][1];

  const long base = (long)b * 513;
  const int qbase = qb * 128 + wave * 32;
  const int qr0 = qbase + l16;
  const int qr1 = qbase + 16 + l16;
  const short8 qA = *(const short8*)(qkvh + (base + (qr0 < 513 ? qr0 : 512)) * 768 + h * 32 + quad * 8);
  const short8 qB = *(const short8*)(qkvh + (base + (qr1 < 513 ? qr1 : 512)) * 768 + h * 32 + quad * 8);
  const long vtb = ((long)(b * 8 + h)) * 32 * 544;

  const unsigned short* kp0 = qkvh + (base + 2 * l16) * 768 + 256 + h * 32 + quad * 8;
  const unsigned short* kp1 = kp0 + 768;
  const unsigned short* vp0 = vth + vtb + (long)l16 * 544 + quad * 8;
  const unsigned short* vp1 = vth + vtb + (long)(16 + l16) * 544 + quad * 8;
  unsigned int* phpA = (unsigned int*)&Ph0[quad * 4][2 * l16];  // row stride 20 uint
  unsigned int* phpB = (unsigned int*)&Ph1[quad * 4][2 * l16];
  const short8* prdA = (const short8*)&Ph0[l16][quad * 8];
  const short8* prdB = (const short8*)&Ph1[l16][quad * 8];

  float lrowA[4] = {0.f, 0.f, 0.f, 0.f};
  float lrowB[4] = {0.f, 0.f, 0.f, 0.f};
  const f32x4 zf = {0.f, 0.f, 0.f, 0.f};
  f32x4 oaccA[2] = {zf, zf};
  f32x4 oaccB[2] = {zf, zf};
  const float sf2 = 0.25506994362f;  // log2(e)/sqrt(32)

  for (int c = 0; c < 16; ++c) {
    const short8 k0r = *(const short8*)kp0;
    const short8 k1r = *(const short8*)kp1;
    kp0 += 32 * 768;
    kp1 += 32 * 768;
    const f32x4 sA0 = __builtin_amdgcn_mfma_f32_16x16x32_bf16(qA, k0r, zf, 0, 0, 0);
    const f32x4 sA1 = __builtin_amdgcn_mfma_f32_16x16x32_bf16(qA, k1r, zf, 0, 0, 0);
    const f32x4 sB0 = __builtin_amdgcn_mfma_f32_16x16x32_bf16(qB, k0r, zf, 0, 0, 0);
    const f32x4 sB1 = __builtin_amdgcn_mfma_f32_16x16x32_bf16(qB, k1r, zf, 0, 0, 0);
#pragma unroll
    for (int r = 0; r < 4; ++r) {
      const float pA0 = fexp2(sA0[r] * sf2);
      const float pA1 = fexp2(sA1[r] * sf2);
      const unsigned int pkA = ((unsigned int)f2bf(pA1) << 16) | f2bf(pA0);
      phpA[r * 20] = pkA;
      lrowA[r] += __uint_as_float(pkA << 16) + __uint_as_float(pkA & 0xFFFF0000u);
      const float pB0 = fexp2(sB0[r] * sf2);
      const float pB1 = fexp2(sB1[r] * sf2);
      const unsigned int pkB = ((unsigned int)f2bf(pB1) << 16) | f2bf(pB0);
      phpB[r * 20] = pkB;
      lrowB[r] += __uint_as_float(pkB << 16) + __uint_as_float(pkB & 0xFFFF0000u);
    }
    asm volatile("" ::: "memory");  // DS writes stay before DS reads (same-wave order)
    const short8 pa = *prdA;
    const short8 pb = *prdB;
    const short8 v0r = *(const short8*)vp0;
    const short8 v1r = *(const short8*)vp1;
    vp0 += 32;
    vp1 += 32;
    oaccA[0] = __builtin_amdgcn_mfma_f32_16x16x32_bf16(pa, v0r, oaccA[0], 0, 0, 0);
    oaccA[1] = __builtin_amdgcn_mfma_f32_16x16x32_bf16(pa, v1r, oaccA[1], 0, 0, 0);
    oaccB[0] = __builtin_amdgcn_mfma_f32_16x16x32_bf16(pb, v0r, oaccB[0], 0, 0, 0);
    oaccB[1] = __builtin_amdgcn_mfma_f32_16x16x32_bf16(pb, v1r, oaccB[1], 0, 0, 0);
    asm volatile("" ::: "memory");  // next chunk's DS writes stay after these reads
  }
  // tail: key 512 only (all lanes load key-512 row; only l16==0 col is real)
  {
    const short8 k512 = *(const short8*)(qkvh + (base + 512) * 768 + 256 + h * 32 + quad * 8);
    const f32x4 sA0 = __builtin_amdgcn_mfma_f32_16x16x32_bf16(qA, k512, zf, 0, 0, 0);
    const f32x4 sB0 = __builtin_amdgcn_mfma_f32_16x16x32_bf16(qB, k512, zf, 0, 0, 0);
#pragma unroll
    for (int r = 0; r < 4; ++r) {
      const float pA0 = (l16 == 0) ? fexp2(sA0[r] * sf2) : 0.f;
      const unsigned int pkA = (unsigned int)f2bf(pA0);
      phpA[r * 20] = pkA;
      lrowA[r] += __uint_as_float(pkA << 16);
      const float pB0 = (l16 == 0) ? fexp2(sB0[r] * sf2) : 0.f;
      const unsigned int pkB = (unsigned int)f2bf(pB0);
      phpB[r * 20] = pkB;
      lrowB[r] += __uint_as_float(pkB << 16);
    }
    asm volatile("" ::: "memory");
    const short8 pa = *prdA;
    const short8 pb = *prdB;
    const short8 v0r = *(const short8*)vp0;
    const short8 v1r = *(const short8*)vp1;
    oaccA[0] = __builtin_amdgcn_mfma_f32_16x16x32_bf16(pa, v0r, oaccA[0], 0, 0, 0);
    oaccA[1] = __builtin_amdgcn_mfma_f32_16x16x32_bf16(pa, v1r, oaccA[1], 0, 0, 0);
    oaccB[0] = __builtin_amdgcn_mfma_f32_16x16x32_bf16(pb, v0r, oaccB[0], 0, 0, 0);
    oaccB[1] = __builtin_amdgcn_mfma_f32_16x16x32_bf16(pb, v1r, oaccB[1], 0, 0, 0);
  }
#pragma unroll
  for (int r = 0; r < 4; ++r) {
    lrowA[r] += __shfl_xor(lrowA[r], 1);
    lrowA[r] += __shfl_xor(lrowA[r], 2);
    lrowA[r] += __shfl_xor(lrowA[r], 4);
    lrowA[r] += __shfl_xor(lrowA[r], 8);
    lrowB[r] += __shfl_xor(lrowB[r], 1);
    lrowB[r] += __shfl_xor(lrowB[r], 2);
    lrowB[r] += __shfl_xor(lrowB[r], 4);
    lrowB[r] += __shfl_xor(lrowB[r], 8);
  }
  const int orowA = qbase + quad * 4;
  const int orowB = qbase + 16 + quad * 4;
#pragma unroll
  for (int r = 0; r < 4; ++r) {
    const int qrA = orowA + r;
    if (qrA < 513) {
      const float inv = 1.0f / lrowA[r];
      oh[(base + qrA) * 256 + h * 32 + l16] = f2bf(oaccA[0][r] * inv);
      oh[(base + qrA) * 256 + h * 32 + 16 + l16] = f2bf(oaccA[1][r] * inv);
    }
    const int qrB = orowB + r;
    if (qrB < 513) {
      const float inv = 1.0f / lrowB[r];
      oh[(base + qrB) * 256 + h * 32 + l16] = f2bf(oaccB[0][r] * inv);
      oh[(base + qrB) * 256 + h * 32 + 16 + l16] = f2bf(oaccB[1][r] * inv);
    }
  }
}

// ---------------- fused fusion head: f = GELU(LN(CLS @ fus_w^T + fus_b)) ----------------
__global__ __launch_bounds__(256) void fushead_kernel(const float* __restrict__ x,
    const float* __restrict__ fw, const float* __restrict__ fb,
    const float* __restrict__ lng, const float* __restrict__ lnb,
    float* __restrict__ feats) {
  const int b = blockIdx.x, tid = threadIdx.x;
  __shared__ float cls[256];
  __shared__ float red[8];
  cls[tid] = x[(long)b * 513 * 256 + tid];
  __syncthreads();
  float s = fb[tid];
  const float* wr = fw + (long)tid * 256;
  for (int j = 0; j < 256; j += 4) {
    const float4 w4 = *(const float4*)(wr + j);
    s += cls[j] * w4.x + cls[j + 1] * w4.y + cls[j + 2] * w4.z + cls[j + 3] * w4.w;
  }
  float m = s;
#pragma unroll
  for (int msk = 32; msk; msk >>= 1) m += __shfl_xor(m, msk);
  if ((tid & 63) == 0) red[tid >> 6] = m;
  __syncthreads();
  m = (red[0] + red[1] + red[2] + red[3]) * (1.0f / 256.0f);
  const float d = s - m;
  float vs = d * d;
#pragma unroll
  for (int msk = 32; msk; msk >>= 1) vs += __shfl_xor(vs, msk);
  if ((tid & 63) == 0) red[4 + (tid >> 6)] = vs;
  __syncthreads();
  vs = red[4] + red[5] + red[6] + red[7];
  const float inv = rsqrtf(vs * (1.0f / 256.0f) + EPS);
  feats[b * 1024 + tid] = gelu_f(d * inv * lng[tid] + lnb[tid]);
}

__global__ void final_kernel(const float* __restrict__ c2, const float* __restrict__ w,
                             const float* __restrict__ bias, float* __restrict__ out) {
  const int tid = threadIdx.x;  // 128 threads: (b, n)
  const int b = tid >> 1, n = tid & 1;
  float s = bias[n];
  for (int j = 0; j < 256; ++j) s += c2[b * 256 + j] * w[n * 256 + j];
  out[b * 2 + n] = s;
}

extern "C" void kernel_launch(void* const* d_in, const int* in_sizes, int n_in, void* d_out,
                              int out_size, void* d_ws, size_t ws_size, hipStream_t stream) {
  const float* acc_data = (const float*)d_in[0];
  const float* conv1_w = (const float*)d_in[1];
  const float* conv1_b = (const float*)d_in[2];
  const float* bn1_g = (const float*)d_in[3];
  const float* bn1_b = (const float*)d_in[4];
  const float* conv2_w = (const float*)d_in[5];
  const float* conv2_b = (const float*)d_in[6];
  const float* bn2_g = (const float*)d_in[7];
  const float* bn2_b = (const float*)d_in[8];
  const float* sa_w1 = (const float*)d_in[9];
  const float* sa_b1 = (const float*)d_in[10];
  const float* sa_ln_g = (const float*)d_in[11];
  const float* sa_ln_b = (const float*)d_in[12];
  const float* sa_w2 = (const float*)d_in[13];
  const float* sa_b2 = (const float*)d_in[14];
  const float* ca_w1 = (const float*)d_in[15];
  const float* ca_b1 = (const float*)d_in[16];
  const float* ca_ln_g = (const float*)d_in[17];
  const float* ca_ln_b = (const float*)d_in[18];
  const float* ca_w2 = (const float*)d_in[19];
  const float* ca_b2 = (const float*)d_in[20];
  const float* cls_token = (const float*)d_in[21];
  const float* n1_g = (const float*)d_in[22];
  const float* n1_b = (const float*)d_in[23];
  const float* attn_in_w = (const float*)d_in[24];
  const float* attn_in_b = (const float*)d_in[25];
  const float* attn_out_w = (const float*)d_in[26];
  const float* attn_out_b = (const float*)d_in[27];
  const float* n2_g = (const float*)d_in[28];
  const float* n2_b = (const float*)d_in[29];
  const float* mlp_w1 = (const float*)d_in[30];
  const float* mlp_b1 = (const float*)d_in[31];
  const float* mlp_w2 = (const float*)d_in[32];
  const float* mlp_b2 = (const float*)d_in[33];
  const float* fus_w = (const float*)d_in[34];
  const float* fus_b = (const float*)d_in[35];
  const float* fus_ln_g = (const float*)d_in[36];
  const float* fus_ln_b = (const float*)d_in[37];
  const float* clf_ln_g = (const float*)d_in[38];
  const float* clf_ln_b = (const float*)d_in[39];
  const float* clf_w1 = (const float*)d_in[40];
  const float* clf_b1 = (const float*)d_in[41];
  const float* clf_w2 = (const float*)d_in[42];
  const float* clf_b2 = (const float*)d_in[43];

  // ---- workspace layout (bytes); total ~185 MB ----
  char* p = (char*)d_ws;
  char* RA = p; p += 68255744L;  // aliases: conv [X1P planes|X2] / QKVh / H (hi, full)
  float* X = (float*)p; p += 33619968L;                      // residual [32832,256] f32
  unsigned short* XNh = (unsigned short*)p; p += 16809984L;  // LN out planes (full batch)
  unsigned short* XNl = (unsigned short*)p; p += 16809984L;
  unsigned short* Oh = (unsigned short*)p; p += 16809984L;   // attn out bf16 (full batch)
  unsigned short* Vth = (unsigned short*)p; p += 17825792L;  // DEDICATED Vt [64,8,32,544]
  unsigned short* WQKVh = (unsigned short*)p; p += 1572864L;
  unsigned short* WAOh = (unsigned short*)p; p += 524288L;
  unsigned short* WAOl = (unsigned short*)p; p += 524288L;
  unsigned short* WM1h = (unsigned short*)p; p += 2097152L;
  unsigned short* WM1l = (unsigned short*)p; p += 2097152L;
  unsigned short* WM2h = (unsigned short*)p; p += 2097152L;
  unsigned short* WM2l = (unsigned short*)p; p += 2097152L;
  unsigned short* W2Eh = (unsigned short*)p; p += 393216L;
  unsigned short* W2El = (unsigned short*)p; p += 393216L;
  float* EFF = (float*)p;    p += 1024L * 4;
  float* CA = (float*)p;     p += 16384L * 4;
  float* GE = (float*)p;     p += 16384L * 4;
  float* TA = (float*)p;     p += 32768L * 4;
  float* GT = (float*)p;     p += 32768L * 4;
  float* FEATS = (float*)p;  p += 65536L * 4;
  float* CLN = (float*)p;    p += 65536L * 4;
  float* C2 = (float*)p;     p += 16384L * 4;
  float* PE = (float*)p;     p += 131072L * 4;

  // RA aliases (sequential within a layer: QKVh consumed by attn before Hh written)
  unsigned short* X1Ph = (unsigned short*)RA;                 // conv: [64,514,256] hi
  unsigned short* X1Pl = (unsigned short*)(RA + 16842752L);   // lo
  float* X2 = (float*)(RA + 33685504L);                       // [32768,256] f32
  unsigned short* QKVh = (unsigned short*)RA;                 // FULL [32832,768] bf16
  unsigned short* Hh = (unsigned short*)RA;                   // FULL [32832,1024] hi only

  const int GBIG = 1 << 30;

  // weight prep
  prep_kernel<<<1, 256, 0, stream>>>(conv1_b, bn1_g, bn1_b, conv2_b, bn2_g, bn2_b, EFF);
  pe_kernel<<<512, 256, 0, stream>>>(PE);
  vtzero_kernel<<<2048, 256, 0, stream>>>(Vth);
  repack_w2_kernel<<<768, 256, 0, stream>>>(conv2_w, W2Eh, W2El);
  f2bf1_kernel<<<3072, 256, 0, stream>>>(attn_in_w, WQKVh, 786432);
  f2bf2_kernel<<<1024, 256, 0, stream>>>(attn_out_w, WAOh, WAOl, 262144);
  f2bf2_kernel<<<4096, 256, 0, stream>>>(mlp_w1, WM1h, WM1l, 1048576);
  f2bf2_kernel<<<4096, 256, 0, stream>>>(mlp_w2, WM2h, WM2l, 1048576);

  // conv encoder (MT=256, NT=2 -> grid 512)
  zeropad_kernel<<<64, 256, 0, stream>>>(X1Ph, X1Pl);
  conv1_kernel<<<dim3(8, 64), 256, 0, stream>>>(acc_data, conv1_w, EFF, X1Ph, X1Pl);
  bgemm3_kernel<0, false, true, true, true, true><<<512, 256, 0, stream>>>(
      X1Ph, X1Pl, W2Eh, W2El, EFF + 768, EFF + 512, X2, nullptr, nullptr, nullptr,
      32768, 256, 768, 256, 768, 512, 514, 2, 256);
  // SE gates + sequence build (fp32)
  ca_mean_kernel<<<64, 256, 0, stream>>>(X2, CA);
  gate1_kernel<<<64, 256, 0, stream>>>(CA, sa_w1, sa_b1, sa_ln_g, sa_ln_b, sa_w2, sa_b2, GE);
  ta_mean_kernel<<<64, 256, 0, stream>>>(X2, GE, TA);
  gate2_kernel<<<64, 256, 0, stream>>>(TA, ca_w1, ca_b1, ca_ln_g, ca_ln_b, ca_w2, ca_b2, GT);
  xseq_kernel<<<dim3(513, 64), 256, 0, stream>>>(X2, GE, GT, cls_token, PE, X);

  // transformer layers; MT=257 -> 33 groups of 8 m-slots
  for (int i = 0; i < 4; ++i) {
    // pre-attn LN: hi plane only (QKV GEMM is 1-term)
    ln256p_kernel<false><<<32832, 256, 0, stream>>>(X, n1_g + i * 256, n1_b + i * 256, XNh, nullptr);
    // QKV full-batch 1-term GEMM with fused V-transpose (NT=6 -> grid 1584)
    bgemm3_kernel<3, false, false, false, false, false><<<1584, 256, 0, stream>>>(
        XNh, nullptr, WQKVh + (long)i * 196608, nullptr,
        attn_in_b + i * 768, nullptr, nullptr, QKVh, nullptr, Vth,
        32832, 768, 256, 256, 256, GBIG, 0, 6, 257);
    attn_bf16_kernel<<<2560, 256, 0, stream>>>(QKVh, Vth, Oh);
    bgemm3_kernel<0, true, false, false, false, true><<<528, 256, 0, stream>>>(
        Oh, nullptr, WAOh + (long)i * 65536, WAOl + (long)i * 65536,
        attn_out_b + i * 256, nullptr, X, nullptr, nullptr, nullptr,
        32832, 256, 256, 256, 256, GBIG, 0, 2, 257);
    // pre-MLP LN: hi+lo (MLP1 stays 3-term)
    ln256p_kernel<true><<<32832, 256, 0, stream>>>(X, n2_g + i * 256, n2_b + i * 256, XNh, XNl);
    bgemm3_kernel<1, false, true, false, true, true><<<2112, 256, 0, stream>>>(
        XNh, XNl, WM1h + (long)i * 262144, WM1l + (long)i * 262144,
        mlp_b1 + i * 1024, nullptr, nullptr, Hh, nullptr, nullptr,
        32832, 1024, 256, 256, 256, GBIG, 0, 8, 257);
    bgemm3_kernel<0, true, false, false, false, true><<<528, 256, 0, stream>>>(
        Hh, nullptr, WM2h + (long)i * 262144, WM2l + (long)i * 262144,
        mlp_b2 + i * 256, nullptr, X, nullptr, nullptr, nullptr,
        32832, 256, 1024, 1024, 1024, GBIG, 0, 2, 257);
    fushead_kernel<<<64, 256, 0, stream>>>(X, fus_w + (long)i * 65536, fus_b + i * 256,
                                           fus_ln_g + i * 256, fus_ln_b + i * 256,
                                           FEATS + i * 256);
  }
  ln_kernel<false><<<64, 256, 0, stream>>>(FEATS, clf_ln_g, clf_ln_b, CLN, 1024, 1024);
  gemm_kernel<false, true, false><<<dim3(1, 4), 256, 0, stream>>>(
      CLN, clf_w1, clf_b1, nullptr, C2, 64, 256, 1024, GBIG, 0, 0);
  final_kernel<<<1, 128, 0, stream>>>(C2, clf_w2, clf_b2, (float*)d_out);
}